// Round 3
// baseline (871.561 us; speedup 1.0000x reference)
//
#include <hip/hip_runtime.h>

typedef unsigned int u32;

#define NH_   4096
#define NNODE 8192
#define NEDGE 262144

// ---- workspace layout (float offsets) ----
#define OFF_H      0        // 8192*25 = 204800
#define OFF_SC1    204800   // 8192*16 = 131072
#define OFF_NODEH  335872   // 8192*36 = 294912
#define OFF_A      630784   // 8192*42 = 344064
#define OFF_SCALS  974848   // 32*10 = 320
#define OFF_MIDS   975168   // 32*16 = 512
#define OFF_W      975680   // 27820 weights fp32 (padded segments)

// ---- weight offsets inside W (each 16B-aligned) ----
#define W_SC1W   0        // 25x16
#define W_LIN1A  400      // 25x25
#define W_FC1A   1028     // TRANSPOSED: [128][10]
#define W_FC1B   2308     // [128][112]: 4 chunks of 25 padded to 28
#define W_L2A0   16644    // 25x16
#define W_L2A1   17044    // 25x3
#define W_L2A2   17120    // 25x2
#define W_L2A3   17172    // 25x1
#define W_SC2W   17200    // 10x256
#define W_L1B0   19760    // 10x10
#define W_L1B1   19860    // 3x3
#define W_L1B2   19872    // 2x2
#define W_L1B3   19876    // 1x1
#define W_FC2A   19880    // TRANSPOSED: [128][10]
#define W_FC2B   21160    // 128x16
#define W_LIN2B  23208    // 16x256
#define W_HEADW  27304    // 256x2
#define W_HEADB  27816    // 2
#define W_TOTAL  27820
#define SRC_TOTAL 26267

__device__ __forceinline__ float sigmoidf_(float v) { return 1.0f / (1.0f + __expf(-v)); }

__device__ __forceinline__ float wave_sum(float v) {
#pragma unroll
  for (int m = 32; m > 0; m >>= 1) v += __shfl_xor(v, m);
  return v;
}

struct WPtrs { const float* p[18]; };

// copy all fp32 weights -> contiguous W
// fc1_w1/fc2_w1 transposed to [128][10]; fc1_w2 repacked to [128][112] (chunk-pad 25->28)
__global__ void k_convert(WPtrs wp, float* __restrict__ W) {
  const int soff[19] = {0,400,1025,2305,15105,15505,15580,15630,15655,
                        18215,18315,18324,18328,18329,19609,21657,25753,26265,26267};
  const int dbase[18] = {0,400,1028,2308,16644,17044,17120,17172,17200,
                         19760,19860,19872,19876,19880,21160,23208,27304,27816};
  int t = blockIdx.x * 256 + threadIdx.x;
  if (t >= SRC_TOTAL) return;
  int seg = 0;
  for (int s = 1; s < 18; ++s) seg += (t >= soff[s]) ? 1 : 0;
  int q = t - soff[seg];
  int dst = q;
  if (seg == 2 || seg == 13) {       // fc1_w1 / fc2_w1: (10,128) -> [k][j]
    dst = (q % 128) * 10 + q / 128;
  } else if (seg == 3) {             // fc1_w2: (128,100) -> [k][chunk*28 + m%25]
    int k = q / 100, m = q % 100;
    dst = k * 112 + (m / 25) * 28 + (m % 25);
  }
  W[dbase[seg] + dst] = wp.p[seg][q];
}

// per-node: h = x@lin1a/5 (25), sc1 = x@sc1_w/5 (16)
__global__ void __launch_bounds__(256, 4) k_node1(
    const float* __restrict__ wt_x, const float* __restrict__ mt_x,
    const float* __restrict__ W, float* __restrict__ h, float* __restrict__ sc1)
{
  int i = blockIdx.x * 256 + threadIdx.x;
  const float* xp = (i < NH_) ? (wt_x + i * 25) : (mt_x + (i - NH_) * 25);
  float xr[25];
#pragma unroll
  for (int m = 0; m < 25; ++m) xr[m] = xp[m];
  const float* Wl = W + W_LIN1A;
  const float* Ws = W + W_SC1W;
  float ah[25], as[16];
#pragma unroll
  for (int j = 0; j < 25; ++j) ah[j] = 0.f;
#pragma unroll
  for (int j = 0; j < 16; ++j) as[j] = 0.f;
#pragma unroll
  for (int m = 0; m < 25; ++m) {
    float xm = xr[m];
#pragma unroll
    for (int j = 0; j < 25; ++j) ah[j] += xm * Wl[m * 25 + j];
#pragma unroll
    for (int j = 0; j < 16; ++j) as[j] += xm * Ws[m * 16 + j];
  }
#pragma unroll
  for (int j = 0; j < 25; ++j) h[i * 25 + j] = 0.2f * ah[j];
#pragma unroll
  for (int j = 0; j < 16; ++j) sc1[i * 16 + j] = 0.2f * as[j];
}

// edge geometry helpers ------------------------------------------------------
__device__ __forceinline__ void edge_vec(
    const float* __restrict__ wt_pos, const float* __restrict__ mt_pos,
    int src, int dst, float& vx, float& vy, float& vz, float& r)
{
  const float* ps = (src < NH_) ? (wt_pos + src * 3) : (mt_pos + (src - NH_) * 3);
  const float* pd = (dst < NH_) ? (wt_pos + dst * 3) : (mt_pos + (dst - NH_) * 3);
  vx = ps[0] - pd[0];
  vy = ps[1] - pd[1];
  vz = ps[2] - pd[2];
  r = sqrtf(vx * vx + vy * vy + vz * vz);
}

// embs = exp(-((r-c)/step)^2)   [sqrt(NB) * 1/sqrt(NB) folded out]
__device__ __forceinline__ void make_emb(float r, float embs[10]) {
  float rb = r * 0.45f;
#pragma unroll
  for (int b = 0; b < 10; ++b) {
    float d = rb - (float)b;
    embs[b] = __expf(-d * d);
  }
}

__device__ __forceinline__ void make_sh(float vx, float vy, float vz, float r, float sh[16]) {
  float rinv = 1.0f / fmaxf(r, 1e-9f);
  float x = vx * rinv, y = vy * rinv, z = vz * rinv;
  float x2 = x * x, y2 = y * y, z2 = z * z;
  float shA = 3.87298334620742f * x * z;             // s15*x*z
  float shB = 1.93649167310371f * (z2 - x2);         // 0.5*s15*(z2-x2)
  sh[0] = 1.f;
  sh[1] = 1.73205080756888f * x;
  sh[2] = 1.73205080756888f * y;
  sh[3] = 1.73205080756888f * z;
  sh[4] = shA;
  sh[5] = 3.87298334620742f * x * y;
  sh[6] = 2.23606797749979f * (y2 - 0.5f * (x2 + z2));
  sh[7] = 3.87298334620742f * y * z;
  sh[8] = shB;
  sh[9]  = 1.08012344973464f * (shA * z + shB * x);
  sh[10] = 2.64575131106459f * shA * y;
  sh[11] = 1.62018517460197f * (4.f * y2 - x2 - z2) * x;
  sh[12] = 1.32287565553230f * y * (2.f * y2 - 3.f * x2 - 3.f * z2);
  sh[13] = 1.62018517460197f * z * (4.f * y2 - x2 - z2);
  sh[14] = 2.64575131106459f * shB * y;
  sh[15] = 1.08012344973464f * (shB * z - shA * x);
}

// edge pass 1: emb -> MLP1 (10->128->112pad) -> project with l2a* -> atomic into A[dst][42]
__global__ void __launch_bounds__(256, 2) k_edge1(
    const float* __restrict__ wt_pos, const float* __restrict__ mt_pos,
    const int* __restrict__ esrc, const int* __restrict__ edst,
    const float* __restrict__ W, const float* __restrict__ h, float* __restrict__ A)
{
  int e = blockIdx.x * 256 + threadIdx.x;
  int src = esrc[e], dst = edst[e];
  float vx, vy, vz, r;
  edge_vec(wt_pos, mt_pos, src, dst, vx, vy, vz, r);
  float embs[10];
  make_emb(r, embs);

  const float* W1 = W + W_FC1A;  // [128][10], lane-uniform -> scalar loads
  const float* W2 = W + W_FC1B;  // [128][112], rows 16B-aligned
  float acc[112];
#pragma unroll
  for (int c = 0; c < 112; ++c) acc[c] = 0.f;
#pragma unroll 1
  for (int k = 0; k < 128; ++k) {
    const float* w1k = W1 + k * 10;
    float hk = 0.f;
#pragma unroll
    for (int j = 0; j < 10; ++j) hk += embs[j] * w1k[j];
    float s = hk * sigmoidf_(hk);     // silu
    const float4* w2r = (const float4*)(W2 + k * 112);
#pragma unroll
    for (int c4 = 0; c4 < 28; ++c4) {
      float4 w = w2r[c4];
      acc[c4 * 4 + 0] += s * w.x;
      acc[c4 * 4 + 1] += s * w.y;
      acc[c4 * 4 + 2] += s * w.z;
      acc[c4 * 4 + 3] += s * w.w;
    }
  }

  // project 4x25 chunks (at 0,28,56,84) through l2a* with per-src h
  const float* hs = h + src * 25;
  float p0[16], p1[3], p2[2], p3 = 0.f;
#pragma unroll
  for (int v = 0; v < 16; ++v) p0[v] = 0.f;
  p1[0] = p1[1] = p1[2] = 0.f; p2[0] = p2[1] = 0.f;
  const float* L0 = W + W_L2A0;
  const float* L1 = W + W_L2A1;
  const float* L2 = W + W_L2A2;
  const float* L3 = W + W_L2A3;
#pragma unroll
  for (int m = 0; m < 25; ++m) {
    float xm = hs[m];
    float t0 = xm * acc[m];
    float t1 = xm * acc[28 + m];
    float t2 = xm * acc[56 + m];
    float t3 = xm * acc[84 + m];
#pragma unroll
    for (int v = 0; v < 16; ++v) p0[v] += t0 * L0[m * 16 + v];
    p1[0] += t1 * L1[m * 3];  p1[1] += t1 * L1[m * 3 + 1];  p1[2] += t1 * L1[m * 3 + 2];
    p2[0] += t2 * L2[m * 2];  p2[1] += t2 * L2[m * 2 + 1];
    p3    += t3 * L3[m];
  }

  float sh[16];
  make_sh(vx, vy, vz, r, sh);

  const float FS = 0.003125f;  // (1/sqrt(128)) * (1/sqrt(32)) * (1/5)
  float* Ad = A + dst * 42;
#pragma unroll
  for (int v = 0; v < 16; ++v) atomicAdd(Ad + v, p0[v] * FS);
#pragma unroll
  for (int v = 0; v < 3; ++v)
#pragma unroll
    for (int m = 0; m < 3; ++m) atomicAdd(Ad + 16 + v * 3 + m, p1[v] * sh[1 + m] * FS);
#pragma unroll
  for (int v = 0; v < 2; ++v)
#pragma unroll
    for (int m = 0; m < 5; ++m) atomicAdd(Ad + 25 + v * 5 + m, p2[v] * sh[4 + m] * FS);
#pragma unroll
  for (int m = 0; m < 7; ++m) atomicAdd(Ad + 35 + m, p3 * sh[9 + m] * FS);
}

// per-node stage 2: gates/scal -> h0..h3 (36 floats) + group scal sums
__global__ void __launch_bounds__(256, 4) k_node2(
    const float* __restrict__ A, const float* __restrict__ sc1,
    const float* __restrict__ W, float* __restrict__ nodeH, float* __restrict__ scalsum)
{
  int i = blockIdx.x * 256 + threadIdx.x;
  const float* Ai = A + i * 42;
  const float CS_ = 0.38268343236509f, CX_ = 0.92387953251129f;
  float scal[10], gate[6];
#pragma unroll
  for (int c = 0; c < 10; ++c) {
    float s = CS_ * sc1[i * 16 + c] + CX_ * Ai[c];
    scal[c] = s * sigmoidf_(s);
  }
#pragma unroll
  for (int c = 0; c < 6; ++c) {
    float s = CS_ * sc1[i * 16 + 10 + c] + CX_ * Ai[10 + c];
    gate[c] = sigmoidf_(s);
  }
  float* out = nodeH + i * 36;
  const float* B0 = W + W_L1B0;
#pragma unroll
  for (int v = 0; v < 10; ++v) {
    float a = 0.f;
#pragma unroll
    for (int u = 0; u < 10; ++u) a += scal[u] * B0[u * 10 + v];
    out[v] = a * 0.31622776601684f;   // /sqrt(10)
  }
  const float* B1 = W + W_L1B1;
#pragma unroll
  for (int v = 0; v < 3; ++v)
#pragma unroll
    for (int m = 0; m < 3; ++m) {
      float a = 0.f;
#pragma unroll
      for (int u = 0; u < 3; ++u) a += Ai[16 + u * 3 + m] * gate[u] * B1[u * 3 + v];
      out[10 + v * 3 + m] = a * 0.57735026918963f;  // /sqrt(3)
    }
  const float* B2 = W + W_L1B2;
#pragma unroll
  for (int v = 0; v < 2; ++v)
#pragma unroll
    for (int m = 0; m < 5; ++m) {
      float a = 0.f;
#pragma unroll
      for (int u = 0; u < 2; ++u) a += Ai[25 + u * 5 + m] * gate[3 + u] * B2[u * 2 + v];
      out[19 + v * 5 + m] = a * 0.70710678118655f;  // /sqrt(2)
    }
  float b3 = W[W_L1B3];
#pragma unroll
  for (int m = 0; m < 7; ++m) out[29 + m] = Ai[35 + m] * gate[5] * b3;

  // group sums of scal (wave covers 64 consecutive nodes -> single group)
  int g = (i >> 7) & 31;
  int lane = threadIdx.x & 63;
#pragma unroll
  for (int c = 0; c < 10; ++c) {
    float v = wave_sum(scal[c]);
    if (lane == 0) atomicAdd(&scalsum[g * 10 + c], v);
  }
}

// edge pass 2: MLP2 (10->128->16) -> e0..e3 -> group mid sums
__global__ void __launch_bounds__(256, 4) k_edge2(
    const float* __restrict__ wt_pos, const float* __restrict__ mt_pos,
    const int* __restrict__ esrc, const int* __restrict__ edst,
    const float* __restrict__ W, const float* __restrict__ nodeH, float* __restrict__ midsum)
{
  int e = blockIdx.x * 256 + threadIdx.x;
  int src = esrc[e], dst = edst[e];
  float vx, vy, vz, r;
  edge_vec(wt_pos, mt_pos, src, dst, vx, vy, vz, r);
  float embs[10];
  make_emb(r, embs);

  const float* Wa = W + W_FC2A;  // [128][10]
  const float* Wb = W + W_FC2B;  // [128][16], rows 16B-aligned
  float acc[16];
#pragma unroll
  for (int c = 0; c < 16; ++c) acc[c] = 0.f;
#pragma unroll 1
  for (int k = 0; k < 128; ++k) {
    const float* wak = Wa + k * 10;
    float hk = 0.f;
#pragma unroll
    for (int j = 0; j < 10; ++j) hk += embs[j] * wak[j];
    float s = hk * sigmoidf_(hk);
    const float4* wbr = (const float4*)(Wb + k * 16);
#pragma unroll
    for (int c4 = 0; c4 < 4; ++c4) {
      float4 w = wbr[c4];
      acc[c4 * 4 + 0] += s * w.x;
      acc[c4 * 4 + 1] += s * w.y;
      acc[c4 * 4 + 2] += s * w.z;
      acc[c4 * 4 + 3] += s * w.w;
    }
  }

  float sh[16];
  make_sh(vx, vy, vz, r, sh);

  const float* Hs = nodeH + src * 36;
  float ev[16];
#pragma unroll
  for (int c = 0; c < 10; ++c) ev[c] = Hs[c] * acc[c];
#pragma unroll
  for (int u = 0; u < 3; ++u) {
    float d = 0.f;
#pragma unroll
    for (int m = 0; m < 3; ++m) d += Hs[10 + u * 3 + m] * sh[1 + m];
    ev[10 + u] = d * 0.57735026918963f * acc[10 + u];
  }
#pragma unroll
  for (int u = 0; u < 2; ++u) {
    float d = 0.f;
#pragma unroll
    for (int m = 0; m < 5; ++m) d += Hs[19 + u * 5 + m] * sh[4 + m];
    ev[13 + u] = d * 0.44721359549996f * acc[13 + u];
  }
  {
    float d = 0.f;
#pragma unroll
    for (int m = 0; m < 7; ++m) d += Hs[29 + m] * sh[9 + m];
    ev[15] = d * 0.37796447300923f * acc[15];
  }

  // group accumulate: all 64 lanes of a wave share the dst block -> same group
  int g = (dst >> 7) & 31;
  int lane = threadIdx.x & 63;
#pragma unroll
  for (int c = 0; c < 16; ++c) {
    float v = wave_sum(ev[c] * 0.015625f);  // * (1/sqrt(128)) * (1/sqrt(32)) = 1/64
    if (lane == 0) atomicAdd(&midsum[g * 16 + c], v);
  }
}

// finale: fold head through sc2_w / lin2b, one block
__global__ void k_final(const float* __restrict__ W, const float* __restrict__ scalsum,
                        const float* __restrict__ midsum, float* __restrict__ out)
{
  __shared__ float WA[20];  // (10,2) = sc2_w @ head_w
  __shared__ float WB[32];  // (16,2) = lin2b @ head_w
  int t = threadIdx.x;
  const float* S  = W + W_SC2W;
  const float* L  = W + W_LIN2B;
  const float* HW = W + W_HEADW;
  if (t < 20) {
    int j = t >> 1, o = t & 1;
    float a = 0.f;
    for (int c = 0; c < 256; ++c) a += S[j * 256 + c] * HW[c * 2 + o];
    WA[t] = a;
  } else if (t < 52) {
    int q = t - 20, j = q >> 1, o = q & 1;
    float a = 0.f;
    for (int c = 0; c < 256; ++c) a += L[j * 256 + c] * HW[c * 2 + o];
    WB[q] = a;
  }
  __syncthreads();
  if (t < 64) {
    int g = t & 31, o = t >> 5;
    float a = 0.f;
#pragma unroll
    for (int j = 0; j < 10; ++j) a += scalsum[g * 10 + j] * WA[j * 2 + o];
    float b = 0.f;
#pragma unroll
    for (int j = 0; j < 16; ++j) b += midsum[g * 16 + j] * WB[j * 2 + o];
    float y = a * (0.38268343236509f * 0.31622776601684f)   // CS * 1/sqrt(10)
            + b * (0.92387953251129f * 0.25f);              // CX * 1/4
    out[o * 32 + g] = y * (1.0f / 256.0f) + W[W_HEADB + o];
  }
}

extern "C" void kernel_launch(void* const* d_in, const int* in_sizes, int n_in,
                              void* d_out, int out_size, void* d_ws, size_t ws_size,
                              hipStream_t stream)
{
  float* ws = (float*)d_ws;
  const float* wt_pos = (const float*)d_in[0];
  const float* mt_pos = (const float*)d_in[1];
  const float* wt_x   = (const float*)d_in[2];
  const float* mt_x   = (const float*)d_in[3];
  const int* esrc     = (const int*)d_in[6];
  const int* edst     = (const int*)d_in[7];

  float* h       = ws + OFF_H;
  float* sc1     = ws + OFF_SC1;
  float* nodeH   = ws + OFF_NODEH;
  float* A       = ws + OFF_A;
  float* scalsum = ws + OFF_SCALS;
  float* midsum  = ws + OFF_MIDS;
  float* W       = ws + OFF_W;

  // zero accumulators (A + scalsum + midsum are contiguous)
  hipMemsetAsync(A, 0, (size_t)(8192 * 42 + 320 + 512) * sizeof(float), stream);

  WPtrs wp;
  for (int i = 0; i < 18; ++i) wp.p[i] = (const float*)d_in[8 + i];
  k_convert<<<(SRC_TOTAL + 255) / 256, 256, 0, stream>>>(wp, W);
  k_node1<<<NNODE / 256, 256, 0, stream>>>(wt_x, mt_x, W, h, sc1);
  k_edge1<<<NEDGE / 256, 256, 0, stream>>>(wt_pos, mt_pos, esrc, edst, W, h, A);
  k_node2<<<NNODE / 256, 256, 0, stream>>>(A, sc1, W, nodeH, scalsum);
  k_edge2<<<NEDGE / 256, 256, 0, stream>>>(wt_pos, mt_pos, esrc, edst, W, nodeH, midsum);
  k_final<<<1, 256, 0, stream>>>(W, scalsum, midsum, (float*)d_out);
}

// Round 4
// 768.480 us; speedup vs baseline: 1.1341x; 1.1341x over previous
//
#include <hip/hip_runtime.h>

typedef unsigned int u32;

#define NH_   4096
#define NNODE 8192
#define NEDGE 262144

// ---- workspace layout (float offsets) ----
#define OFF_H      0        // 8192*25 = 204800
#define OFF_SC1    204800   // 8192*16 = 131072
#define OFF_NODEH  335872   // 8192*36 = 294912
#define OFF_A      630784   // 8192*42 = 344064
#define OFF_SCALS  974848   // 32*10 = 320
#define OFF_MIDS   975168   // 32*16 = 512
#define OFF_W      975680   // 27820 weights fp32 (padded segments)

// ---- weight offsets inside W (each 16B-aligned) ----
#define W_SC1W   0        // 25x16
#define W_LIN1A  400      // 25x25
#define W_FC1A   1028     // TRANSPOSED: [128][10]
#define W_FC1B   2308     // [128][112]: 4 chunks of 25 padded to 28
#define W_L2A0   16644    // 25x16
#define W_L2A1   17044    // 25x3
#define W_L2A2   17120    // 25x2
#define W_L2A3   17172    // 25x1
#define W_SC2W   17200    // 10x256
#define W_L1B0   19760    // 10x10
#define W_L1B1   19860    // 3x3
#define W_L1B2   19872    // 2x2
#define W_L1B3   19876    // 1x1
#define W_FC2A   19880    // TRANSPOSED: [128][10]
#define W_FC2B   21160    // 128x16
#define W_LIN2B  23208    // 16x256
#define W_HEADW  27304    // 256x2
#define W_HEADB  27816    // 2
#define W_TOTAL  27820
#define SRC_TOTAL 26267

// ---- compile-time unroll: every private-array index is a constant at IR-gen
// time so early SROA promotes arrays to registers (rule #20). ----
template <int I> struct ic { static constexpr int v = I; };
template <int N, typename F>
__device__ __forceinline__ void UN(F&& f) {
  if constexpr (N > 0) { UN<N - 1>(f); f(ic<N - 1>{}); }
}

__device__ __forceinline__ float sigmoidf_(float v) { return 1.0f / (1.0f + __expf(-v)); }

__device__ __forceinline__ float wave_sum(float v) {
#pragma unroll
  for (int m = 32; m > 0; m >>= 1) v += __shfl_xor(v, m);
  return v;
}

struct WPtrs { const float* p[18]; };

// copy all fp32 weights -> contiguous W
// fc1_w1/fc2_w1 transposed to [128][10]; fc1_w2 repacked to [128][112] (chunk-pad 25->28)
__global__ void k_convert(WPtrs wp, float* __restrict__ W) {
  const int soff[19] = {0,400,1025,2305,15105,15505,15580,15630,15655,
                        18215,18315,18324,18328,18329,19609,21657,25753,26265,26267};
  const int dbase[18] = {0,400,1028,2308,16644,17044,17120,17172,17200,
                         19760,19860,19872,19876,19880,21160,23208,27304,27816};
  int t = blockIdx.x * 256 + threadIdx.x;
  if (t >= SRC_TOTAL) return;
  int seg = 0;
  for (int s = 1; s < 18; ++s) seg += (t >= soff[s]) ? 1 : 0;
  int q = t - soff[seg];
  int dst = q;
  if (seg == 2 || seg == 13) {       // fc1_w1 / fc2_w1: (10,128) -> [k][j]
    dst = (q % 128) * 10 + q / 128;
  } else if (seg == 3) {             // fc1_w2: (128,100) -> [k][chunk*28 + m%25]
    int k = q / 100, m = q % 100;
    dst = k * 112 + (m / 25) * 28 + (m % 25);
  }
  W[dbase[seg] + dst] = wp.p[seg][q];
}

// per-node: h = x@lin1a/5 (25), sc1 = x@sc1_w/5 (16)
__global__ void __launch_bounds__(256, 4) k_node1(
    const float* __restrict__ wt_x, const float* __restrict__ mt_x,
    const float* __restrict__ W, float* __restrict__ h, float* __restrict__ sc1)
{
  int i = blockIdx.x * 256 + threadIdx.x;
  const float* xp = (i < NH_) ? (wt_x + i * 25) : (mt_x + (i - NH_) * 25);
  float xr[25];
  UN<25>([&](auto m){ xr[m.v] = xp[m.v]; });
  const float* Wl = W + W_LIN1A;
  const float* Ws = W + W_SC1W;
  float ah[25], as[16];
  UN<25>([&](auto j){ ah[j.v] = 0.f; });
  UN<16>([&](auto j){ as[j.v] = 0.f; });
  UN<25>([&](auto m){
    float xm = xr[m.v];
    UN<25>([&](auto j){ ah[j.v] = fmaf(xm, Wl[m.v * 25 + j.v], ah[j.v]); });
    UN<16>([&](auto j){ as[j.v] = fmaf(xm, Ws[m.v * 16 + j.v], as[j.v]); });
  });
  UN<25>([&](auto j){ h[i * 25 + j.v] = 0.2f * ah[j.v]; });
  UN<16>([&](auto j){ sc1[i * 16 + j.v] = 0.2f * as[j.v]; });
}

// edge geometry helpers ------------------------------------------------------
__device__ __forceinline__ void edge_vec(
    const float* __restrict__ wt_pos, const float* __restrict__ mt_pos,
    int src, int dst, float& vx, float& vy, float& vz, float& r)
{
  const float* ps = (src < NH_) ? (wt_pos + src * 3) : (mt_pos + (src - NH_) * 3);
  const float* pd = (dst < NH_) ? (wt_pos + dst * 3) : (mt_pos + (dst - NH_) * 3);
  vx = ps[0] - pd[0];
  vy = ps[1] - pd[1];
  vz = ps[2] - pd[2];
  r = sqrtf(vx * vx + vy * vy + vz * vz);
}

// embs = exp(-((r-c)/step)^2)   [sqrt(NB) * 1/sqrt(NB) folded out]
__device__ __forceinline__ void make_emb(float r, float* embs) {
  float rb = r * 0.45f;
  UN<10>([&](auto b){ float d = rb - (float)b.v; embs[b.v] = __expf(-d * d); });
}

__device__ __forceinline__ void make_sh(float vx, float vy, float vz, float r, float* sh) {
  float rinv = 1.0f / fmaxf(r, 1e-9f);
  float x = vx * rinv, y = vy * rinv, z = vz * rinv;
  float x2 = x * x, y2 = y * y, z2 = z * z;
  float shA = 3.87298334620742f * x * z;             // s15*x*z
  float shB = 1.93649167310371f * (z2 - x2);         // 0.5*s15*(z2-x2)
  sh[0] = 1.f;
  sh[1] = 1.73205080756888f * x;
  sh[2] = 1.73205080756888f * y;
  sh[3] = 1.73205080756888f * z;
  sh[4] = shA;
  sh[5] = 3.87298334620742f * x * y;
  sh[6] = 2.23606797749979f * (y2 - 0.5f * (x2 + z2));
  sh[7] = 3.87298334620742f * y * z;
  sh[8] = shB;
  sh[9]  = 1.08012344973464f * (shA * z + shB * x);
  sh[10] = 2.64575131106459f * shA * y;
  sh[11] = 1.62018517460197f * (4.f * y2 - x2 - z2) * x;
  sh[12] = 1.32287565553230f * y * (2.f * y2 - 3.f * x2 - 3.f * z2);
  sh[13] = 1.62018517460197f * z * (4.f * y2 - x2 - z2);
  sh[14] = 2.64575131106459f * shB * y;
  sh[15] = 1.08012344973464f * (shB * z - shA * x);
}

// edge pass 1: emb -> MLP1 (10->128->100) -> project with l2a* -> atomic into A[dst][42]
// 2 waves per 64 edges: wave-half 0 owns chunks {0,1} (-> p0,p1), half 1 owns {2,3} (-> p2,p3).
// Chunk base via readfirstlane so all weight reads are provably wave-uniform -> s_load.
__global__ void __launch_bounds__(256, 4) k_edge1(
    const float* __restrict__ wt_pos, const float* __restrict__ mt_pos,
    const int* __restrict__ esrc, const int* __restrict__ edst,
    const float* __restrict__ W, const float* __restrict__ h, float* __restrict__ Aout)
{
  const int lane = threadIdx.x & 63;
  const int wv = threadIdx.x >> 6;
  const int halfu = __builtin_amdgcn_readfirstlane(wv & 1);
  const int e = blockIdx.x * 128 + (wv >> 1) * 64 + lane;
  const int src = esrc[e], dst = edst[e];
  float vx, vy, vz, r;
  edge_vec(wt_pos, mt_pos, src, dst, vx, vy, vz, r);
  float emb[10];
  make_emb(r, emb);

  const float* W1 = W + W_FC1A;                 // [128][10] uniform
  const float* W2 = W + W_FC1B + halfu * 56;    // two 28-wide chunks, uniform
  float AA[25], AB[25];
  UN<25>([&](auto c){ AA[c.v] = 0.f; AB[c.v] = 0.f; });
#pragma unroll 2
  for (int k = 0; k < 128; ++k) {
    const float* w1r = W1 + k * 10;
    float hk = 0.f;
    UN<10>([&](auto j){ hk = fmaf(emb[j.v], w1r[j.v], hk); });
    float s = hk * sigmoidf_(hk);               // silu
    const float* w2r = W2 + k * 112;
    UN<25>([&](auto c){
      AA[c.v] = fmaf(s, w2r[c.v], AA[c.v]);
      AB[c.v] = fmaf(s, w2r[28 + c.v], AB[c.v]);
    });
  }

  const float* hs = h + src * 25;
  float hsr[25];
  UN<25>([&](auto m){ hsr[m.v] = hs[m.v]; });
  float sh[16];
  make_sh(vx, vy, vz, r, sh);

  const float FS = 0.003125f;  // (1/sqrt(128)) * (1/sqrt(32)) * (1/5)
  float* Ad = Aout + dst * 42;
  float T[25];
  if (halfu == 0) {
    UN<25>([&](auto m){ T[m.v] = hsr[m.v] * AA[m.v]; });
    const float* L0 = W + W_L2A0;
    UN<16>([&](auto v){
      float p = 0.f;
      UN<25>([&](auto m){ p = fmaf(T[m.v], L0[m.v * 16 + v.v], p); });
      atomicAdd(Ad + v.v, p * FS);
    });
    UN<25>([&](auto m){ T[m.v] = hsr[m.v] * AB[m.v]; });
    const float* L1 = W + W_L2A1;
    UN<3>([&](auto v){
      float p = 0.f;
      UN<25>([&](auto m){ p = fmaf(T[m.v], L1[m.v * 3 + v.v], p); });
      UN<3>([&](auto m){ atomicAdd(Ad + 16 + v.v * 3 + m.v, p * sh[1 + m.v] * FS); });
    });
  } else {
    UN<25>([&](auto m){ T[m.v] = hsr[m.v] * AA[m.v]; });
    const float* L2 = W + W_L2A2;
    UN<2>([&](auto v){
      float p = 0.f;
      UN<25>([&](auto m){ p = fmaf(T[m.v], L2[m.v * 2 + v.v], p); });
      UN<5>([&](auto m){ atomicAdd(Ad + 25 + v.v * 5 + m.v, p * sh[4 + m.v] * FS); });
    });
    UN<25>([&](auto m){ T[m.v] = hsr[m.v] * AB[m.v]; });
    const float* L3 = W + W_L2A3;
    {
      float p = 0.f;
      UN<25>([&](auto m){ p = fmaf(T[m.v], L3[m.v], p); });
      UN<7>([&](auto m){ atomicAdd(Ad + 35 + m.v, p * sh[9 + m.v] * FS); });
    }
  }
}

// per-node stage 2: gates/scal -> h0..h3 (36 floats) + group scal sums
__global__ void __launch_bounds__(256, 4) k_node2(
    const float* __restrict__ A, const float* __restrict__ sc1,
    const float* __restrict__ W, float* __restrict__ nodeH, float* __restrict__ scalsum)
{
  int i = blockIdx.x * 256 + threadIdx.x;
  const float* Ai = A + i * 42;
  const float CS_ = 0.38268343236509f, CX_ = 0.92387953251129f;
  float scal[10], gate[6];
  UN<10>([&](auto c){
    float s = CS_ * sc1[i * 16 + c.v] + CX_ * Ai[c.v];
    scal[c.v] = s * sigmoidf_(s);
  });
  UN<6>([&](auto c){
    float s = CS_ * sc1[i * 16 + 10 + c.v] + CX_ * Ai[10 + c.v];
    gate[c.v] = sigmoidf_(s);
  });
  float* out = nodeH + i * 36;
  const float* B0 = W + W_L1B0;
  UN<10>([&](auto v){
    float a = 0.f;
    UN<10>([&](auto u){ a = fmaf(scal[u.v], B0[u.v * 10 + v.v], a); });
    out[v.v] = a * 0.31622776601684f;   // /sqrt(10)
  });
  const float* B1 = W + W_L1B1;
  UN<3>([&](auto v){
    UN<3>([&](auto m){
      float a = 0.f;
      UN<3>([&](auto u){ a = fmaf(Ai[16 + u.v * 3 + m.v] * gate[u.v], B1[u.v * 3 + v.v], a); });
      out[10 + v.v * 3 + m.v] = a * 0.57735026918963f;  // /sqrt(3)
    });
  });
  const float* B2 = W + W_L1B2;
  UN<2>([&](auto v){
    UN<5>([&](auto m){
      float a = 0.f;
      UN<2>([&](auto u){ a = fmaf(Ai[25 + u.v * 5 + m.v] * gate[3 + u.v], B2[u.v * 2 + v.v], a); });
      out[19 + v.v * 5 + m.v] = a * 0.70710678118655f;  // /sqrt(2)
    });
  });
  float b3 = W[W_L1B3];
  UN<7>([&](auto m){ out[29 + m.v] = Ai[35 + m.v] * gate[5] * b3; });

  // group sums of scal (wave covers 64 consecutive nodes -> single group)
  int g = (i >> 7) & 31;
  int lane = threadIdx.x & 63;
  UN<10>([&](auto c){
    float v = wave_sum(scal[c.v]);
    if (lane == 0) atomicAdd(&scalsum[g * 10 + c.v], v);
  });
}

// edge pass 2: MLP2 (10->128->16) -> e0..e3 -> group mid sums
__global__ void __launch_bounds__(256, 4) k_edge2(
    const float* __restrict__ wt_pos, const float* __restrict__ mt_pos,
    const int* __restrict__ esrc, const int* __restrict__ edst,
    const float* __restrict__ W, const float* __restrict__ nodeH, float* __restrict__ midsum)
{
  int e = blockIdx.x * 256 + threadIdx.x;
  int src = esrc[e], dst = edst[e];
  float vx, vy, vz, r;
  edge_vec(wt_pos, mt_pos, src, dst, vx, vy, vz, r);
  float emb[10];
  make_emb(r, emb);

  const float* Wa = W + W_FC2A;  // [128][10] uniform
  const float* Wb = W + W_FC2B;  // [128][16] uniform
  float acc[16];
  UN<16>([&](auto c){ acc[c.v] = 0.f; });
#pragma unroll 2
  for (int k = 0; k < 128; ++k) {
    const float* war = Wa + k * 10;
    float hk = 0.f;
    UN<10>([&](auto j){ hk = fmaf(emb[j.v], war[j.v], hk); });
    float s = hk * sigmoidf_(hk);
    const float* wbr = Wb + k * 16;
    UN<16>([&](auto c){ acc[c.v] = fmaf(s, wbr[c.v], acc[c.v]); });
  }

  float sh[16];
  make_sh(vx, vy, vz, r, sh);

  const float* Hs = nodeH + src * 36;
  float ev[16];
  UN<10>([&](auto c){ ev[c.v] = Hs[c.v] * acc[c.v]; });
  UN<3>([&](auto u){
    float d = 0.f;
    UN<3>([&](auto m){ d = fmaf(Hs[10 + u.v * 3 + m.v], sh[1 + m.v], d); });
    ev[10 + u.v] = d * 0.57735026918963f * acc[10 + u.v];
  });
  UN<2>([&](auto u){
    float d = 0.f;
    UN<5>([&](auto m){ d = fmaf(Hs[19 + u.v * 5 + m.v], sh[4 + m.v], d); });
    ev[13 + u.v] = d * 0.44721359549996f * acc[13 + u.v];
  });
  {
    float d = 0.f;
    UN<7>([&](auto m){ d = fmaf(Hs[29 + m.v], sh[9 + m.v], d); });
    ev[15] = d * 0.37796447300923f * acc[15];
  }

  // group accumulate: all 64 lanes of a wave share the dst block -> same group
  int g = (dst >> 7) & 31;
  int lane = threadIdx.x & 63;
  UN<16>([&](auto c){
    float v = wave_sum(ev[c.v] * 0.015625f);  // * (1/sqrt(128)) * (1/sqrt(32)) = 1/64
    if (lane == 0) atomicAdd(&midsum[g * 16 + c.v], v);
  });
}

// finale: fold head through sc2_w / lin2b, one block
__global__ void k_final(const float* __restrict__ W, const float* __restrict__ scalsum,
                        const float* __restrict__ midsum, float* __restrict__ out)
{
  __shared__ float WA[20];  // (10,2) = sc2_w @ head_w
  __shared__ float WB[32];  // (16,2) = lin2b @ head_w
  int t = threadIdx.x;
  const float* S  = W + W_SC2W;
  const float* L  = W + W_LIN2B;
  const float* HW = W + W_HEADW;
  if (t < 20) {
    int j = t >> 1, o = t & 1;
    float a = 0.f;
    for (int c = 0; c < 256; ++c) a += S[j * 256 + c] * HW[c * 2 + o];
    WA[t] = a;
  } else if (t < 52) {
    int q = t - 20, j = q >> 1, o = q & 1;
    float a = 0.f;
    for (int c = 0; c < 256; ++c) a += L[j * 256 + c] * HW[c * 2 + o];
    WB[q] = a;
  }
  __syncthreads();
  if (t < 64) {
    int g = t & 31, o = t >> 5;
    float a = 0.f;
    for (int j = 0; j < 10; ++j) a += scalsum[g * 10 + j] * WA[j * 2 + o];
    float b = 0.f;
    for (int j = 0; j < 16; ++j) b += midsum[g * 16 + j] * WB[j * 2 + o];
    float y = a * (0.38268343236509f * 0.31622776601684f)   // CS * 1/sqrt(10)
            + b * (0.92387953251129f * 0.25f);              // CX * 1/4
    out[o * 32 + g] = y * (1.0f / 256.0f) + W[W_HEADB + o];
  }
}

extern "C" void kernel_launch(void* const* d_in, const int* in_sizes, int n_in,
                              void* d_out, int out_size, void* d_ws, size_t ws_size,
                              hipStream_t stream)
{
  float* ws = (float*)d_ws;
  const float* wt_pos = (const float*)d_in[0];
  const float* mt_pos = (const float*)d_in[1];
  const float* wt_x   = (const float*)d_in[2];
  const float* mt_x   = (const float*)d_in[3];
  const int* esrc     = (const int*)d_in[6];
  const int* edst     = (const int*)d_in[7];

  float* h       = ws + OFF_H;
  float* sc1     = ws + OFF_SC1;
  float* nodeH   = ws + OFF_NODEH;
  float* A       = ws + OFF_A;
  float* scalsum = ws + OFF_SCALS;
  float* midsum  = ws + OFF_MIDS;
  float* W       = ws + OFF_W;

  // zero accumulators (A + scalsum + midsum are contiguous)
  hipMemsetAsync(A, 0, (size_t)(8192 * 42 + 320 + 512) * sizeof(float), stream);

  WPtrs wp;
  for (int i = 0; i < 18; ++i) wp.p[i] = (const float*)d_in[8 + i];
  k_convert<<<(SRC_TOTAL + 255) / 256, 256, 0, stream>>>(wp, W);
  k_node1<<<NNODE / 256, 256, 0, stream>>>(wt_x, mt_x, W, h, sc1);
  k_edge1<<<NEDGE / 128, 256, 0, stream>>>(wt_pos, mt_pos, esrc, edst, W, h, A);
  k_node2<<<NNODE / 256, 256, 0, stream>>>(A, sc1, W, nodeH, scalsum);
  k_edge2<<<NEDGE / 256, 256, 0, stream>>>(wt_pos, mt_pos, esrc, edst, W, nodeH, midsum);
  k_final<<<1, 256, 0, stream>>>(W, scalsum, midsum, (float*)d_out);
}

// Round 5
// 286.802 us; speedup vs baseline: 3.0389x; 2.6795x over previous
//
#include <hip/hip_runtime.h>

typedef unsigned int u32;

#define NH_   4096
#define NNODE 8192
#define NEDGE 262144

// ---- workspace layout (float offsets) ----
#define OFF_H      0        // 8192*25 = 204800
#define OFF_SC1    204800   // 8192*16 = 131072
#define OFF_NODEH  335872   // 8192*36 = 294912
#define OFF_SCALS  630784   // 32*10 = 320
#define OFF_MIDS   631104   // 32*16 = 512
#define OFF_W      631616   // 27820 weights fp32 (padded segments)
#define OFF_APART  659456   // 256 blocks * 5376 = 1376256 partial tiles

// ---- weight offsets inside W (each 16B-aligned) ----
#define W_SC1W   0        // 25x16
#define W_LIN1A  400      // 25x25
#define W_FC1A   1028     // TRANSPOSED: [128][10]
#define W_FC1B   2308     // [128][112]: 4 chunks of 25 padded to 28
#define W_L2A0   16644    // 25x16
#define W_L2A1   17044    // 25x3
#define W_L2A2   17120    // 25x2
#define W_L2A3   17172    // 25x1
#define W_SC2W   17200    // 10x256
#define W_L1B0   19760    // 10x10
#define W_L1B1   19860    // 3x3
#define W_L1B2   19872    // 2x2
#define W_L1B3   19876    // 1x1
#define W_FC2A   19880    // TRANSPOSED: [128][10]
#define W_FC2B   21160    // 128x16
#define W_LIN2B  23208    // 16x256
#define W_HEADW  27304    // 256x2
#define W_HEADB  27816    // 2
#define W_TOTAL  27820
#define SRC_TOTAL 26267

// ---- compile-time unroll: every private-array index is a constant at IR-gen
// time so early SROA promotes arrays to registers (rule #20). ----
template <int I> struct ic { static constexpr int v = I; };
template <int N, typename F>
__device__ __forceinline__ void UN(F&& f) {
  if constexpr (N > 0) { UN<N - 1>(f); f(ic<N - 1>{}); }
}

__device__ __forceinline__ float sigmoidf_(float v) { return 1.0f / (1.0f + __expf(-v)); }

__device__ __forceinline__ float wave_sum(float v) {
#pragma unroll
  for (int m = 32; m > 0; m >>= 1) v += __shfl_xor(v, m);
  return v;
}

struct WPtrs { const float* p[18]; };

// copy all fp32 weights -> contiguous W
// fc1_w1/fc2_w1 transposed to [128][10]; fc1_w2 repacked to [128][112] (chunk-pad 25->28)
__global__ void k_convert(WPtrs wp, float* __restrict__ W) {
  const int soff[19] = {0,400,1025,2305,15105,15505,15580,15630,15655,
                        18215,18315,18324,18328,18329,19609,21657,25753,26265,26267};
  const int dbase[18] = {0,400,1028,2308,16644,17044,17120,17172,17200,
                         19760,19860,19872,19876,19880,21160,23208,27304,27816};
  int t = blockIdx.x * 256 + threadIdx.x;
  if (t >= SRC_TOTAL) return;
  int seg = 0;
  for (int s = 1; s < 18; ++s) seg += (t >= soff[s]) ? 1 : 0;
  int q = t - soff[seg];
  int dst = q;
  if (seg == 2 || seg == 13) {       // fc1_w1 / fc2_w1: (10,128) -> [k][j]
    dst = (q % 128) * 10 + q / 128;
  } else if (seg == 3) {             // fc1_w2: (128,100) -> [k][chunk*28 + m%25]
    int k = q / 100, m = q % 100;
    dst = k * 112 + (m / 25) * 28 + (m % 25);
  }
  W[dbase[seg] + dst] = wp.p[seg][q];
}

// per-node: h = x@lin1a/5 (25), sc1 = x@sc1_w/5 (16)
__global__ void __launch_bounds__(256, 4) k_node1(
    const float* __restrict__ wt_x, const float* __restrict__ mt_x,
    const float* __restrict__ W, float* __restrict__ h, float* __restrict__ sc1)
{
  int i = blockIdx.x * 256 + threadIdx.x;
  const float* xp = (i < NH_) ? (wt_x + i * 25) : (mt_x + (i - NH_) * 25);
  float xr[25];
  UN<25>([&](auto m){ xr[m.v] = xp[m.v]; });
  const float* Wl = W + W_LIN1A;
  const float* Ws = W + W_SC1W;
  float ah[25], as[16];
  UN<25>([&](auto j){ ah[j.v] = 0.f; });
  UN<16>([&](auto j){ as[j.v] = 0.f; });
  UN<25>([&](auto m){
    float xm = xr[m.v];
    UN<25>([&](auto j){ ah[j.v] = fmaf(xm, Wl[m.v * 25 + j.v], ah[j.v]); });
    UN<16>([&](auto j){ as[j.v] = fmaf(xm, Ws[m.v * 16 + j.v], as[j.v]); });
  });
  UN<25>([&](auto j){ h[i * 25 + j.v] = 0.2f * ah[j.v]; });
  UN<16>([&](auto j){ sc1[i * 16 + j.v] = 0.2f * as[j.v]; });
}

// edge geometry helpers ------------------------------------------------------
__device__ __forceinline__ void edge_vec(
    const float* __restrict__ wt_pos, const float* __restrict__ mt_pos,
    int src, int dst, float& vx, float& vy, float& vz, float& r)
{
  const float* ps = (src < NH_) ? (wt_pos + src * 3) : (mt_pos + (src - NH_) * 3);
  const float* pd = (dst < NH_) ? (wt_pos + dst * 3) : (mt_pos + (dst - NH_) * 3);
  vx = ps[0] - pd[0];
  vy = ps[1] - pd[1];
  vz = ps[2] - pd[2];
  r = sqrtf(vx * vx + vy * vy + vz * vz);
}

// embs = exp(-((r-c)/step)^2)   [sqrt(NB) * 1/sqrt(NB) folded out]
__device__ __forceinline__ void make_emb(float r, float* embs) {
  float rb = r * 0.45f;
  UN<10>([&](auto b){ float d = rb - (float)b.v; embs[b.v] = __expf(-d * d); });
}

__device__ __forceinline__ void make_sh(float vx, float vy, float vz, float r, float* sh) {
  float rinv = 1.0f / fmaxf(r, 1e-9f);
  float x = vx * rinv, y = vy * rinv, z = vz * rinv;
  float x2 = x * x, y2 = y * y, z2 = z * z;
  float shA = 3.87298334620742f * x * z;             // s15*x*z
  float shB = 1.93649167310371f * (z2 - x2);         // 0.5*s15*(z2-x2)
  sh[0] = 1.f;
  sh[1] = 1.73205080756888f * x;
  sh[2] = 1.73205080756888f * y;
  sh[3] = 1.73205080756888f * z;
  sh[4] = shA;
  sh[5] = 3.87298334620742f * x * y;
  sh[6] = 2.23606797749979f * (y2 - 0.5f * (x2 + z2));
  sh[7] = 3.87298334620742f * y * z;
  sh[8] = shB;
  sh[9]  = 1.08012344973464f * (shA * z + shB * x);
  sh[10] = 2.64575131106459f * shA * y;
  sh[11] = 1.62018517460197f * (4.f * y2 - x2 - z2) * x;
  sh[12] = 1.32287565553230f * y * (2.f * y2 - 3.f * x2 - 3.f * z2);
  sh[13] = 1.62018517460197f * z * (4.f * y2 - x2 - z2);
  sh[14] = 2.64575131106459f * shB * y;
  sh[15] = 1.08012344973464f * (shB * z - shA * x);
}

// edge pass 1: emb -> MLP1 (10->128->100) -> project with l2a* -> LDS tile -> partial store.
// One block per quarter-group: 1024 threads = 16 waves; wave pair (2k,2k+1) covers the
// same 64 edges (half 0 -> chunks {0,1} = channels 0..24, half 1 -> {2,3} = 25..41).
// All segment-sum atomics go to LDS (group-local by construction); the block then
// streams its 128x42 partial tile to Apart[block] — zero global atomics.
__global__ void __launch_bounds__(1024, 4) k_edge1(
    const float* __restrict__ wt_pos, const float* __restrict__ mt_pos,
    const int* __restrict__ esrc, const int* __restrict__ edst,
    const float* __restrict__ W, const float* __restrict__ h, float* __restrict__ Apart)
{
  __shared__ float lacc[128 * 42];
  const int tid = threadIdx.x;
  const int lane = tid & 63;
  const int wv = tid >> 6;                                   // 0..15
  const int halfu = __builtin_amdgcn_readfirstlane(wv & 1);
  const int g = blockIdx.x >> 2;                             // group (64 total)
  const int q = blockIdx.x & 3;                              // quarter

  for (int t = tid; t < 128 * 42; t += 1024) lacc[t] = 0.f;
  __syncthreads();

  const float* W1 = W + W_FC1A;                 // [128][10] uniform
  const float* W2 = W + W_FC1B + halfu * 56;    // two 28-wide chunks, uniform

#pragma unroll 1
  for (int pass = 0; pass < 2; ++pass) {
    const int e = g * 4096 + q * 1024 + pass * 512 + (wv >> 1) * 64 + lane;
    const int src = esrc[e], dst = edst[e];
    float vx, vy, vz, r;
    edge_vec(wt_pos, mt_pos, src, dst, vx, vy, vz, r);
    float emb[10];
    make_emb(r, emb);

    float AA[25], AB[25];
    UN<25>([&](auto c){ AA[c.v] = 0.f; AB[c.v] = 0.f; });
#pragma unroll 2
    for (int k = 0; k < 128; ++k) {
      const float* w1r = W1 + k * 10;
      float hk = 0.f;
      UN<10>([&](auto j){ hk = fmaf(emb[j.v], w1r[j.v], hk); });
      float s = hk * sigmoidf_(hk);               // silu
      const float* w2r = W2 + k * 112;
      UN<25>([&](auto c){
        AA[c.v] = fmaf(s, w2r[c.v], AA[c.v]);
        AB[c.v] = fmaf(s, w2r[28 + c.v], AB[c.v]);
      });
    }

    const float* hs = h + src * 25;
    float hsr[25];
    UN<25>([&](auto m){ hsr[m.v] = hs[m.v]; });
    float sh[16];
    make_sh(vx, vy, vz, r, sh);

    const float FS = 0.003125f;  // (1/sqrt(128)) * (1/sqrt(32)) * (1/5)
    float* Ad = lacc + (dst & 127) * 42;
    float T[25];
    if (halfu == 0) {
      UN<25>([&](auto m){ T[m.v] = hsr[m.v] * AA[m.v]; });
      const float* L0 = W + W_L2A0;
      UN<16>([&](auto v){
        float p = 0.f;
        UN<25>([&](auto m){ p = fmaf(T[m.v], L0[m.v * 16 + v.v], p); });
        atomicAdd(Ad + v.v, p * FS);
      });
      UN<25>([&](auto m){ T[m.v] = hsr[m.v] * AB[m.v]; });
      const float* L1 = W + W_L2A1;
      UN<3>([&](auto v){
        float p = 0.f;
        UN<25>([&](auto m){ p = fmaf(T[m.v], L1[m.v * 3 + v.v], p); });
        UN<3>([&](auto m){ atomicAdd(Ad + 16 + v.v * 3 + m.v, p * sh[1 + m.v] * FS); });
      });
    } else {
      UN<25>([&](auto m){ T[m.v] = hsr[m.v] * AA[m.v]; });
      const float* L2 = W + W_L2A2;
      UN<2>([&](auto v){
        float p = 0.f;
        UN<25>([&](auto m){ p = fmaf(T[m.v], L2[m.v * 2 + v.v], p); });
        UN<5>([&](auto m){ atomicAdd(Ad + 25 + v.v * 5 + m.v, p * sh[4 + m.v] * FS); });
      });
      UN<25>([&](auto m){ T[m.v] = hsr[m.v] * AB[m.v]; });
      const float* L3 = W + W_L2A3;
      {
        float p = 0.f;
        UN<25>([&](auto m){ p = fmaf(T[m.v], L3[m.v], p); });
        UN<7>([&](auto m){ atomicAdd(Ad + 35 + m.v, p * sh[9 + m.v] * FS); });
      }
    }
  }

  __syncthreads();
  float* out = Apart + (size_t)blockIdx.x * (128 * 42);
  for (int t = tid; t < 128 * 42; t += 1024) out[t] = lacc[t];
}

// per-node stage 2: sum 4 partial tiles -> gates/scal -> h0..h3 (36) + group scal sums
__global__ void __launch_bounds__(256, 4) k_node2(
    const float* __restrict__ Apart, const float* __restrict__ sc1,
    const float* __restrict__ W, float* __restrict__ nodeH, float* __restrict__ scalsum)
{
  int i = blockIdx.x * 256 + threadIdx.x;
  const float* Ap = Apart + (size_t)(i >> 7) * 4 * (128 * 42) + (i & 127) * 42;
  float Ai[42];
  UN<42>([&](auto c){
    Ai[c.v] = (Ap[c.v] + Ap[128 * 42 + c.v]) + (Ap[2 * 128 * 42 + c.v] + Ap[3 * 128 * 42 + c.v]);
  });
  const float CS_ = 0.38268343236509f, CX_ = 0.92387953251129f;
  float scal[10], gate[6];
  UN<10>([&](auto c){
    float s = CS_ * sc1[i * 16 + c.v] + CX_ * Ai[c.v];
    scal[c.v] = s * sigmoidf_(s);
  });
  UN<6>([&](auto c){
    float s = CS_ * sc1[i * 16 + 10 + c.v] + CX_ * Ai[10 + c.v];
    gate[c.v] = sigmoidf_(s);
  });
  float* out = nodeH + i * 36;
  const float* B0 = W + W_L1B0;
  UN<10>([&](auto v){
    float a = 0.f;
    UN<10>([&](auto u){ a = fmaf(scal[u.v], B0[u.v * 10 + v.v], a); });
    out[v.v] = a * 0.31622776601684f;   // /sqrt(10)
  });
  const float* B1 = W + W_L1B1;
  UN<3>([&](auto v){
    UN<3>([&](auto m){
      float a = 0.f;
      UN<3>([&](auto u){ a = fmaf(Ai[16 + u.v * 3 + m.v] * gate[u.v], B1[u.v * 3 + v.v], a); });
      out[10 + v.v * 3 + m.v] = a * 0.57735026918963f;  // /sqrt(3)
    });
  });
  const float* B2 = W + W_L1B2;
  UN<2>([&](auto v){
    UN<5>([&](auto m){
      float a = 0.f;
      UN<2>([&](auto u){ a = fmaf(Ai[25 + u.v * 5 + m.v] * gate[3 + u.v], B2[u.v * 2 + v.v], a); });
      out[19 + v.v * 5 + m.v] = a * 0.70710678118655f;  // /sqrt(2)
    });
  });
  float b3 = W[W_L1B3];
  UN<7>([&](auto m){ out[29 + m.v] = Ai[35 + m.v] * gate[5] * b3; });

  // group sums of scal (wave covers 64 consecutive nodes -> single group)
  int g = (i >> 7) & 31;
  int lane = threadIdx.x & 63;
  UN<10>([&](auto c){
    float v = wave_sum(scal[c.v]);
    if (lane == 0) atomicAdd(&scalsum[g * 10 + c.v], v);
  });
}

// edge pass 2: MLP2 (10->128->16) -> e0..e3 -> group mid sums
__global__ void __launch_bounds__(256, 4) k_edge2(
    const float* __restrict__ wt_pos, const float* __restrict__ mt_pos,
    const int* __restrict__ esrc, const int* __restrict__ edst,
    const float* __restrict__ W, const float* __restrict__ nodeH, float* __restrict__ midsum)
{
  int e = blockIdx.x * 256 + threadIdx.x;
  int src = esrc[e], dst = edst[e];
  float vx, vy, vz, r;
  edge_vec(wt_pos, mt_pos, src, dst, vx, vy, vz, r);
  float emb[10];
  make_emb(r, emb);

  const float* Wa = W + W_FC2A;  // [128][10] uniform
  const float* Wb = W + W_FC2B;  // [128][16] uniform
  float acc[16];
  UN<16>([&](auto c){ acc[c.v] = 0.f; });
#pragma unroll 2
  for (int k = 0; k < 128; ++k) {
    const float* war = Wa + k * 10;
    float hk = 0.f;
    UN<10>([&](auto j){ hk = fmaf(emb[j.v], war[j.v], hk); });
    float s = hk * sigmoidf_(hk);
    const float* wbr = Wb + k * 16;
    UN<16>([&](auto c){ acc[c.v] = fmaf(s, wbr[c.v], acc[c.v]); });
  }

  float sh[16];
  make_sh(vx, vy, vz, r, sh);

  const float* Hs = nodeH + src * 36;
  float ev[16];
  UN<10>([&](auto c){ ev[c.v] = Hs[c.v] * acc[c.v]; });
  UN<3>([&](auto u){
    float d = 0.f;
    UN<3>([&](auto m){ d = fmaf(Hs[10 + u.v * 3 + m.v], sh[1 + m.v], d); });
    ev[10 + u.v] = d * 0.57735026918963f * acc[10 + u.v];
  });
  UN<2>([&](auto u){
    float d = 0.f;
    UN<5>([&](auto m){ d = fmaf(Hs[19 + u.v * 5 + m.v], sh[4 + m.v], d); });
    ev[13 + u.v] = d * 0.44721359549996f * acc[13 + u.v];
  });
  {
    float d = 0.f;
    UN<7>([&](auto m){ d = fmaf(Hs[29 + m.v], sh[9 + m.v], d); });
    ev[15] = d * 0.37796447300923f * acc[15];
  }

  // group accumulate: all 64 lanes of a wave share the dst block -> same group
  int g = (dst >> 7) & 31;
  int lane = threadIdx.x & 63;
  UN<16>([&](auto c){
    float v = wave_sum(ev[c.v] * 0.015625f);  // * (1/sqrt(128)) * (1/sqrt(32)) = 1/64
    if (lane == 0) atomicAdd(&midsum[g * 16 + c.v], v);
  });
}

// finale: fold head through sc2_w / lin2b, one block
__global__ void k_final(const float* __restrict__ W, const float* __restrict__ scalsum,
                        const float* __restrict__ midsum, float* __restrict__ out)
{
  __shared__ float WA[20];  // (10,2) = sc2_w @ head_w
  __shared__ float WB[32];  // (16,2) = lin2b @ head_w
  int t = threadIdx.x;
  const float* S  = W + W_SC2W;
  const float* L  = W + W_LIN2B;
  const float* HW = W + W_HEADW;
  if (t < 20) {
    int j = t >> 1, o = t & 1;
    float a = 0.f;
    for (int c = 0; c < 256; ++c) a += S[j * 256 + c] * HW[c * 2 + o];
    WA[t] = a;
  } else if (t < 52) {
    int q = t - 20, j = q >> 1, o = q & 1;
    float a = 0.f;
    for (int c = 0; c < 256; ++c) a += L[j * 256 + c] * HW[c * 2 + o];
    WB[q] = a;
  }
  __syncthreads();
  if (t < 64) {
    int g = t & 31, o = t >> 5;
    float a = 0.f;
    for (int j = 0; j < 10; ++j) a += scalsum[g * 10 + j] * WA[j * 2 + o];
    float b = 0.f;
    for (int j = 0; j < 16; ++j) b += midsum[g * 16 + j] * WB[j * 2 + o];
    float y = a * (0.38268343236509f * 0.31622776601684f)   // CS * 1/sqrt(10)
            + b * (0.92387953251129f * 0.25f);              // CX * 1/4
    out[o * 32 + g] = y * (1.0f / 256.0f) + W[W_HEADB + o];
  }
}

extern "C" void kernel_launch(void* const* d_in, const int* in_sizes, int n_in,
                              void* d_out, int out_size, void* d_ws, size_t ws_size,
                              hipStream_t stream)
{
  float* ws = (float*)d_ws;
  const float* wt_pos = (const float*)d_in[0];
  const float* mt_pos = (const float*)d_in[1];
  const float* wt_x   = (const float*)d_in[2];
  const float* mt_x   = (const float*)d_in[3];
  const int* esrc     = (const int*)d_in[6];
  const int* edst     = (const int*)d_in[7];

  float* h       = ws + OFF_H;
  float* sc1     = ws + OFF_SC1;
  float* nodeH   = ws + OFF_NODEH;
  float* scalsum = ws + OFF_SCALS;
  float* midsum  = ws + OFF_MIDS;
  float* W       = ws + OFF_W;
  float* Apart   = ws + OFF_APART;

  // zero the tiny group accumulators (scalsum + midsum are contiguous);
  // Apart needs no init — every block fully overwrites its tile.
  hipMemsetAsync(scalsum, 0, (size_t)(320 + 512) * sizeof(float), stream);

  WPtrs wp;
  for (int i = 0; i < 18; ++i) wp.p[i] = (const float*)d_in[8 + i];
  k_convert<<<(SRC_TOTAL + 255) / 256, 256, 0, stream>>>(wp, W);
  k_node1<<<NNODE / 256, 256, 0, stream>>>(wt_x, mt_x, W, h, sc1);
  k_edge1<<<256, 1024, 0, stream>>>(wt_pos, mt_pos, esrc, edst, W, h, Apart);
  k_node2<<<NNODE / 256, 256, 0, stream>>>(Apart, sc1, W, nodeH, scalsum);
  k_edge2<<<NEDGE / 256, 256, 0, stream>>>(wt_pos, mt_pos, esrc, edst, W, nodeH, midsum);
  k_final<<<1, 256, 0, stream>>>(W, scalsum, midsum, (float*)d_out);
}

// Round 6
// 188.002 us; speedup vs baseline: 4.6359x; 1.5255x over previous
//
#include <hip/hip_runtime.h>

#define NH_   4096
#define NNODE 8192
#define NEDGE 262144
#define TS    1024
#define RT    17.4f

// ---- workspace layout (float offsets) ----
#define OFF_H      0        // 8192*28 = 229376 (h padded to 28/row for float4)
#define OFF_SC1    229376   // 8192*16 = 131072
#define OFF_NODEH  360448   // 8192*36 = 294912
#define OFF_SCALS  655360   // 32*10 = 320
#define OFF_MIDS   655680   // 32*16 = 512   (contiguous with SCALS: 832 total)
#define OFF_TAB    656384   // 1024*128 = 131072  (r-table, FS pre-folded)
#define OFF_APART  787456   // 256 blocks * 5376 = 1376256 partial tiles
// total 2163712 floats = 8.66 MB

// ---- compile-time unroll: every private-array index is a constant at IR-gen
// time so early SROA promotes arrays to registers. ----
template <int I> struct ic { static constexpr int v = I; };
template <int N, typename F>
__device__ __forceinline__ void UN(F&& f) {
  if constexpr (N > 0) { UN<N - 1>(f); f(ic<N - 1>{}); }
}

// static extraction from float4 arrays (keeps everything in registers)
template <int K>
__device__ __forceinline__ float f4c(float4 v) {
  if constexpr (K == 0) return v.x;
  else if constexpr (K == 1) return v.y;
  else if constexpr (K == 2) return v.z;
  else return v.w;
}
template <int C>
__device__ __forceinline__ float f4get(const float4* v) {
  return f4c<C & 3>(v[C >> 2]);
}

__device__ __forceinline__ float sigmoidf_(float v) { return 1.0f / (1.0f + __expf(-v)); }

__device__ __forceinline__ float wave_sum(float v) {
#pragma unroll
  for (int m = 32; m > 0; m >>= 1) v += __shfl_xor(v, m);
  return v;
}

// embs = exp(-((r-c)/step)^2)   [sqrt(NB) * 1/sqrt(NB) folded out]
__device__ __forceinline__ void make_emb(float r, float* embs) {
  float rb = r * 0.45f;
  UN<10>([&](auto b){ float d = rb - (float)b.v; embs[b.v] = __expf(-d * d); });
}

__device__ __forceinline__ void edge_vec(
    const float* __restrict__ wt_pos, const float* __restrict__ mt_pos,
    int src, int dst, float& vx, float& vy, float& vz, float& r)
{
  const float* ps = (src < NH_) ? (wt_pos + src * 3) : (mt_pos + (src - NH_) * 3);
  const float* pd = (dst < NH_) ? (wt_pos + dst * 3) : (mt_pos + (dst - NH_) * 3);
  vx = ps[0] - pd[0];
  vy = ps[1] - pd[1];
  vz = ps[2] - pd[2];
  r = sqrtf(vx * vx + vy * vy + vz * vz);
}

__device__ __forceinline__ void make_sh(float vx, float vy, float vz, float r, float* sh) {
  float rinv = 1.0f / fmaxf(r, 1e-9f);
  float x = vx * rinv, y = vy * rinv, z = vz * rinv;
  float x2 = x * x, y2 = y * y, z2 = z * z;
  float shA = 3.87298334620742f * x * z;             // s15*x*z
  float shB = 1.93649167310371f * (z2 - x2);         // 0.5*s15*(z2-x2)
  sh[0] = 1.f;
  sh[1] = 1.73205080756888f * x;
  sh[2] = 1.73205080756888f * y;
  sh[3] = 1.73205080756888f * z;
  sh[4] = shA;
  sh[5] = 3.87298334620742f * x * y;
  sh[6] = 2.23606797749979f * (y2 - 0.5f * (x2 + z2));
  sh[7] = 3.87298334620742f * y * z;
  sh[8] = shB;
  sh[9]  = 1.08012344973464f * (shA * z + shB * x);
  sh[10] = 2.64575131106459f * shA * y;
  sh[11] = 1.62018517460197f * (4.f * y2 - x2 - z2) * x;
  sh[12] = 1.32287565553230f * y * (2.f * y2 - 3.f * x2 - 3.f * z2);
  sh[13] = 1.62018517460197f * z * (4.f * y2 - x2 - z2);
  sh[14] = 2.64575131106459f * shB * y;
  sh[15] = 1.08012344973464f * (shB * z - shA * x);
}

// ---------------------------------------------------------------------------
// k_prep: fused (a) node1: h = x@lin1a/5 (padded 28/row), sc1 = x@sc1_w/5;
//               (b) r-table build: tab[s][128] = {w1(r_s)*FS1 in 4 chunks of
//                   25 padded to 28 at bases 0/28/56/84, w2(r_s)*FS2 at 112};
//               (c) zero scalsum+midsum (832 floats).
// Both MLPs are functions of the scalar r only -> tabulate, lerp in edge pass.
// ---------------------------------------------------------------------------
__global__ void __launch_bounds__(256, 4) k_prep(
    const float* __restrict__ wt_x, const float* __restrict__ mt_x,
    const float* __restrict__ lin1a, const float* __restrict__ sc1w,
    const float* __restrict__ fc1w1, const float* __restrict__ fc1w2,
    const float* __restrict__ fc2w1, const float* __restrict__ fc2w2,
    float* __restrict__ h, float* __restrict__ sc1,
    float* __restrict__ tab, float* __restrict__ zacc)
{
  const int blk = blockIdx.x;
  if (blk < 32) {
    // ---- node1 ----
    int i = blk * 256 + threadIdx.x;
    const float* xp = (i < NH_) ? (wt_x + i * 25) : (mt_x + (i - NH_) * 25);
    float xr[25];
    UN<25>([&](auto m){ xr[m.v] = xp[m.v]; });
    float ah[25], as[16];
    UN<25>([&](auto j){ ah[j.v] = 0.f; });
    UN<16>([&](auto j){ as[j.v] = 0.f; });
    UN<25>([&](auto m){
      float xm = xr[m.v];
      UN<25>([&](auto j){ ah[j.v] = fmaf(xm, lin1a[m.v * 25 + j.v], ah[j.v]); });
      UN<16>([&](auto j){ as[j.v] = fmaf(xm, sc1w[m.v * 16 + j.v], as[j.v]); });
    });
    UN<25>([&](auto j){ h[i * 28 + j.v] = 0.2f * ah[j.v]; });
    UN<16>([&](auto j){ sc1[i * 16 + j.v] = 0.2f * as[j.v]; });
  } else if (blk < 48) {
    // ---- table build: wave = part p (0..3), lane = sample within 64 ----
    const int lane = threadIdx.x & 63;
    const int p = __builtin_amdgcn_readfirstlane(threadIdx.x >> 6);
    const int s = (blk - 32) * 64 + lane;
    const float r = (float)s * (RT / (float)(TS - 1));
    float emb[10];
    make_emb(r, emb);
    const float FS1 = 0.003125f;   // (1/sqrt(128))*(1/sqrt(32))*(1/5)
    const float FS2 = 0.015625f;   // (1/sqrt(128))*(1/sqrt(32))
    if (p < 3) {
      const int cb = p * 25;       // fc1_w2 channel base (uniform)
      float acc[25];
      UN<25>([&](auto c){ acc[c.v] = 0.f; });
#pragma unroll 2
      for (int k = 0; k < 128; ++k) {
        float hk = 0.f;
        UN<10>([&](auto j){ hk = fmaf(emb[j.v], fc1w1[j.v * 128 + k], hk); });
        float sS = hk * sigmoidf_(hk);
        UN<25>([&](auto c){ acc[c.v] = fmaf(sS, fc1w2[k * 100 + cb + c.v], acc[c.v]); });
      }
      float* trow = tab + s * 128 + p * 28;
      UN<25>([&](auto c){ trow[c.v] = acc[c.v] * FS1; });
    } else {
      float acc[25], a2[16];
      UN<25>([&](auto c){ acc[c.v] = 0.f; });
      UN<16>([&](auto c){ a2[c.v] = 0.f; });
#pragma unroll 2
      for (int k = 0; k < 128; ++k) {
        float hk1 = 0.f, hk2 = 0.f;
        UN<10>([&](auto j){
          hk1 = fmaf(emb[j.v], fc1w1[j.v * 128 + k], hk1);
          hk2 = fmaf(emb[j.v], fc2w1[j.v * 128 + k], hk2);
        });
        float s1 = hk1 * sigmoidf_(hk1);
        float s2 = hk2 * sigmoidf_(hk2);
        UN<25>([&](auto c){ acc[c.v] = fmaf(s1, fc1w2[k * 100 + 75 + c.v], acc[c.v]); });
        UN<16>([&](auto c){ a2[c.v]  = fmaf(s2, fc2w2[k * 16 + c.v],       a2[c.v]); });
      }
      float* trow = tab + s * 128;
      UN<25>([&](auto c){ trow[84 + c.v]  = acc[c.v] * FS1; });
      UN<16>([&](auto c){ trow[112 + c.v] = a2[c.v]  * FS2; });
    }
  } else {
    for (int z = threadIdx.x; z < 832; z += 256) zacc[z] = 0.f;
  }
}

// ---------------------------------------------------------------------------
// edge pass 1: r -> table lerp (w1, FS-folded) -> project with l2a* (uniform
// s_loads) -> LDS tile atomics -> partial tile store. One block per
// quarter-group; wave-pair covers 64 edges; halfu = (wv>>2)&1 interleaves the
// heavy (L0) and light (L2/L3) waves across SIMDs.
// ---------------------------------------------------------------------------
__global__ void __launch_bounds__(1024, 4) k_edge1(
    const float* __restrict__ wt_pos, const float* __restrict__ mt_pos,
    const int* __restrict__ esrc, const int* __restrict__ edst,
    const float* __restrict__ tab, const float* __restrict__ h,
    const float* __restrict__ l2a0, const float* __restrict__ l2a1,
    const float* __restrict__ l2a2, const float* __restrict__ l2a3,
    float* __restrict__ Apart)
{
  __shared__ float lacc[128 * 42];
  const int tid = threadIdx.x;
  const int lane = tid & 63;
  const int wv = tid >> 6;                                    // 0..15
  const int halfu = __builtin_amdgcn_readfirstlane((wv >> 2) & 1);
  const int pi = (wv & 3) | ((wv >> 3) << 2);                 // pair index 0..7
  const int g = blockIdx.x >> 2;
  const int q = blockIdx.x & 3;

  for (int z = tid; z < 128 * 42; z += 1024) lacc[z] = 0.f;
  __syncthreads();

#pragma unroll 1
  for (int pass = 0; pass < 2; ++pass) {
    const int e = g * 4096 + q * 1024 + pass * 512 + pi * 64 + lane;
    const int src = esrc[e], dst = edst[e];
    float vx, vy, vz, r;
    edge_vec(wt_pos, mt_pos, src, dst, vx, vy, vz, r);
    float tt = fminf(r * ((float)(TS - 1) / RT), (float)(TS - 2) + 0.99f);
    int ti = (int)tt;
    float fr = tt - (float)ti;
    const float4* r0 = (const float4*)(tab + ti * 128 + halfu * 56);
    const float4* r1 = (const float4*)(tab + (ti + 1) * 128 + halfu * 56);
    const float4* hp = (const float4*)(h + src * 28);
    float4 hv[7];
    UN<7>([&](auto j){ hv[j.v] = hp[j.v]; });
    float sh[16];
    make_sh(vx, vy, vz, r, sh);
    float* Ad = lacc + (dst & 127) * 42;

    float T[25];
    // ---- chunk A (table base +0) ----
    UN<7>([&](auto j){
      float4 w0 = r0[j.v], w1 = r1[j.v];
      UN<4>([&](auto k){
        constexpr int c = j.v * 4 + k.v;
        if constexpr (c < 25) {
          float a = f4c<k.v>(w0), b = f4c<k.v>(w1);
          T[c] = f4get<c>(hv) * fmaf(fr, b - a, a);
        }
      });
    });
    if (halfu == 0) {
      UN<16>([&](auto v){
        float p = 0.f;
        UN<25>([&](auto m){ p = fmaf(T[m.v], l2a0[m.v * 16 + v.v], p); });
        atomicAdd(Ad + v.v, p);
      });
    } else {
      UN<2>([&](auto v){
        float p = 0.f;
        UN<25>([&](auto m){ p = fmaf(T[m.v], l2a2[m.v * 2 + v.v], p); });
        UN<5>([&](auto m){ atomicAdd(Ad + 25 + v.v * 5 + m.v, p * sh[4 + m.v]); });
      });
    }
    // ---- chunk B (table base +28 floats = +7 float4) ----
    UN<7>([&](auto j){
      float4 w0 = r0[7 + j.v], w1 = r1[7 + j.v];
      UN<4>([&](auto k){
        constexpr int c = j.v * 4 + k.v;
        if constexpr (c < 25) {
          float a = f4c<k.v>(w0), b = f4c<k.v>(w1);
          T[c] = f4get<c>(hv) * fmaf(fr, b - a, a);
        }
      });
    });
    if (halfu == 0) {
      UN<3>([&](auto v){
        float p = 0.f;
        UN<25>([&](auto m){ p = fmaf(T[m.v], l2a1[m.v * 3 + v.v], p); });
        UN<3>([&](auto m){ atomicAdd(Ad + 16 + v.v * 3 + m.v, p * sh[1 + m.v]); });
      });
    } else {
      float p = 0.f;
      UN<25>([&](auto m){ p = fmaf(T[m.v], l2a3[m.v], p); });
      UN<7>([&](auto m){ atomicAdd(Ad + 35 + m.v, p * sh[9 + m.v]); });
    }
  }

  __syncthreads();
  float* out = Apart + (size_t)blockIdx.x * (128 * 42);
  for (int z = tid; z < 128 * 42; z += 1024) out[z] = lacc[z];
}

// per-node stage 2: sum 4 partial tiles -> gates/scal -> h0..h3 (36) + group scal sums
__global__ void __launch_bounds__(256, 4) k_node2(
    const float* __restrict__ Apart, const float* __restrict__ sc1,
    const float* __restrict__ l1b0, const float* __restrict__ l1b1,
    const float* __restrict__ l1b2, const float* __restrict__ l1b3,
    float* __restrict__ nodeH, float* __restrict__ scalsum)
{
  int i = blockIdx.x * 256 + threadIdx.x;
  const float* Ap = Apart + (size_t)(i >> 7) * 4 * (128 * 42) + (i & 127) * 42;
  float Ai[42];
  UN<42>([&](auto c){
    Ai[c.v] = (Ap[c.v] + Ap[128 * 42 + c.v]) + (Ap[2 * 128 * 42 + c.v] + Ap[3 * 128 * 42 + c.v]);
  });
  const float CS_ = 0.38268343236509f, CX_ = 0.92387953251129f;
  float scal[10], gate[6];
  UN<10>([&](auto c){
    float s = CS_ * sc1[i * 16 + c.v] + CX_ * Ai[c.v];
    scal[c.v] = s * sigmoidf_(s);
  });
  UN<6>([&](auto c){
    float s = CS_ * sc1[i * 16 + 10 + c.v] + CX_ * Ai[10 + c.v];
    gate[c.v] = sigmoidf_(s);
  });
  float* out = nodeH + i * 36;
  UN<10>([&](auto v){
    float a = 0.f;
    UN<10>([&](auto u){ a = fmaf(scal[u.v], l1b0[u.v * 10 + v.v], a); });
    out[v.v] = a * 0.31622776601684f;   // /sqrt(10)
  });
  UN<3>([&](auto v){
    UN<3>([&](auto m){
      float a = 0.f;
      UN<3>([&](auto u){ a = fmaf(Ai[16 + u.v * 3 + m.v] * gate[u.v], l1b1[u.v * 3 + v.v], a); });
      out[10 + v.v * 3 + m.v] = a * 0.57735026918963f;  // /sqrt(3)
    });
  });
  UN<2>([&](auto v){
    UN<5>([&](auto m){
      float a = 0.f;
      UN<2>([&](auto u){ a = fmaf(Ai[25 + u.v * 5 + m.v] * gate[3 + u.v], l1b2[u.v * 2 + v.v], a); });
      out[19 + v.v * 5 + m.v] = a * 0.70710678118655f;  // /sqrt(2)
    });
  });
  float b3 = l1b3[0];
  UN<7>([&](auto m){ out[29 + m.v] = Ai[35 + m.v] * gate[5] * b3; });

  // group sums of scal (wave covers 64 consecutive nodes -> single group)
  int g = (i >> 7) & 31;
  int lane = threadIdx.x & 63;
  UN<10>([&](auto c){
    float v = wave_sum(scal[c.v]);
    if (lane == 0) atomicAdd(&scalsum[g * 10 + c.v], v);
  });
}

// edge pass 2: r -> table lerp (w2, 1/64 folded) -> e0..e3 -> group mid sums
__global__ void __launch_bounds__(256, 4) k_edge2(
    const float* __restrict__ wt_pos, const float* __restrict__ mt_pos,
    const int* __restrict__ esrc, const int* __restrict__ edst,
    const float* __restrict__ tab, const float* __restrict__ nodeH,
    float* __restrict__ midsum)
{
  int e = blockIdx.x * 256 + threadIdx.x;
  int src = esrc[e], dst = edst[e];
  float vx, vy, vz, r;
  edge_vec(wt_pos, mt_pos, src, dst, vx, vy, vz, r);
  float tt = fminf(r * ((float)(TS - 1) / RT), (float)(TS - 2) + 0.99f);
  int ti = (int)tt;
  float fr = tt - (float)ti;
  const float4* r0 = (const float4*)(tab + ti * 128 + 112);
  const float4* r1 = (const float4*)(tab + (ti + 1) * 128 + 112);
  float acc[16];
  UN<4>([&](auto j){
    float4 w0 = r0[j.v], w1 = r1[j.v];
    UN<4>([&](auto k){
      constexpr int c = j.v * 4 + k.v;
      float a = f4c<k.v>(w0), b = f4c<k.v>(w1);
      acc[c] = fmaf(fr, b - a, a);
    });
  });

  float sh[16];
  make_sh(vx, vy, vz, r, sh);

  const float4* Hp = (const float4*)(nodeH + src * 36);
  float4 Hv[9];
  UN<9>([&](auto j){ Hv[j.v] = Hp[j.v]; });

  float ev[16];
  UN<10>([&](auto c){ ev[c.v] = f4get<c.v>(Hv) * acc[c.v]; });
  UN<3>([&](auto u){
    float d = 0.f;
    UN<3>([&](auto m){ d = fmaf(f4get<10 + u.v * 3 + m.v>(Hv), sh[1 + m.v], d); });
    ev[10 + u.v] = d * 0.57735026918963f * acc[10 + u.v];
  });
  UN<2>([&](auto u){
    float d = 0.f;
    UN<5>([&](auto m){ d = fmaf(f4get<19 + u.v * 5 + m.v>(Hv), sh[4 + m.v], d); });
    ev[13 + u.v] = d * 0.44721359549996f * acc[13 + u.v];
  });
  {
    float d = 0.f;
    UN<7>([&](auto m){ d = fmaf(f4get<29 + m.v>(Hv), sh[9 + m.v], d); });
    ev[15] = d * 0.37796447300923f * acc[15];
  }

  // group accumulate: all 64 lanes of a wave share the dst block -> same group
  int g = (dst >> 7) & 31;
  int lane = threadIdx.x & 63;
  UN<16>([&](auto c){
    float v = wave_sum(ev[c.v]);   // scales folded into table
    if (lane == 0) atomicAdd(&midsum[g * 16 + c.v], v);
  });
}

// finale: fold head through sc2_w / lin2b, one block
__global__ void k_final(const float* __restrict__ sc2w, const float* __restrict__ lin2b,
                        const float* __restrict__ headw, const float* __restrict__ headb,
                        const float* __restrict__ scalsum, const float* __restrict__ midsum,
                        float* __restrict__ out)
{
  __shared__ float WA[20];  // (10,2) = sc2_w @ head_w
  __shared__ float WB[32];  // (16,2) = lin2b @ head_w
  int t = threadIdx.x;
  if (t < 20) {
    int j = t >> 1, o = t & 1;
    float a = 0.f;
    for (int c = 0; c < 256; ++c) a += sc2w[j * 256 + c] * headw[c * 2 + o];
    WA[t] = a;
  } else if (t < 52) {
    int q = t - 20, j = q >> 1, o = q & 1;
    float a = 0.f;
    for (int c = 0; c < 256; ++c) a += lin2b[j * 256 + c] * headw[c * 2 + o];
    WB[q] = a;
  }
  __syncthreads();
  if (t < 64) {
    int g = t & 31, o = t >> 5;
    float a = 0.f;
    for (int j = 0; j < 10; ++j) a += scalsum[g * 10 + j] * WA[j * 2 + o];
    float b = 0.f;
    for (int j = 0; j < 16; ++j) b += midsum[g * 16 + j] * WB[j * 2 + o];
    float y = a * (0.38268343236509f * 0.31622776601684f)   // CS * 1/sqrt(10)
            + b * (0.92387953251129f * 0.25f);              // CX * 1/4
    out[o * 32 + g] = y * (1.0f / 256.0f) + headb[o];
  }
}

extern "C" void kernel_launch(void* const* d_in, const int* in_sizes, int n_in,
                              void* d_out, int out_size, void* d_ws, size_t ws_size,
                              hipStream_t stream)
{
  float* ws = (float*)d_ws;
  const float* wt_pos = (const float*)d_in[0];
  const float* mt_pos = (const float*)d_in[1];
  const float* wt_x   = (const float*)d_in[2];
  const float* mt_x   = (const float*)d_in[3];
  const int* esrc     = (const int*)d_in[6];
  const int* edst     = (const int*)d_in[7];
  const float* sc1w   = (const float*)d_in[8];
  const float* lin1a  = (const float*)d_in[9];
  const float* fc1w1  = (const float*)d_in[10];
  const float* fc1w2  = (const float*)d_in[11];
  const float* l2a0   = (const float*)d_in[12];
  const float* l2a1   = (const float*)d_in[13];
  const float* l2a2   = (const float*)d_in[14];
  const float* l2a3   = (const float*)d_in[15];
  const float* sc2w   = (const float*)d_in[16];
  const float* l1b0   = (const float*)d_in[17];
  const float* l1b1   = (const float*)d_in[18];
  const float* l1b2   = (const float*)d_in[19];
  const float* l1b3   = (const float*)d_in[20];
  const float* fc2w1  = (const float*)d_in[21];
  const float* fc2w2  = (const float*)d_in[22];
  const float* lin2b  = (const float*)d_in[23];
  const float* headw  = (const float*)d_in[24];
  const float* headb  = (const float*)d_in[25];

  float* h       = ws + OFF_H;
  float* sc1     = ws + OFF_SC1;
  float* nodeH   = ws + OFF_NODEH;
  float* scalsum = ws + OFF_SCALS;
  float* midsum  = ws + OFF_MIDS;
  float* tab     = ws + OFF_TAB;
  float* Apart   = ws + OFF_APART;

  k_prep<<<49, 256, 0, stream>>>(wt_x, mt_x, lin1a, sc1w, fc1w1, fc1w2, fc2w1, fc2w2,
                                 h, sc1, tab, scalsum);
  k_edge1<<<256, 1024, 0, stream>>>(wt_pos, mt_pos, esrc, edst, tab, h,
                                    l2a0, l2a1, l2a2, l2a3, Apart);
  k_node2<<<NNODE / 256, 256, 0, stream>>>(Apart, sc1, l1b0, l1b1, l1b2, l1b3,
                                           nodeH, scalsum);
  k_edge2<<<NEDGE / 256, 256, 0, stream>>>(wt_pos, mt_pos, esrc, edst, tab, nodeH, midsum);
  k_final<<<1, 256, 0, stream>>>(sc2w, lin2b, headw, headb, scalsum, midsum, (float*)d_out);
}

// Round 7
// 143.238 us; speedup vs baseline: 6.0847x; 1.3125x over previous
//
#include <hip/hip_runtime.h>

#define NH_   4096
#define NNODE 8192
#define NEDGE 262144
#define TS    4096
#define RT    17.4f
#define RIDX  (((float)(TS - 1)) / RT)

// ---- workspace layout (float offsets) ----
#define OFF_H      0        // 8192*28 = 229376 (h padded to 28/row for float4)
#define OFF_SC1    229376   // 8192*16 = 131072
#define OFF_NODEH  360448   // 8192*36 = 294912
#define OFF_SCALS  655360   // 32*10 = 320
#define OFF_MIDS   655680   // 32*16 = 512   (contiguous with SCALS: 832 total)
#define OFF_TAB    656384   // 4096*128 = 524288  (r-table, FS pre-folded)
#define OFF_APART  1180672  // 256 blocks * 128*44 = 1441792 partial tiles
// total ~2.62M floats = 10.5 MB

// ---- compile-time unroll: every private-array index is a constant at IR-gen
// time so early SROA promotes arrays to registers. ----
template <int I> struct ic { static constexpr int v = I; };
template <int N, typename F>
__device__ __forceinline__ void UN(F&& f) {
  if constexpr (N > 0) { UN<N - 1>(f); f(ic<N - 1>{}); }
}

template <int K>
__device__ __forceinline__ float f4c(float4 v) {
  if constexpr (K == 0) return v.x;
  else if constexpr (K == 1) return v.y;
  else if constexpr (K == 2) return v.z;
  else return v.w;
}
template <int C>
__device__ __forceinline__ float f4get(const float4* v) {
  return f4c<C & 3>(v[C >> 2]);
}

__device__ __forceinline__ float sigmoidf_(float v) { return 1.0f / (1.0f + __expf(-v)); }

// ---- butterfly-compacting multi-channel wave reduction ----
// Input: v[C] per lane (C power of 2, <= 32). After call, returns the
// full-wave (64-lane) sum of channel (lane & (C-1)).
template <int C, int B>
__device__ __forceinline__ void cred_rec(float* a, int lane) {
  if constexpr ((1 << B) < C) {
    const bool hi = (lane >> B) & 1;
    constexpr int n = C >> (B + 1);
    UN<n>([&](auto j){
      float s0 = a[2 * j.v], s1 = a[2 * j.v + 1];
      float send = hi ? s0 : s1;
      float recv = __shfl_xor(send, 1 << B);
      a[j.v] = (hi ? s1 : s0) + recv;
    });
    cred_rec<C, B + 1>(a, lane);
  }
}
template <int C>
__device__ __forceinline__ float creduce(float* v, int lane) {
  cred_rec<C, 0>(v, lane);
  float s = v[0];
#pragma unroll
  for (int m = C; m < 64; m <<= 1) s += __shfl_xor(s, m);
  return s;
}

// embs = exp(-((r-c)/step)^2)   [sqrt(NB) * 1/sqrt(NB) folded out]
__device__ __forceinline__ void make_emb(float r, float* embs) {
  float rb = r * 0.45f;
  UN<10>([&](auto b){ float d = rb - (float)b.v; embs[b.v] = __expf(-d * d); });
}

__device__ __forceinline__ void edge_vec(
    const float* __restrict__ wt_pos, const float* __restrict__ mt_pos,
    int src, int dst, float& vx, float& vy, float& vz, float& r)
{
  const float* ps = (src < NH_) ? (wt_pos + src * 3) : (mt_pos + (src - NH_) * 3);
  const float* pd = (dst < NH_) ? (wt_pos + dst * 3) : (mt_pos + (dst - NH_) * 3);
  vx = ps[0] - pd[0];
  vy = ps[1] - pd[1];
  vz = ps[2] - pd[2];
  r = sqrtf(vx * vx + vy * vy + vz * vz);
}

__device__ __forceinline__ void make_sh(float vx, float vy, float vz, float r, float* sh) {
  float rinv = 1.0f / fmaxf(r, 1e-9f);
  float x = vx * rinv, y = vy * rinv, z = vz * rinv;
  float x2 = x * x, y2 = y * y, z2 = z * z;
  float shA = 3.87298334620742f * x * z;             // s15*x*z
  float shB = 1.93649167310371f * (z2 - x2);         // 0.5*s15*(z2-x2)
  sh[0] = 1.f;
  sh[1] = 1.73205080756888f * x;
  sh[2] = 1.73205080756888f * y;
  sh[3] = 1.73205080756888f * z;
  sh[4] = shA;
  sh[5] = 3.87298334620742f * x * y;
  sh[6] = 2.23606797749979f * (y2 - 0.5f * (x2 + z2));
  sh[7] = 3.87298334620742f * y * z;
  sh[8] = shB;
  sh[9]  = 1.08012344973464f * (shA * z + shB * x);
  sh[10] = 2.64575131106459f * shA * y;
  sh[11] = 1.62018517460197f * (4.f * y2 - x2 - z2) * x;
  sh[12] = 1.32287565553230f * y * (2.f * y2 - 3.f * x2 - 3.f * z2);
  sh[13] = 1.62018517460197f * z * (4.f * y2 - x2 - z2);
  sh[14] = 2.64575131106459f * shB * y;
  sh[15] = 1.08012344973464f * (shB * z - shA * x);
}

// ---------------------------------------------------------------------------
// k_prep: (a) node1: h = x@lin1a/5 (pad 28), sc1 = x@sc1_w/5;
//         (b) r-table: tab[s][128] = {w1(r_s)*FS1, chunks 25->28 at 0/28/56/84,
//             w2(r_s)*FS2 at 112}; TS=4096 samples;
//         (c) zero scalsum+midsum.
// ---------------------------------------------------------------------------
__global__ void __launch_bounds__(256, 4) k_prep(
    const float* __restrict__ wt_x, const float* __restrict__ mt_x,
    const float* __restrict__ lin1a, const float* __restrict__ sc1w,
    const float* __restrict__ fc1w1, const float* __restrict__ fc1w2,
    const float* __restrict__ fc2w1, const float* __restrict__ fc2w2,
    float* __restrict__ h, float* __restrict__ sc1,
    float* __restrict__ tab, float* __restrict__ zacc)
{
  const int blk = blockIdx.x;
  if (blk < 32) {
    // ---- node1 ----
    int i = blk * 256 + threadIdx.x;
    const float* xp = (i < NH_) ? (wt_x + i * 25) : (mt_x + (i - NH_) * 25);
    float xr[25];
    UN<25>([&](auto m){ xr[m.v] = xp[m.v]; });
    float ah[25], as[16];
    UN<25>([&](auto j){ ah[j.v] = 0.f; });
    UN<16>([&](auto j){ as[j.v] = 0.f; });
    UN<25>([&](auto m){
      float xm = xr[m.v];
      UN<25>([&](auto j){ ah[j.v] = fmaf(xm, lin1a[m.v * 25 + j.v], ah[j.v]); });
      UN<16>([&](auto j){ as[j.v] = fmaf(xm, sc1w[m.v * 16 + j.v], as[j.v]); });
    });
    UN<25>([&](auto j){ h[i * 28 + j.v] = 0.2f * ah[j.v]; });
    UN<16>([&](auto j){ sc1[i * 16 + j.v] = 0.2f * as[j.v]; });
  } else if (blk < 96) {
    // ---- table build: wave = part p (0..3), lane = sample within 64 ----
    const int lane = threadIdx.x & 63;
    const int p = __builtin_amdgcn_readfirstlane(threadIdx.x >> 6);
    const int s = (blk - 32) * 64 + lane;
    const float r = (float)s * (RT / (float)(TS - 1));
    float emb[10];
    make_emb(r, emb);
    const float FS1 = 0.003125f;   // (1/sqrt(128))*(1/sqrt(32))*(1/5)
    const float FS2 = 0.015625f;   // (1/sqrt(128))*(1/sqrt(32))
    if (p < 3) {
      const int cb = p * 25;       // fc1_w2 channel base (uniform)
      float acc[25];
      UN<25>([&](auto c){ acc[c.v] = 0.f; });
#pragma unroll 2
      for (int k = 0; k < 128; ++k) {
        float hk = 0.f;
        UN<10>([&](auto j){ hk = fmaf(emb[j.v], fc1w1[j.v * 128 + k], hk); });
        float sS = hk * sigmoidf_(hk);
        UN<25>([&](auto c){ acc[c.v] = fmaf(sS, fc1w2[k * 100 + cb + c.v], acc[c.v]); });
      }
      float* trow = tab + s * 128 + p * 28;
      UN<25>([&](auto c){ trow[c.v] = acc[c.v] * FS1; });
    } else {
      float acc[25], a2[16];
      UN<25>([&](auto c){ acc[c.v] = 0.f; });
      UN<16>([&](auto c){ a2[c.v] = 0.f; });
#pragma unroll 2
      for (int k = 0; k < 128; ++k) {
        float hk1 = 0.f, hk2 = 0.f;
        UN<10>([&](auto j){
          hk1 = fmaf(emb[j.v], fc1w1[j.v * 128 + k], hk1);
          hk2 = fmaf(emb[j.v], fc2w1[j.v * 128 + k], hk2);
        });
        float s1 = hk1 * sigmoidf_(hk1);
        float s2 = hk2 * sigmoidf_(hk2);
        UN<25>([&](auto c){ acc[c.v] = fmaf(s1, fc1w2[k * 100 + 75 + c.v], acc[c.v]); });
        UN<16>([&](auto c){ a2[c.v]  = fmaf(s2, fc2w2[k * 16 + c.v],       a2[c.v]); });
      }
      float* trow = tab + s * 128;
      UN<25>([&](auto c){ trow[84 + c.v]  = acc[c.v] * FS1; });
      UN<16>([&](auto c){ trow[112 + c.v] = a2[c.v]  * FS2; });
    }
  } else {
    for (int z = threadIdx.x; z < 832; z += 256) zacc[z] = 0.f;
  }
}

// ---------------------------------------------------------------------------
// edge pass 1: r -> nearest table row (FS folded) -> incremental projection
// through l2a* (uniform s_loads) -> LDS tile atomics -> partial tile store.
// Single wave per 64 edges; one block per quarter-group (16 waves x 64 = 1024
// edges, all dst in one 128-node tile).
// ---------------------------------------------------------------------------
__global__ void __launch_bounds__(1024, 4) k_edge1(
    const float* __restrict__ wt_pos, const float* __restrict__ mt_pos,
    const int* __restrict__ esrc, const int* __restrict__ edst,
    const float* __restrict__ tab, const float* __restrict__ h,
    const float* __restrict__ l2a0, const float* __restrict__ l2a1,
    const float* __restrict__ l2a2, const float* __restrict__ l2a3,
    float* __restrict__ Apart)
{
  __shared__ float lacc[128 * 44];
  const int tid = threadIdx.x;

  {
    float4* l4 = (float4*)lacc;
    for (int z = tid; z < 128 * 11; z += 1024) l4[z] = make_float4(0.f, 0.f, 0.f, 0.f);
  }
  __syncthreads();

  const int e = blockIdx.x * 1024 + tid;
  const int src = esrc[e], dst = edst[e];
  float vx, vy, vz, r;
  edge_vec(wt_pos, mt_pos, src, dst, vx, vy, vz, r);
  int ti = (int)(r * RIDX + 0.5f);
  ti = min(ti, TS - 1);
  const float4* wrow = (const float4*)(tab + ti * 128);
  const float4* hp = (const float4*)(h + src * 28);
  float4 hq[7];
  UN<7>([&](auto j){ hq[j.v] = hp[j.v]; });
  float sh[16];
  make_sh(vx, vy, vz, r, sh);
  float* Ad = lacc + (dst & 127) * 44;

  // chunk 0 -> l2a0 (16 outs)
  {
    float p0[16];
    UN<16>([&](auto v){ p0[v.v] = 0.f; });
    UN<7>([&](auto j){
      float4 w = wrow[j.v];
      UN<4>([&](auto k){
        constexpr int c = j.v * 4 + k.v;
        if constexpr (c < 25) {
          float t = f4get<c>(hq) * f4c<k.v>(w);
          UN<16>([&](auto v){ p0[v.v] = fmaf(t, l2a0[c * 16 + v.v], p0[v.v]); });
        }
      });
    });
    UN<16>([&](auto v){ atomicAdd(Ad + v.v, p0[v.v]); });
  }
  // chunk 1 -> l2a1 (3 outs x sh[1..3])
  {
    float p1[3];
    UN<3>([&](auto v){ p1[v.v] = 0.f; });
    UN<7>([&](auto j){
      float4 w = wrow[7 + j.v];
      UN<4>([&](auto k){
        constexpr int c = j.v * 4 + k.v;
        if constexpr (c < 25) {
          float t = f4get<c>(hq) * f4c<k.v>(w);
          UN<3>([&](auto v){ p1[v.v] = fmaf(t, l2a1[c * 3 + v.v], p1[v.v]); });
        }
      });
    });
    UN<3>([&](auto v){
      UN<3>([&](auto m){ atomicAdd(Ad + 16 + v.v * 3 + m.v, p1[v.v] * sh[1 + m.v]); });
    });
  }
  // chunk 2 -> l2a2 (2 outs x sh[4..8])
  {
    float p2[2];
    p2[0] = 0.f; p2[1] = 0.f;
    UN<7>([&](auto j){
      float4 w = wrow[14 + j.v];
      UN<4>([&](auto k){
        constexpr int c = j.v * 4 + k.v;
        if constexpr (c < 25) {
          float t = f4get<c>(hq) * f4c<k.v>(w);
          UN<2>([&](auto v){ p2[v.v] = fmaf(t, l2a2[c * 2 + v.v], p2[v.v]); });
        }
      });
    });
    UN<2>([&](auto v){
      UN<5>([&](auto m){ atomicAdd(Ad + 25 + v.v * 5 + m.v, p2[v.v] * sh[4 + m.v]); });
    });
  }
  // chunk 3 -> l2a3 (1 out x sh[9..15])
  {
    float p3 = 0.f;
    UN<7>([&](auto j){
      float4 w = wrow[21 + j.v];
      UN<4>([&](auto k){
        constexpr int c = j.v * 4 + k.v;
        if constexpr (c < 25) {
          float t = f4get<c>(hq) * f4c<k.v>(w);
          p3 = fmaf(t, l2a3[c], p3);
        }
      });
    });
    UN<7>([&](auto m){ atomicAdd(Ad + 35 + m.v, p3 * sh[9 + m.v]); });
  }

  __syncthreads();
  {
    const float4* l4 = (const float4*)lacc;
    float4* out = (float4*)(Apart + (size_t)blockIdx.x * (128 * 44));
    for (int z = tid; z < 128 * 11; z += 1024) out[z] = l4[z];
  }
}

// per-node stage 2: sum 4 partial tiles (float4) -> gates/scal -> h0..h3 -> group scal sums
__global__ void __launch_bounds__(256, 4) k_node2(
    const float* __restrict__ Apart, const float* __restrict__ sc1,
    const float* __restrict__ l1b0, const float* __restrict__ l1b1,
    const float* __restrict__ l1b2, const float* __restrict__ l1b3,
    float* __restrict__ nodeH, float* __restrict__ scalsum)
{
  int i = blockIdx.x * 256 + threadIdx.x;
  const float4* A0 = (const float4*)(Apart + (size_t)(i >> 7) * (4 * 128 * 44) + (i & 127) * 44);
  float Ai[44];
  UN<11>([&](auto j){
    float4 a = A0[j.v], b = A0[j.v + 1408], c = A0[j.v + 2816], d = A0[j.v + 4224];
    Ai[j.v * 4 + 0] = (a.x + b.x) + (c.x + d.x);
    Ai[j.v * 4 + 1] = (a.y + b.y) + (c.y + d.y);
    Ai[j.v * 4 + 2] = (a.z + b.z) + (c.z + d.z);
    Ai[j.v * 4 + 3] = (a.w + b.w) + (c.w + d.w);
  });
  const float CS_ = 0.38268343236509f, CX_ = 0.92387953251129f;
  float scal[16], gate[6];
  UN<10>([&](auto c){
    float s = CS_ * sc1[i * 16 + c.v] + CX_ * Ai[c.v];
    scal[c.v] = s * sigmoidf_(s);
  });
  UN<6>([&](auto c){
    float s = CS_ * sc1[i * 16 + 10 + c.v] + CX_ * Ai[10 + c.v];
    gate[c.v] = sigmoidf_(s);
    scal[10 + c.v] = 0.f;   // pad channels for creduce<16>
  });
  float* out = nodeH + i * 36;
  UN<10>([&](auto v){
    float a = 0.f;
    UN<10>([&](auto u){ a = fmaf(scal[u.v], l1b0[u.v * 10 + v.v], a); });
    out[v.v] = a * 0.31622776601684f;   // /sqrt(10)
  });
  UN<3>([&](auto v){
    UN<3>([&](auto m){
      float a = 0.f;
      UN<3>([&](auto u){ a = fmaf(Ai[16 + u.v * 3 + m.v] * gate[u.v], l1b1[u.v * 3 + v.v], a); });
      out[10 + v.v * 3 + m.v] = a * 0.57735026918963f;  // /sqrt(3)
    });
  });
  UN<2>([&](auto v){
    UN<5>([&](auto m){
      float a = 0.f;
      UN<2>([&](auto u){ a = fmaf(Ai[25 + u.v * 5 + m.v] * gate[3 + u.v], l1b2[u.v * 2 + v.v], a); });
      out[19 + v.v * 5 + m.v] = a * 0.70710678118655f;  // /sqrt(2)
    });
  });
  float b3 = l1b3[0];
  UN<7>([&](auto m){ out[29 + m.v] = Ai[35 + m.v] * gate[5] * b3; });

  // group sums of scal via compacting tree (wave = 64 consecutive nodes = one group)
  int g = (i >> 7) & 31;
  int lane = threadIdx.x & 63;
  float s = creduce<16>(scal, lane);
  if (lane < 10) atomicAdd(&scalsum[g * 10 + lane], s);
}

// edge pass 2: nearest table (w2, scales folded) -> e0..e3 -> tree-reduced group mid sums
__global__ void __launch_bounds__(256, 4) k_edge2(
    const float* __restrict__ wt_pos, const float* __restrict__ mt_pos,
    const int* __restrict__ esrc, const int* __restrict__ edst,
    const float* __restrict__ tab, const float* __restrict__ nodeH,
    float* __restrict__ midsum)
{
  __shared__ float nh[288];   // 8 src rows x 36
  const int tid = threadIdx.x;
  const int blk = blockIdx.x;
  if (tid < 72) ((float4*)nh)[tid] = ((const float4*)(nodeH + blk * 288))[tid];
  __syncthreads();

  int e = blk * 256 + tid;
  int src = esrc[e], dst = edst[e];
  float vx, vy, vz, r;
  edge_vec(wt_pos, mt_pos, src, dst, vx, vy, vz, r);
  int ti = (int)(r * RIDX + 0.5f);
  ti = min(ti, TS - 1);
  const float4* wrow = (const float4*)(tab + ti * 128 + 112);
  float acc[16];
  UN<4>([&](auto j){
    float4 w = wrow[j.v];
    UN<4>([&](auto k){ acc[j.v * 4 + k.v] = f4c<k.v>(w); });
  });

  float sh[16];
  make_sh(vx, vy, vz, r, sh);

  const float4* Hp = (const float4*)(nh + (src & 7) * 36);
  float4 Hv[9];
  UN<9>([&](auto j){ Hv[j.v] = Hp[j.v]; });

  float ev[16];
  UN<10>([&](auto c){ ev[c.v] = f4get<c.v>(Hv) * acc[c.v]; });
  UN<3>([&](auto u){
    float d = 0.f;
    UN<3>([&](auto m){ d = fmaf(f4get<10 + u.v * 3 + m.v>(Hv), sh[1 + m.v], d); });
    ev[10 + u.v] = d * 0.57735026918963f * acc[10 + u.v];
  });
  UN<2>([&](auto u){
    float d = 0.f;
    UN<5>([&](auto m){ d = fmaf(f4get<19 + u.v * 5 + m.v>(Hv), sh[4 + m.v], d); });
    ev[13 + u.v] = d * 0.44721359549996f * acc[13 + u.v];
  });
  {
    float d = 0.f;
    UN<7>([&](auto m){ d = fmaf(f4get<29 + m.v>(Hv), sh[9 + m.v], d); });
    ev[15] = d * 0.37796447300923f * acc[15];
  }

  // group accumulate via compacting tree: one 16-lane atomic per wave
  int g = (dst >> 7) & 31;
  int lane = tid & 63;
  float s = creduce<16>(ev, lane);
  if (lane < 16) atomicAdd(&midsum[g * 16 + lane], s);
}

// finale: fold head through sc2_w / lin2b, one block
__global__ void k_final(const float* __restrict__ sc2w, const float* __restrict__ lin2b,
                        const float* __restrict__ headw, const float* __restrict__ headb,
                        const float* __restrict__ scalsum, const float* __restrict__ midsum,
                        float* __restrict__ out)
{
  __shared__ float WA[20];  // (10,2) = sc2_w @ head_w
  __shared__ float WB[32];  // (16,2) = lin2b @ head_w
  int t = threadIdx.x;
  if (t < 20) {
    int j = t >> 1, o = t & 1;
    float a = 0.f;
    for (int c = 0; c < 256; ++c) a += sc2w[j * 256 + c] * headw[c * 2 + o];
    WA[t] = a;
  } else if (t < 52) {
    int q = t - 20, j = q >> 1, o = q & 1;
    float a = 0.f;
    for (int c = 0; c < 256; ++c) a += lin2b[j * 256 + c] * headw[c * 2 + o];
    WB[q] = a;
  }
  __syncthreads();
  if (t < 64) {
    int g = t & 31, o = t >> 5;
    float a = 0.f;
    for (int j = 0; j < 10; ++j) a += scalsum[g * 10 + j] * WA[j * 2 + o];
    float b = 0.f;
    for (int j = 0; j < 16; ++j) b += midsum[g * 16 + j] * WB[j * 2 + o];
    float y = a * (0.38268343236509f * 0.31622776601684f)   // CS * 1/sqrt(10)
            + b * (0.92387953251129f * 0.25f);              // CX * 1/4
    out[o * 32 + g] = y * (1.0f / 256.0f) + headb[o];
  }
}

extern "C" void kernel_launch(void* const* d_in, const int* in_sizes, int n_in,
                              void* d_out, int out_size, void* d_ws, size_t ws_size,
                              hipStream_t stream)
{
  float* ws = (float*)d_ws;
  const float* wt_pos = (const float*)d_in[0];
  const float* mt_pos = (const float*)d_in[1];
  const float* wt_x   = (const float*)d_in[2];
  const float* mt_x   = (const float*)d_in[3];
  const int* esrc     = (const int*)d_in[6];
  const int* edst     = (const int*)d_in[7];
  const float* sc1w   = (const float*)d_in[8];
  const float* lin1a  = (const float*)d_in[9];
  const float* fc1w1  = (const float*)d_in[10];
  const float* fc1w2  = (const float*)d_in[11];
  const float* l2a0   = (const float*)d_in[12];
  const float* l2a1   = (const float*)d_in[13];
  const float* l2a2   = (const float*)d_in[14];
  const float* l2a3   = (const float*)d_in[15];
  const float* sc2w   = (const float*)d_in[16];
  const float* l1b0   = (const float*)d_in[17];
  const float* l1b1   = (const float*)d_in[18];
  const float* l1b2   = (const float*)d_in[19];
  const float* l1b3   = (const float*)d_in[20];
  const float* fc2w1  = (const float*)d_in[21];
  const float* fc2w2  = (const float*)d_in[22];
  const float* lin2b  = (const float*)d_in[23];
  const float* headw  = (const float*)d_in[24];
  const float* headb  = (const float*)d_in[25];

  float* h       = ws + OFF_H;
  float* sc1     = ws + OFF_SC1;
  float* nodeH   = ws + OFF_NODEH;
  float* scalsum = ws + OFF_SCALS;
  float* midsum  = ws + OFF_MIDS;
  float* tab     = ws + OFF_TAB;
  float* Apart   = ws + OFF_APART;

  k_prep<<<97, 256, 0, stream>>>(wt_x, mt_x, lin1a, sc1w, fc1w1, fc1w2, fc2w1, fc2w2,
                                 h, sc1, tab, scalsum);
  k_edge1<<<256, 1024, 0, stream>>>(wt_pos, mt_pos, esrc, edst, tab, h,
                                    l2a0, l2a1, l2a2, l2a3, Apart);
  k_node2<<<NNODE / 256, 256, 0, stream>>>(Apart, sc1, l1b0, l1b1, l1b2, l1b3,
                                           nodeH, scalsum);
  k_edge2<<<NEDGE / 256, 256, 0, stream>>>(wt_pos, mt_pos, esrc, edst, tab, nodeH, midsum);
  k_final<<<1, 256, 0, stream>>>(sc2w, lin2b, headw, headb, scalsum, midsum, (float*)d_out);
}

// Round 8
// 103.263 us; speedup vs baseline: 8.4402x; 1.3871x over previous
//
#include <hip/hip_runtime.h>

typedef unsigned int uint;

#define NH_   4096
#define NNODE 8192
#define NEDGE 262144
#define TS    4096
#define RT    17.4f
#define RIDX  (((float)(TS - 1)) / RT)

// ---- workspace layout (float offsets) ----
#define OFF_H      0        // 8192*28
#define OFF_SC1    229376   // 8192*16
#define OFF_NODEH  360448   // 8192*36
#define OFF_SCALS  655360   // 32*10
#define OFF_MIDS   655680   // 32*16  (contiguous with SCALS: 832)
#define OFF_TABU   656384   // 4096*64 uints (bf16-packed r-table, scales folded)
#define OFF_A      918528   // 8192*44
#define OFF_SSRC   1278976  // 262144 ints (src sorted by dst)
#define OFF_SOFF   1541120  // 8256 ints (CSR offsets by dst)

// ---- compile-time unroll ----
template <int I> struct ic { static constexpr int v = I; };
template <int N, typename F>
__device__ __forceinline__ void UN(F&& f) {
  if constexpr (N > 0) { UN<N - 1>(f); f(ic<N - 1>{}); }
}

template <int K>
__device__ __forceinline__ float f4c(float4 v) {
  if constexpr (K == 0) return v.x;
  else if constexpr (K == 1) return v.y;
  else if constexpr (K == 2) return v.z;
  else return v.w;
}
template <int C>
__device__ __forceinline__ float f4get(const float4* v) {
  return f4c<C & 3>(v[C >> 2]);
}
template <int K>
__device__ __forceinline__ uint u4c(uint4 v) {
  if constexpr (K == 0) return v.x;
  else if constexpr (K == 1) return v.y;
  else if constexpr (K == 2) return v.z;
  else return v.w;
}
// unpack bf16-pair channel CH from packed uint4 regs
template <int CH>
__device__ __forceinline__ float upk(const uint4* wr) {
  constexpr int pr = CH >> 1;
  uint u = u4c<pr & 3>(wr[pr >> 2]);
  if constexpr (CH & 1) return __uint_as_float(u & 0xffff0000u);
  else return __uint_as_float(u << 16);
}

__device__ __forceinline__ float sigmoidf_(float v) { return 1.0f / (1.0f + __expf(-v)); }

// full-wave compacting reduction: C channels -> channel (lane & (C-1))
template <int C, int B>
__device__ __forceinline__ void cred_rec(float* a, int lane) {
  if constexpr ((1 << B) < C) {
    const bool hi = (lane >> B) & 1;
    constexpr int n = C >> (B + 1);
    UN<n>([&](auto j){
      float s0 = a[2 * j.v], s1 = a[2 * j.v + 1];
      float send = hi ? s0 : s1;
      float recv = __shfl_xor(send, 1 << B);
      a[j.v] = (hi ? s1 : s0) + recv;
    });
    cred_rec<C, B + 1>(a, lane);
  }
}
template <int C>
__device__ __forceinline__ float creduce(float* v, int lane) {
  cred_rec<C, 0>(v, lane);
  float s = v[0];
#pragma unroll
  for (int m = C; m < 64; m <<= 1) s += __shfl_xor(s, m);
  return s;
}
// half-wave (32-lane) compacting reduction of 64 channels, 5 steps.
// After: a[0] = ch (lane&31), a[1] = ch 32+(lane&31), summed over the half.
template <int B>
__device__ __forceinline__ void cred32_rec(float* a, int lane) {
  if constexpr (B < 5) {
    const bool hi = (lane >> B) & 1;
    constexpr int n = 64 >> (B + 1);
    UN<n>([&](auto j){
      float s0 = a[2 * j.v], s1 = a[2 * j.v + 1];
      float send = hi ? s0 : s1;
      float recv = __shfl_xor(send, 1 << B);
      a[j.v] = (hi ? s1 : s0) + recv;
    });
    cred32_rec<B + 1>(a, lane);
  }
}

__device__ __forceinline__ void make_emb(float r, float* embs) {
  float rb = r * 0.45f;
  UN<10>([&](auto b){ float d = rb - (float)b.v; embs[b.v] = __expf(-d * d); });
}

__device__ __forceinline__ void make_sh(float vx, float vy, float vz, float r, float* sh) {
  float rinv = 1.0f / fmaxf(r, 1e-9f);
  float x = vx * rinv, y = vy * rinv, z = vz * rinv;
  float x2 = x * x, y2 = y * y, z2 = z * z;
  float shA = 3.87298334620742f * x * z;
  float shB = 1.93649167310371f * (z2 - x2);
  sh[0] = 1.f;
  sh[1] = 1.73205080756888f * x;
  sh[2] = 1.73205080756888f * y;
  sh[3] = 1.73205080756888f * z;
  sh[4] = shA;
  sh[5] = 3.87298334620742f * x * y;
  sh[6] = 2.23606797749979f * (y2 - 0.5f * (x2 + z2));
  sh[7] = 3.87298334620742f * y * z;
  sh[8] = shB;
  sh[9]  = 1.08012344973464f * (shA * z + shB * x);
  sh[10] = 2.64575131106459f * shA * y;
  sh[11] = 1.62018517460197f * (4.f * y2 - x2 - z2) * x;
  sh[12] = 1.32287565553230f * y * (2.f * y2 - 3.f * x2 - 3.f * z2);
  sh[13] = 1.62018517460197f * z * (4.f * y2 - x2 - z2);
  sh[14] = 2.64575131106459f * shB * y;
  sh[15] = 1.08012344973464f * (shB * z - shA * x);
}

// ---------------------------------------------------------------------------
// k_sortE: per-group counting sort of edges by dst. One block per group
// (4096 edges, 128 dst bins). Outputs ssrc (src sorted by dst) + soff (CSR).
// ---------------------------------------------------------------------------
__global__ void __launch_bounds__(1024, 2) k_sortE(
    const int* __restrict__ edst, int* __restrict__ ssrc, int* __restrict__ soff)
{
  __shared__ int hist[128];
  __shared__ int cnt[128];
  const int g = blockIdx.x;
  const int tid = threadIdx.x;
  if (tid < 128) hist[tid] = 0;
  __syncthreads();
  int dl[4];
  UN<4>([&](auto k){
    int e = g * 4096 + k.v * 1024 + tid;
    dl[k.v] = edst[e] & 127;
    atomicAdd(&hist[dl[k.v]], 1);
  });
  __syncthreads();
  if (tid < 64) {
    int s0 = hist[2 * tid], s1 = hist[2 * tid + 1];
    int ps = s0 + s1;
    int sum = ps;
#pragma unroll
    for (int m = 1; m < 64; m <<= 1) {
      int t = __shfl_up(sum, m);
      if (tid >= m) sum += t;
    }
    int excl = sum - ps;
    cnt[2 * tid] = excl;
    cnt[2 * tid + 1] = excl + s0;
    soff[g * 128 + 2 * tid] = g * 4096 + excl;
    soff[g * 128 + 2 * tid + 1] = g * 4096 + excl + s0;
  }
  if (g == 0 && tid == 1023) soff[NNODE] = NEDGE;
  __syncthreads();
  UN<4>([&](auto k){
    int e = g * 4096 + k.v * 1024 + tid;
    int slot = atomicAdd(&cnt[dl[k.v]], 1);
    ssrc[g * 4096 + slot] = e >> 5;    // src = e / K (edge list is src-major)
  });
}

// ---------------------------------------------------------------------------
// k_prep: (a) blocks 0..31: node1 (h pad 28, sc1);
//         (b) blocks 32..95: r-table build + bf16 pack (64 samples/block);
//             row = 64 uints: [0..49] w1 pairs (FS1 folded), [52..59] w2 pairs
//             (FS2 folded), rest 0;
//         (c) block 96: zero scalsum+midsum.
// ---------------------------------------------------------------------------
__global__ void __launch_bounds__(256, 4) k_prep(
    const float* __restrict__ wt_x, const float* __restrict__ mt_x,
    const float* __restrict__ lin1a, const float* __restrict__ sc1w,
    const float* __restrict__ fc1w1, const float* __restrict__ fc1w2,
    const float* __restrict__ fc2w1, const float* __restrict__ fc2w2,
    float* __restrict__ h, float* __restrict__ sc1,
    uint* __restrict__ tabU, float* __restrict__ zacc)
{
  __shared__ float stage[64][120];
  const int blk = blockIdx.x;
  if (blk < 32) {
    int i = blk * 256 + threadIdx.x;
    const float* xp = (i < NH_) ? (wt_x + i * 25) : (mt_x + (i - NH_) * 25);
    float xr[25];
    UN<25>([&](auto m){ xr[m.v] = xp[m.v]; });
    float ah[25], as[16];
    UN<25>([&](auto j){ ah[j.v] = 0.f; });
    UN<16>([&](auto j){ as[j.v] = 0.f; });
    UN<25>([&](auto m){
      float xm = xr[m.v];
      UN<25>([&](auto j){ ah[j.v] = fmaf(xm, lin1a[m.v * 25 + j.v], ah[j.v]); });
      UN<16>([&](auto j){ as[j.v] = fmaf(xm, sc1w[m.v * 16 + j.v], as[j.v]); });
    });
    UN<25>([&](auto j){ h[i * 28 + j.v] = 0.2f * ah[j.v]; });
    UN<16>([&](auto j){ sc1[i * 16 + j.v] = 0.2f * as[j.v]; });
  } else if (blk < 96) {
    const int lane = threadIdx.x & 63;
    const int p = __builtin_amdgcn_readfirstlane(threadIdx.x >> 6);
    const int s = (blk - 32) * 64 + lane;
    const float r = (float)s * (RT / (float)(TS - 1));
    float emb[10];
    make_emb(r, emb);
    const float FS1 = 0.003125f;   // (1/sqrt(128))*(1/sqrt(32))*(1/5)
    const float FS2 = 0.015625f;   // (1/sqrt(128))*(1/sqrt(32))
    if (p < 3) {
      const int cb = p * 25;
      float acc[25];
      UN<25>([&](auto c){ acc[c.v] = 0.f; });
#pragma unroll 2
      for (int k = 0; k < 128; ++k) {
        float hk = 0.f;
        UN<10>([&](auto j){ hk = fmaf(emb[j.v], fc1w1[j.v * 128 + k], hk); });
        float sS = hk * sigmoidf_(hk);
        UN<25>([&](auto c){ acc[c.v] = fmaf(sS, fc1w2[k * 100 + cb + c.v], acc[c.v]); });
      }
      UN<25>([&](auto c){ stage[lane][cb + c.v] = acc[c.v] * FS1; });
    } else {
      float acc[25], a2[16];
      UN<25>([&](auto c){ acc[c.v] = 0.f; });
      UN<16>([&](auto c){ a2[c.v] = 0.f; });
#pragma unroll 2
      for (int k = 0; k < 128; ++k) {
        float hk1 = 0.f, hk2 = 0.f;
        UN<10>([&](auto j){
          hk1 = fmaf(emb[j.v], fc1w1[j.v * 128 + k], hk1);
          hk2 = fmaf(emb[j.v], fc2w1[j.v * 128 + k], hk2);
        });
        float s1 = hk1 * sigmoidf_(hk1);
        float s2 = hk2 * sigmoidf_(hk2);
        UN<25>([&](auto c){ acc[c.v] = fmaf(s1, fc1w2[k * 100 + 75 + c.v], acc[c.v]); });
        UN<16>([&](auto c){ a2[c.v]  = fmaf(s2, fc2w2[k * 16 + c.v],       a2[c.v]); });
      }
      UN<25>([&](auto c){ stage[lane][75 + c.v]  = acc[c.v] * FS1; });
      UN<16>([&](auto c){ stage[lane][104 + c.v] = a2[c.v]  * FS2; });
    }
    __syncthreads();
    for (int z = threadIdx.x; z < 64 * 64; z += 256) {
      int sl = z >> 6, c = z & 63;
      float lo = 0.f, hi = 0.f;
      if (c < 50)                { lo = stage[sl][2 * c];            hi = stage[sl][2 * c + 1]; }
      else if (c >= 52 && c < 60){ int k = c - 52;
                                   lo = stage[sl][104 + 2 * k];      hi = stage[sl][104 + 2 * k + 1]; }
      uint u = ((__float_as_uint(lo) + 0x8000u) >> 16)
             | (((__float_as_uint(hi) + 0x8000u) >> 16) << 16);
      tabU[(size_t)((blk - 32) * 64 + sl) * 64 + c] = u;
    }
  } else {
    for (int z = threadIdx.x; z < 832; z += 256) zacc[z] = 0.f;
  }
}

// ---------------------------------------------------------------------------
// edge pass 1 (gather): half-wave per dst. Each lane owns one in-edge:
// nearest bf16 table row -> T = h_src * w1 -> project l2a* -> 42-float
// register accumulator; half-wave tree-reduce; single coalesced write of
// A[dst][42]. No atomics, no LDS.
// ---------------------------------------------------------------------------
__global__ void __launch_bounds__(256, 3) k_edge1(
    const float* __restrict__ wt_pos, const float* __restrict__ mt_pos,
    const int* __restrict__ soff, const int* __restrict__ ssrc,
    const uint* __restrict__ tabU, const float* __restrict__ h,
    const float* __restrict__ l2a0, const float* __restrict__ l2a1,
    const float* __restrict__ l2a2, const float* __restrict__ l2a3,
    float* __restrict__ A)
{
  const int tid = threadIdx.x;
  const int lane = tid & 63;
  const int li = lane & 31;
  const int wv = tid >> 6;
  const int dst = (blockIdx.x * 4 + wv) * 2 + (lane >> 5);

  const int start = soff[dst];
  const int n = soff[dst + 1] - start;
  const float* pd = (dst < NH_) ? (wt_pos + dst * 3) : (mt_pos + (dst - NH_) * 3);
  const float pdx = pd[0], pdy = pd[1], pdz = pd[2];

  float acc[42];
  UN<42>([&](auto c){ acc[c.v] = 0.f; });

  const int nmax = max(n, __shfl_xor(n, 32));
#pragma unroll 1
  for (int it = 0; it < nmax; it += 32) {
    const int i = it + li;
    if (i < n) {
      const int src = ssrc[start + i];
      const float* ps = (src < NH_) ? (wt_pos + src * 3) : (mt_pos + (src - NH_) * 3);
      float vx = ps[0] - pdx, vy = ps[1] - pdy, vz = ps[2] - pdz;
      float r = sqrtf(vx * vx + vy * vy + vz * vz);
      int ti = min((int)(r * RIDX + 0.5f), TS - 1);
      const uint4* w4 = (const uint4*)(tabU + (size_t)ti * 64);
      uint4 wr[13];
      UN<13>([&](auto j){ wr[j.v] = w4[j.v]; });
      const float4* hp = (const float4*)(h + src * 28);
      float4 hq[7];
      UN<7>([&](auto j){ hq[j.v] = hp[j.v]; });
      float sh[16];
      make_sh(vx, vy, vz, r, sh);

      // chunk 0 -> acc[0..15] directly
      UN<25>([&](auto mm){
        float t = f4get<mm.v>(hq) * upk<mm.v>(wr);
        UN<16>([&](auto v){ acc[v.v] = fmaf(t, l2a0[mm.v * 16 + v.v], acc[v.v]); });
      });
      // chunk 1 -> p1[3] -> acc[16 + v*3 + m'] += p1[v]*sh[1+m']
      {
        float p1[3] = {0.f, 0.f, 0.f};
        UN<25>([&](auto mm){
          float t = f4get<mm.v>(hq) * upk<25 + mm.v>(wr);
          UN<3>([&](auto v){ p1[v.v] = fmaf(t, l2a1[mm.v * 3 + v.v], p1[v.v]); });
        });
        UN<3>([&](auto v){
          UN<3>([&](auto m){ acc[16 + v.v * 3 + m.v] = fmaf(p1[v.v], sh[1 + m.v], acc[16 + v.v * 3 + m.v]); });
        });
      }
      // chunk 2 -> p2[2] -> acc[25 + v*5 + m'] += p2[v]*sh[4+m']
      {
        float p2[2] = {0.f, 0.f};
        UN<25>([&](auto mm){
          float t = f4get<mm.v>(hq) * upk<50 + mm.v>(wr);
          UN<2>([&](auto v){ p2[v.v] = fmaf(t, l2a2[mm.v * 2 + v.v], p2[v.v]); });
        });
        UN<2>([&](auto v){
          UN<5>([&](auto m){ acc[25 + v.v * 5 + m.v] = fmaf(p2[v.v], sh[4 + m.v], acc[25 + v.v * 5 + m.v]); });
        });
      }
      // chunk 3 -> p3 -> acc[35 + m'] += p3*sh[9+m']
      {
        float p3 = 0.f;
        UN<25>([&](auto mm){
          float t = f4get<mm.v>(hq) * upk<75 + mm.v>(wr);
          p3 = fmaf(t, l2a3[mm.v], p3);
        });
        UN<7>([&](auto m){ acc[35 + m.v] = fmaf(p3, sh[9 + m.v], acc[35 + m.v]); });
      }
    }
  }

  // half-wave tree reduce: 64 padded channels over 32 lanes
  float red[64];
  UN<42>([&](auto c){ red[c.v] = acc[c.v]; });
  UN<22>([&](auto c){ red[42 + c.v] = 0.f; });
  cred32_rec<0>(red, lane);
  float* Ad = A + (size_t)dst * 44;
  Ad[li] = red[0];
  if (li < 10) Ad[32 + li] = red[1];
}

// per-node stage 2: A -> gates/scal -> h0..h3 (36) + group scal sums
__global__ void __launch_bounds__(256, 4) k_node2(
    const float* __restrict__ A, const float* __restrict__ sc1,
    const float* __restrict__ l1b0, const float* __restrict__ l1b1,
    const float* __restrict__ l1b2, const float* __restrict__ l1b3,
    float* __restrict__ nodeH, float* __restrict__ scalsum)
{
  int i = blockIdx.x * 256 + threadIdx.x;
  const float4* A0 = (const float4*)(A + (size_t)i * 44);
  float Ai[44];
  UN<11>([&](auto j){
    float4 a = A0[j.v];
    Ai[j.v * 4 + 0] = a.x; Ai[j.v * 4 + 1] = a.y;
    Ai[j.v * 4 + 2] = a.z; Ai[j.v * 4 + 3] = a.w;
  });
  const float CS_ = 0.38268343236509f, CX_ = 0.92387953251129f;
  float scal[16], gate[6];
  UN<10>([&](auto c){
    float s = CS_ * sc1[i * 16 + c.v] + CX_ * Ai[c.v];
    scal[c.v] = s * sigmoidf_(s);
  });
  UN<6>([&](auto c){
    float s = CS_ * sc1[i * 16 + 10 + c.v] + CX_ * Ai[10 + c.v];
    gate[c.v] = sigmoidf_(s);
    scal[10 + c.v] = 0.f;
  });
  float* out = nodeH + i * 36;
  UN<10>([&](auto v){
    float a = 0.f;
    UN<10>([&](auto u){ a = fmaf(scal[u.v], l1b0[u.v * 10 + v.v], a); });
    out[v.v] = a * 0.31622776601684f;
  });
  UN<3>([&](auto v){
    UN<3>([&](auto m){
      float a = 0.f;
      UN<3>([&](auto u){ a = fmaf(Ai[16 + u.v * 3 + m.v] * gate[u.v], l1b1[u.v * 3 + v.v], a); });
      out[10 + v.v * 3 + m.v] = a * 0.57735026918963f;
    });
  });
  UN<2>([&](auto v){
    UN<5>([&](auto m){
      float a = 0.f;
      UN<2>([&](auto u){ a = fmaf(Ai[25 + u.v * 5 + m.v] * gate[3 + u.v], l1b2[u.v * 2 + v.v], a); });
      out[19 + v.v * 5 + m.v] = a * 0.70710678118655f;
    });
  });
  float b3 = l1b3[0];
  UN<7>([&](auto m){ out[29 + m.v] = Ai[35 + m.v] * gate[5] * b3; });

  int g = (i >> 7) & 31;
  int lane = threadIdx.x & 63;
  float s = creduce<16>(scal, lane);
  if (lane < 10) atomicAdd(&scalsum[g * 10 + lane], s);
}

// edge pass 2: nearest bf16 table (w2) -> e0..e3 -> tree-reduced group mid sums
__global__ void __launch_bounds__(256, 4) k_edge2(
    const float* __restrict__ wt_pos, const float* __restrict__ mt_pos,
    const int* __restrict__ edst,
    const uint* __restrict__ tabU, const float* __restrict__ nodeH,
    float* __restrict__ midsum)
{
  __shared__ float nh[288];   // 8 src rows x 36
  const int tid = threadIdx.x;
  const int blk = blockIdx.x;
  if (tid < 72) ((float4*)nh)[tid] = ((const float4*)(nodeH + (size_t)blk * 288))[tid];
  __syncthreads();

  int e = blk * 256 + tid;
  int src = e >> 5;                    // edge list is src-major
  int dst = edst[e];
  const float* ps = (src < NH_) ? (wt_pos + src * 3) : (mt_pos + (src - NH_) * 3);
  const float* pdp = (dst < NH_) ? (wt_pos + dst * 3) : (mt_pos + (dst - NH_) * 3);
  float vx = ps[0] - pdp[0], vy = ps[1] - pdp[1], vz = ps[2] - pdp[2];
  float r = sqrtf(vx * vx + vy * vy + vz * vz);
  int ti = min((int)(r * RIDX + 0.5f), TS - 1);
  const uint4* w4 = (const uint4*)(tabU + (size_t)ti * 64 + 52);
  uint4 wr[2];
  wr[0] = w4[0]; wr[1] = w4[1];
  float acc[16];
  UN<16>([&](auto c){ acc[c.v] = upk<c.v>(wr); });

  float sh[16];
  make_sh(vx, vy, vz, r, sh);

  const float4* Hp = (const float4*)(nh + (src & 7) * 36);
  float4 Hv[9];
  UN<9>([&](auto j){ Hv[j.v] = Hp[j.v]; });

  float ev[16];
  UN<10>([&](auto c){ ev[c.v] = f4get<c.v>(Hv) * acc[c.v]; });
  UN<3>([&](auto u){
    float d = 0.f;
    UN<3>([&](auto m){ d = fmaf(f4get<10 + u.v * 3 + m.v>(Hv), sh[1 + m.v], d); });
    ev[10 + u.v] = d * 0.57735026918963f * acc[10 + u.v];
  });
  UN<2>([&](auto u){
    float d = 0.f;
    UN<5>([&](auto m){ d = fmaf(f4get<19 + u.v * 5 + m.v>(Hv), sh[4 + m.v], d); });
    ev[13 + u.v] = d * 0.44721359549996f * acc[13 + u.v];
  });
  {
    float d = 0.f;
    UN<7>([&](auto m){ d = fmaf(f4get<29 + m.v>(Hv), sh[9 + m.v], d); });
    ev[15] = d * 0.37796447300923f * acc[15];
  }

  int g = (dst >> 7) & 31;
  int lane = tid & 63;
  float s = creduce<16>(ev, lane);
  if (lane < 16) atomicAdd(&midsum[g * 16 + lane], s);
}

// finale: fold head through sc2_w / lin2b, one block
__global__ void k_final(const float* __restrict__ sc2w, const float* __restrict__ lin2b,
                        const float* __restrict__ headw, const float* __restrict__ headb,
                        const float* __restrict__ scalsum, const float* __restrict__ midsum,
                        float* __restrict__ out)
{
  __shared__ float WA[20];
  __shared__ float WB[32];
  int t = threadIdx.x;
  if (t < 20) {
    int j = t >> 1, o = t & 1;
    float a = 0.f;
    for (int c = 0; c < 256; ++c) a += sc2w[j * 256 + c] * headw[c * 2 + o];
    WA[t] = a;
  } else if (t < 52) {
    int q = t - 20, j = q >> 1, o = q & 1;
    float a = 0.f;
    for (int c = 0; c < 256; ++c) a += lin2b[j * 256 + c] * headw[c * 2 + o];
    WB[q] = a;
  }
  __syncthreads();
  if (t < 64) {
    int g = t & 31, o = t >> 5;
    float a = 0.f;
    for (int j = 0; j < 10; ++j) a += scalsum[g * 10 + j] * WA[j * 2 + o];
    float b = 0.f;
    for (int j = 0; j < 16; ++j) b += midsum[g * 16 + j] * WB[j * 2 + o];
    float y = a * (0.38268343236509f * 0.31622776601684f)
            + b * (0.92387953251129f * 0.25f);
    out[o * 32 + g] = y * (1.0f / 256.0f) + headb[o];
  }
}

extern "C" void kernel_launch(void* const* d_in, const int* in_sizes, int n_in,
                              void* d_out, int out_size, void* d_ws, size_t ws_size,
                              hipStream_t stream)
{
  float* ws = (float*)d_ws;
  const float* wt_pos = (const float*)d_in[0];
  const float* mt_pos = (const float*)d_in[1];
  const float* wt_x   = (const float*)d_in[2];
  const float* mt_x   = (const float*)d_in[3];
  const int* edst     = (const int*)d_in[7];
  const float* sc1w   = (const float*)d_in[8];
  const float* lin1a  = (const float*)d_in[9];
  const float* fc1w1  = (const float*)d_in[10];
  const float* fc1w2  = (const float*)d_in[11];
  const float* l2a0   = (const float*)d_in[12];
  const float* l2a1   = (const float*)d_in[13];
  const float* l2a2   = (const float*)d_in[14];
  const float* l2a3   = (const float*)d_in[15];
  const float* sc2w   = (const float*)d_in[16];
  const float* l1b0   = (const float*)d_in[17];
  const float* l1b1   = (const float*)d_in[18];
  const float* l1b2   = (const float*)d_in[19];
  const float* l1b3   = (const float*)d_in[20];
  const float* fc2w1  = (const float*)d_in[21];
  const float* fc2w2  = (const float*)d_in[22];
  const float* lin2b  = (const float*)d_in[23];
  const float* headw  = (const float*)d_in[24];
  const float* headb  = (const float*)d_in[25];

  float* h       = ws + OFF_H;
  float* sc1     = ws + OFF_SC1;
  float* nodeH   = ws + OFF_NODEH;
  float* scalsum = ws + OFF_SCALS;
  float* midsum  = ws + OFF_MIDS;
  uint*  tabU    = (uint*)(ws + OFF_TABU);
  float* A       = ws + OFF_A;
  int*   ssrc    = (int*)(ws + OFF_SSRC);
  int*   soff    = (int*)(ws + OFF_SOFF);

  k_sortE<<<64, 1024, 0, stream>>>(edst, ssrc, soff);
  k_prep<<<97, 256, 0, stream>>>(wt_x, mt_x, lin1a, sc1w, fc1w1, fc1w2, fc2w1, fc2w2,
                                 h, sc1, tabU, scalsum);
  k_edge1<<<1024, 256, 0, stream>>>(wt_pos, mt_pos, soff, ssrc, tabU, h,
                                    l2a0, l2a1, l2a2, l2a3, A);
  k_node2<<<32, 256, 0, stream>>>(A, sc1, l1b0, l1b1, l1b2, l1b3, nodeH, scalsum);
  k_edge2<<<1024, 256, 0, stream>>>(wt_pos, mt_pos, edst, tabU, nodeH, midsum);
  k_final<<<1, 256, 0, stream>>>(sc2w, lin2b, headw, headb, scalsum, midsum, (float*)d_out);
}

// Round 9
// 100.626 us; speedup vs baseline: 8.6614x; 1.0262x over previous
//
#include <hip/hip_runtime.h>

typedef unsigned int uint;

#define NH_   4096
#define NNODE 8192
#define NEDGE 262144
#define TS    4096
#define RT    17.4f
#define RIDX  (((float)(TS - 1)) / RT)

// ---- workspace layout (float offsets) ----
#define OFF_H      0        // 8192*28
#define OFF_SC1    229376   // 8192*16
#define OFF_NODEH  360448   // 8192*36
#define OFF_SCALS  655360   // 32*10
#define OFF_MIDS   655680   // 32*16  (contiguous with SCALS: 832)
#define OFF_TABU   656384   // 4096*64 uints (bf16-packed r-table, scales folded)
#define OFF_A      918528   // 8192*44
#define OFF_SSRC   1278976  // 262144 ints (src sorted by dst)
#define OFF_SOFF   1541120  // 8256 ints (CSR offsets by dst)

// ---- compile-time unroll ----
template <int I> struct ic { static constexpr int v = I; };
template <int N, typename F>
__device__ __forceinline__ void UN(F&& f) {
  if constexpr (N > 0) { UN<N - 1>(f); f(ic<N - 1>{}); }
}

template <int K>
__device__ __forceinline__ float f4c(float4 v) {
  if constexpr (K == 0) return v.x;
  else if constexpr (K == 1) return v.y;
  else if constexpr (K == 2) return v.z;
  else return v.w;
}
template <int C>
__device__ __forceinline__ float f4get(const float4* v) {
  return f4c<C & 3>(v[C >> 2]);
}
template <int K>
__device__ __forceinline__ uint u4c(uint4 v) {
  if constexpr (K == 0) return v.x;
  else if constexpr (K == 1) return v.y;
  else if constexpr (K == 2) return v.z;
  else return v.w;
}
// unpack bf16-pair channel CH from packed uint4 regs
template <int CH>
__device__ __forceinline__ float upk(const uint4* wr) {
  constexpr int pr = CH >> 1;
  uint u = u4c<pr & 3>(wr[pr >> 2]);
  if constexpr (CH & 1) return __uint_as_float(u & 0xffff0000u);
  else return __uint_as_float(u << 16);
}

__device__ __forceinline__ float sigmoidf_(float v) { return 1.0f / (1.0f + __expf(-v)); }

// full-wave compacting reduction: C channels -> channel (lane & (C-1))
template <int C, int B>
__device__ __forceinline__ void cred_rec(float* a, int lane) {
  if constexpr ((1 << B) < C) {
    const bool hi = (lane >> B) & 1;
    constexpr int n = C >> (B + 1);
    UN<n>([&](auto j){
      float s0 = a[2 * j.v], s1 = a[2 * j.v + 1];
      float send = hi ? s0 : s1;
      float recv = __shfl_xor(send, 1 << B);
      a[j.v] = (hi ? s1 : s0) + recv;
    });
    cred_rec<C, B + 1>(a, lane);
  }
}
template <int C>
__device__ __forceinline__ float creduce(float* v, int lane) {
  cred_rec<C, 0>(v, lane);
  float s = v[0];
#pragma unroll
  for (int m = C; m < 64; m <<= 1) s += __shfl_xor(s, m);
  return s;
}
// half-wave (32-lane) compacting reduction of 64 channels, 5 steps.
// After: a[0] = ch (lane&31), a[1] = ch 32+(lane&31), summed over the half.
template <int B>
__device__ __forceinline__ void cred32_rec(float* a, int lane) {
  if constexpr (B < 5) {
    const bool hi = (lane >> B) & 1;
    constexpr int n = 64 >> (B + 1);
    UN<n>([&](auto j){
      float s0 = a[2 * j.v], s1 = a[2 * j.v + 1];
      float send = hi ? s0 : s1;
      float recv = __shfl_xor(send, 1 << B);
      a[j.v] = (hi ? s1 : s0) + recv;
    });
    cred32_rec<B + 1>(a, lane);
  }
}

__device__ __forceinline__ void make_emb(float r, float* embs) {
  float rb = r * 0.45f;
  UN<10>([&](auto b){ float d = rb - (float)b.v; embs[b.v] = __expf(-d * d); });
}

__device__ __forceinline__ void make_sh(float vx, float vy, float vz, float r, float* sh) {
  float rinv = 1.0f / fmaxf(r, 1e-9f);
  float x = vx * rinv, y = vy * rinv, z = vz * rinv;
  float x2 = x * x, y2 = y * y, z2 = z * z;
  float shA = 3.87298334620742f * x * z;
  float shB = 1.93649167310371f * (z2 - x2);
  sh[0] = 1.f;
  sh[1] = 1.73205080756888f * x;
  sh[2] = 1.73205080756888f * y;
  sh[3] = 1.73205080756888f * z;
  sh[4] = shA;
  sh[5] = 3.87298334620742f * x * y;
  sh[6] = 2.23606797749979f * (y2 - 0.5f * (x2 + z2));
  sh[7] = 3.87298334620742f * y * z;
  sh[8] = shB;
  sh[9]  = 1.08012344973464f * (shA * z + shB * x);
  sh[10] = 2.64575131106459f * shA * y;
  sh[11] = 1.62018517460197f * (4.f * y2 - x2 - z2) * x;
  sh[12] = 1.32287565553230f * y * (2.f * y2 - 3.f * x2 - 3.f * z2);
  sh[13] = 1.62018517460197f * z * (4.f * y2 - x2 - z2);
  sh[14] = 2.64575131106459f * shB * y;
  sh[15] = 1.08012344973464f * (shB * z - shA * x);
}

// ---------------------------------------------------------------------------
// k_sortE: per-group counting sort of edges by dst. One block per group
// (4096 edges, 128 dst bins). Outputs ssrc (src sorted by dst) + soff (CSR).
// ---------------------------------------------------------------------------
__global__ void __launch_bounds__(1024, 2) k_sortE(
    const int* __restrict__ edst, int* __restrict__ ssrc, int* __restrict__ soff)
{
  __shared__ int hist[128];
  __shared__ int cnt[128];
  const int g = blockIdx.x;
  const int tid = threadIdx.x;
  if (tid < 128) hist[tid] = 0;
  __syncthreads();
  int dl[4];
  UN<4>([&](auto k){
    int e = g * 4096 + k.v * 1024 + tid;
    dl[k.v] = edst[e] & 127;
    atomicAdd(&hist[dl[k.v]], 1);
  });
  __syncthreads();
  if (tid < 64) {
    int s0 = hist[2 * tid], s1 = hist[2 * tid + 1];
    int ps = s0 + s1;
    int sum = ps;
#pragma unroll
    for (int m = 1; m < 64; m <<= 1) {
      int t = __shfl_up(sum, m);
      if (tid >= m) sum += t;
    }
    int excl = sum - ps;
    cnt[2 * tid] = excl;
    cnt[2 * tid + 1] = excl + s0;
    soff[g * 128 + 2 * tid] = g * 4096 + excl;
    soff[g * 128 + 2 * tid + 1] = g * 4096 + excl + s0;
  }
  if (g == 0 && tid == 1023) soff[NNODE] = NEDGE;
  __syncthreads();
  UN<4>([&](auto k){
    int e = g * 4096 + k.v * 1024 + tid;
    int slot = atomicAdd(&cnt[dl[k.v]], 1);
    ssrc[g * 4096 + slot] = e >> 5;    // src = e / K (edge list is src-major)
  });
}

// ---------------------------------------------------------------------------
// k_prep: (a) blocks 0..31: node1 (h pad 28, sc1);
//         (b) blocks 32..95: r-table build + bf16 pack (64 samples/block);
//             row = 64 uints: [0..49] w1 pairs (FS1 folded), [52..59] w2 pairs
//             (FS2 folded), rest 0;
//         (c) block 96: zero scalsum+midsum.
// ---------------------------------------------------------------------------
__global__ void __launch_bounds__(256, 4) k_prep(
    const float* __restrict__ wt_x, const float* __restrict__ mt_x,
    const float* __restrict__ lin1a, const float* __restrict__ sc1w,
    const float* __restrict__ fc1w1, const float* __restrict__ fc1w2,
    const float* __restrict__ fc2w1, const float* __restrict__ fc2w2,
    float* __restrict__ h, float* __restrict__ sc1,
    uint* __restrict__ tabU, float* __restrict__ zacc)
{
  __shared__ float stage[64][120];
  const int blk = blockIdx.x;
  if (blk < 32) {
    int i = blk * 256 + threadIdx.x;
    const float* xp = (i < NH_) ? (wt_x + i * 25) : (mt_x + (i - NH_) * 25);
    float xr[25];
    UN<25>([&](auto m){ xr[m.v] = xp[m.v]; });
    float ah[25], as[16];
    UN<25>([&](auto j){ ah[j.v] = 0.f; });
    UN<16>([&](auto j){ as[j.v] = 0.f; });
    UN<25>([&](auto m){
      float xm = xr[m.v];
      UN<25>([&](auto j){ ah[j.v] = fmaf(xm, lin1a[m.v * 25 + j.v], ah[j.v]); });
      UN<16>([&](auto j){ as[j.v] = fmaf(xm, sc1w[m.v * 16 + j.v], as[j.v]); });
    });
    UN<25>([&](auto j){ h[i * 28 + j.v] = 0.2f * ah[j.v]; });
    UN<16>([&](auto j){ sc1[i * 16 + j.v] = 0.2f * as[j.v]; });
  } else if (blk < 96) {
    const int lane = threadIdx.x & 63;
    const int p = __builtin_amdgcn_readfirstlane(threadIdx.x >> 6);
    const int s = (blk - 32) * 64 + lane;
    const float r = (float)s * (RT / (float)(TS - 1));
    float emb[10];
    make_emb(r, emb);
    const float FS1 = 0.003125f;   // (1/sqrt(128))*(1/sqrt(32))*(1/5)
    const float FS2 = 0.015625f;   // (1/sqrt(128))*(1/sqrt(32))
    if (p < 3) {
      const int cb = p * 25;
      float acc[25];
      UN<25>([&](auto c){ acc[c.v] = 0.f; });
#pragma unroll 2
      for (int k = 0; k < 128; ++k) {
        float hk = 0.f;
        UN<10>([&](auto j){ hk = fmaf(emb[j.v], fc1w1[j.v * 128 + k], hk); });
        float sS = hk * sigmoidf_(hk);
        UN<25>([&](auto c){ acc[c.v] = fmaf(sS, fc1w2[k * 100 + cb + c.v], acc[c.v]); });
      }
      UN<25>([&](auto c){ stage[lane][cb + c.v] = acc[c.v] * FS1; });
    } else {
      float acc[25], a2[16];
      UN<25>([&](auto c){ acc[c.v] = 0.f; });
      UN<16>([&](auto c){ a2[c.v] = 0.f; });
#pragma unroll 2
      for (int k = 0; k < 128; ++k) {
        float hk1 = 0.f, hk2 = 0.f;
        UN<10>([&](auto j){
          hk1 = fmaf(emb[j.v], fc1w1[j.v * 128 + k], hk1);
          hk2 = fmaf(emb[j.v], fc2w1[j.v * 128 + k], hk2);
        });
        float s1 = hk1 * sigmoidf_(hk1);
        float s2 = hk2 * sigmoidf_(hk2);
        UN<25>([&](auto c){ acc[c.v] = fmaf(s1, fc1w2[k * 100 + 75 + c.v], acc[c.v]); });
        UN<16>([&](auto c){ a2[c.v]  = fmaf(s2, fc2w2[k * 16 + c.v],       a2[c.v]); });
      }
      UN<25>([&](auto c){ stage[lane][75 + c.v]  = acc[c.v] * FS1; });
      UN<16>([&](auto c){ stage[lane][104 + c.v] = a2[c.v]  * FS2; });
    }
    __syncthreads();
    for (int z = threadIdx.x; z < 64 * 64; z += 256) {
      int sl = z >> 6, c = z & 63;
      float lo = 0.f, hi = 0.f;
      if (c < 50)                { lo = stage[sl][2 * c];            hi = stage[sl][2 * c + 1]; }
      else if (c >= 52 && c < 60){ int k = c - 52;
                                   lo = stage[sl][104 + 2 * k];      hi = stage[sl][104 + 2 * k + 1]; }
      uint u = ((__float_as_uint(lo) + 0x8000u) >> 16)
             | (((__float_as_uint(hi) + 0x8000u) >> 16) << 16);
      tabU[(size_t)((blk - 32) * 64 + sl) * 64 + c] = u;
    }
  } else {
    for (int z = threadIdx.x; z < 832; z += 256) zacc[z] = 0.f;
  }
}

// ---------------------------------------------------------------------------
// edge pass 1 (gather): half-wave per dst. Each lane owns one in-edge:
// nearest bf16 table row -> T = h_src * w1 -> project l2a* -> 42-float
// register accumulator; half-wave tree-reduce; single coalesced write of
// A[dst][42]. No atomics, no LDS.
// ---------------------------------------------------------------------------
__global__ void __launch_bounds__(256, 3) k_edge1(
    const float* __restrict__ wt_pos, const float* __restrict__ mt_pos,
    const int* __restrict__ soff, const int* __restrict__ ssrc,
    const uint* __restrict__ tabU, const float* __restrict__ h,
    const float* __restrict__ l2a0, const float* __restrict__ l2a1,
    const float* __restrict__ l2a2, const float* __restrict__ l2a3,
    float* __restrict__ A)
{
  const int tid = threadIdx.x;
  const int lane = tid & 63;
  const int li = lane & 31;
  const int wv = tid >> 6;
  const int dst = (blockIdx.x * 4 + wv) * 2 + (lane >> 5);

  const int start = soff[dst];
  const int n = soff[dst + 1] - start;
  const float* pd = (dst < NH_) ? (wt_pos + dst * 3) : (mt_pos + (dst - NH_) * 3);
  const float pdx = pd[0], pdy = pd[1], pdz = pd[2];

  float acc[42];
  UN<42>([&](auto c){ acc[c.v] = 0.f; });

  const int nmax = max(n, __shfl_xor(n, 32));
#pragma unroll 1
  for (int it = 0; it < nmax; it += 32) {
    const int i = it + li;
    if (i < n) {
      const int src = ssrc[start + i];
      const float* ps = (src < NH_) ? (wt_pos + src * 3) : (mt_pos + (src - NH_) * 3);
      float vx = ps[0] - pdx, vy = ps[1] - pdy, vz = ps[2] - pdz;
      float r = sqrtf(vx * vx + vy * vy + vz * vz);
      int ti = min((int)(r * RIDX + 0.5f), TS - 1);
      const uint4* w4 = (const uint4*)(tabU + (size_t)ti * 64);
      uint4 wr[13];
      UN<13>([&](auto j){ wr[j.v] = w4[j.v]; });
      const float4* hp = (const float4*)(h + src * 28);
      float4 hq[7];
      UN<7>([&](auto j){ hq[j.v] = hp[j.v]; });
      float sh[16];
      make_sh(vx, vy, vz, r, sh);

      // chunk 0 -> acc[0..15] directly
      UN<25>([&](auto mm){
        float t = f4get<mm.v>(hq) * upk<mm.v>(wr);
        UN<16>([&](auto v){ acc[v.v] = fmaf(t, l2a0[mm.v * 16 + v.v], acc[v.v]); });
      });
      // chunk 1 -> p1[3] -> acc[16 + v*3 + m'] += p1[v]*sh[1+m']
      {
        float p1[3] = {0.f, 0.f, 0.f};
        UN<25>([&](auto mm){
          float t = f4get<mm.v>(hq) * upk<25 + mm.v>(wr);
          UN<3>([&](auto v){ p1[v.v] = fmaf(t, l2a1[mm.v * 3 + v.v], p1[v.v]); });
        });
        UN<3>([&](auto v){
          UN<3>([&](auto m){ acc[16 + v.v * 3 + m.v] = fmaf(p1[v.v], sh[1 + m.v], acc[16 + v.v * 3 + m.v]); });
        });
      }
      // chunk 2 -> p2[2] -> acc[25 + v*5 + m'] += p2[v]*sh[4+m']
      {
        float p2[2] = {0.f, 0.f};
        UN<25>([&](auto mm){
          float t = f4get<mm.v>(hq) * upk<50 + mm.v>(wr);
          UN<2>([&](auto v){ p2[v.v] = fmaf(t, l2a2[mm.v * 2 + v.v], p2[v.v]); });
        });
        UN<2>([&](auto v){
          UN<5>([&](auto m){ acc[25 + v.v * 5 + m.v] = fmaf(p2[v.v], sh[4 + m.v], acc[25 + v.v * 5 + m.v]); });
        });
      }
      // chunk 3 -> p3 -> acc[35 + m'] += p3*sh[9+m']
      {
        float p3 = 0.f;
        UN<25>([&](auto mm){
          float t = f4get<mm.v>(hq) * upk<75 + mm.v>(wr);
          p3 = fmaf(t, l2a3[mm.v], p3);
        });
        UN<7>([&](auto m){ acc[35 + m.v] = fmaf(p3, sh[9 + m.v], acc[35 + m.v]); });
      }
    }
  }

  // half-wave tree reduce: 64 padded channels over 32 lanes
  float red[64];
  UN<42>([&](auto c){ red[c.v] = acc[c.v]; });
  UN<22>([&](auto c){ red[42 + c.v] = 0.f; });
  cred32_rec<0>(red, lane);
  float* Ad = A + (size_t)dst * 44;
  Ad[li] = red[0];
  if (li < 10) Ad[32 + li] = red[1];
}

// per-node stage 2: A -> gates/scal -> h0..h3 (36) + group scal sums
__global__ void __launch_bounds__(256, 4) k_node2(
    const float* __restrict__ A, const float* __restrict__ sc1,
    const float* __restrict__ l1b0, const float* __restrict__ l1b1,
    const float* __restrict__ l1b2, const float* __restrict__ l1b3,
    float* __restrict__ nodeH, float* __restrict__ scalsum)
{
  int i = blockIdx.x * 256 + threadIdx.x;
  const float4* A0 = (const float4*)(A + (size_t)i * 44);
  float Ai[44];
  UN<11>([&](auto j){
    float4 a = A0[j.v];
    Ai[j.v * 4 + 0] = a.x; Ai[j.v * 4 + 1] = a.y;
    Ai[j.v * 4 + 2] = a.z; Ai[j.v * 4 + 3] = a.w;
  });
  const float CS_ = 0.38268343236509f, CX_ = 0.92387953251129f;
  float scal[16], gate[6];
  UN<10>([&](auto c){
    float s = CS_ * sc1[i * 16 + c.v] + CX_ * Ai[c.v];
    scal[c.v] = s * sigmoidf_(s);
  });
  UN<6>([&](auto c){
    float s = CS_ * sc1[i * 16 + 10 + c.v] + CX_ * Ai[10 + c.v];
    gate[c.v] = sigmoidf_(s);
    scal[10 + c.v] = 0.f;
  });
  float* out = nodeH + i * 36;
  UN<10>([&](auto v){
    float a = 0.f;
    UN<10>([&](auto u){ a = fmaf(scal[u.v], l1b0[u.v * 10 + v.v], a); });
    out[v.v] = a * 0.31622776601684f;
  });
  UN<3>([&](auto v){
    UN<3>([&](auto m){
      float a = 0.f;
      UN<3>([&](auto u){ a = fmaf(Ai[16 + u.v * 3 + m.v] * gate[u.v], l1b1[u.v * 3 + v.v], a); });
      out[10 + v.v * 3 + m.v] = a * 0.57735026918963f;
    });
  });
  UN<2>([&](auto v){
    UN<5>([&](auto m){
      float a = 0.f;
      UN<2>([&](auto u){ a = fmaf(Ai[25 + u.v * 5 + m.v] * gate[3 + u.v], l1b2[u.v * 2 + v.v], a); });
      out[19 + v.v * 5 + m.v] = a * 0.70710678118655f;
    });
  });
  float b3 = l1b3[0];
  UN<7>([&](auto m){ out[29 + m.v] = Ai[35 + m.v] * gate[5] * b3; });

  int g = (i >> 7) & 31;
  int lane = threadIdx.x & 63;
  float s = creduce<16>(scal, lane);
  if (lane < 10) atomicAdd(&scalsum[g * 10 + lane], s);
}

// edge pass 2: nearest bf16 table (w2) -> e0..e3 -> tree-reduced group mid sums
__global__ void __launch_bounds__(256, 4) k_edge2(
    const float* __restrict__ wt_pos, const float* __restrict__ mt_pos,
    const int* __restrict__ edst,
    const uint* __restrict__ tabU, const float* __restrict__ nodeH,
    float* __restrict__ midsum)
{
  __shared__ float nh[288];   // 8 src rows x 36
  const int tid = threadIdx.x;
  const int blk = blockIdx.x;
  if (tid < 72) ((float4*)nh)[tid] = ((const float4*)(nodeH + (size_t)blk * 288))[tid];
  __syncthreads();

  int e = blk * 256 + tid;
  int src = e >> 5;                    // edge list is src-major
  int dst = edst[e];
  const float* ps = (src < NH_) ? (wt_pos + src * 3) : (mt_pos + (src - NH_) * 3);
  const float* pdp = (dst < NH_) ? (wt_pos + dst * 3) : (mt_pos + (dst - NH_) * 3);
  float vx = ps[0] - pdp[0], vy = ps[1] - pdp[1], vz = ps[2] - pdp[2];
  float r = sqrtf(vx * vx + vy * vy + vz * vz);
  int ti = min((int)(r * RIDX + 0.5f), TS - 1);
  const uint4* w4 = (const uint4*)(tabU + (size_t)ti * 64 + 52);
  uint4 wr[2];
  wr[0] = w4[0]; wr[1] = w4[1];
  float acc[16];
  UN<16>([&](auto c){ acc[c.v] = upk<c.v>(wr); });

  float sh[16];
  make_sh(vx, vy, vz, r, sh);

  const float4* Hp = (const float4*)(nh + (src & 7) * 36);
  float4 Hv[9];
  UN<9>([&](auto j){ Hv[j.v] = Hp[j.v]; });

  float ev[16];
  UN<10>([&](auto c){ ev[c.v] = f4get<c.v>(Hv) * acc[c.v]; });
  UN<3>([&](auto u){
    float d = 0.f;
    UN<3>([&](auto m){ d = fmaf(f4get<10 + u.v * 3 + m.v>(Hv), sh[1 + m.v], d); });
    ev[10 + u.v] = d * 0.57735026918963f * acc[10 + u.v];
  });
  UN<2>([&](auto u){
    float d = 0.f;
    UN<5>([&](auto m){ d = fmaf(f4get<19 + u.v * 5 + m.v>(Hv), sh[4 + m.v], d); });
    ev[13 + u.v] = d * 0.44721359549996f * acc[13 + u.v];
  });
  {
    float d = 0.f;
    UN<7>([&](auto m){ d = fmaf(f4get<29 + m.v>(Hv), sh[9 + m.v], d); });
    ev[15] = d * 0.37796447300923f * acc[15];
  }

  int g = (dst >> 7) & 31;
  int lane = tid & 63;
  float s = creduce<16>(ev, lane);
  if (lane < 16) atomicAdd(&midsum[g * 16 + lane], s);
}

// finale: fold head through sc2_w / lin2b, one block
__global__ void k_final(const float* __restrict__ sc2w, const float* __restrict__ lin2b,
                        const float* __restrict__ headw, const float* __restrict__ headb,
                        const float* __restrict__ scalsum, const float* __restrict__ midsum,
                        float* __restrict__ out)
{
  __shared__ float WA[20];
  __shared__ float WB[32];
  int t = threadIdx.x;
  if (t < 20) {
    int j = t >> 1, o = t & 1;
    float a = 0.f;
    for (int c = 0; c < 256; ++c) a += sc2w[j * 256 + c] * headw[c * 2 + o];
    WA[t] = a;
  } else if (t < 52) {
    int q = t - 20, j = q >> 1, o = q & 1;
    float a = 0.f;
    for (int c = 0; c < 256; ++c) a += lin2b[j * 256 + c] * headw[c * 2 + o];
    WB[q] = a;
  }
  __syncthreads();
  if (t < 64) {
    int g = t & 31, o = t >> 5;
    float a = 0.f;
    for (int j = 0; j < 10; ++j) a += scalsum[g * 10 + j] * WA[j * 2 + o];
    float b = 0.f;
    for (int j = 0; j < 16; ++j) b += midsum[g * 16 + j] * WB[j * 2 + o];
    float y = a * (0.38268343236509f * 0.31622776601684f)
            + b * (0.92387953251129f * 0.25f);
    out[o * 32 + g] = y * (1.0f / 256.0f) + headb[o];
  }
}

extern "C" void kernel_launch(void* const* d_in, const int* in_sizes, int n_in,
                              void* d_out, int out_size, void* d_ws, size_t ws_size,
                              hipStream_t stream)
{
  float* ws = (float*)d_ws;
  const float* wt_pos = (const float*)d_in[0];
  const float* mt_pos = (const float*)d_in[1];
  const float* wt_x   = (const float*)d_in[2];
  const float* mt_x   = (const float*)d_in[3];
  const int* edst     = (const int*)d_in[7];
  const float* sc1w   = (const float*)d_in[8];
  const float* lin1a  = (const float*)d_in[9];
  const float* fc1w1  = (const float*)d_in[10];
  const float* fc1w2  = (const float*)d_in[11];
  const float* l2a0   = (const float*)d_in[12];
  const float* l2a1   = (const float*)d_in[13];
  const float* l2a2   = (const float*)d_in[14];
  const float* l2a3   = (const float*)d_in[15];
  const float* sc2w   = (const float*)d_in[16];
  const float* l1b0   = (const float*)d_in[17];
  const float* l1b1   = (const float*)d_in[18];
  const float* l1b2   = (const float*)d_in[19];
  const float* l1b3   = (const float*)d_in[20];
  const float* fc2w1  = (const float*)d_in[21];
  const float* fc2w2  = (const float*)d_in[22];
  const float* lin2b  = (const float*)d_in[23];
  const float* headw  = (const float*)d_in[24];
  const float* headb  = (const float*)d_in[25];

  float* h       = ws + OFF_H;
  float* sc1     = ws + OFF_SC1;
  float* nodeH   = ws + OFF_NODEH;
  float* scalsum = ws + OFF_SCALS;
  float* midsum  = ws + OFF_MIDS;
  uint*  tabU    = (uint*)(ws + OFF_TABU);
  float* A       = ws + OFF_A;
  int*   ssrc    = (int*)(ws + OFF_SSRC);
  int*   soff    = (int*)(ws + OFF_SOFF);

  k_sortE<<<64, 1024, 0, stream>>>(edst, ssrc, soff);
  k_prep<<<97, 256, 0, stream>>>(wt_x, mt_x, lin1a, sc1w, fc1w1, fc1w2, fc2w1, fc2w2,
                                 h, sc1, tabU, scalsum);
  k_edge1<<<1024, 256, 0, stream>>>(wt_pos, mt_pos, soff, ssrc, tabU, h,
                                    l2a0, l2a1, l2a2, l2a3, A);
  k_node2<<<32, 256, 0, stream>>>(A, sc1, l1b0, l1b1, l1b2, l1b3, nodeH, scalsum);
  k_edge2<<<1024, 256, 0, stream>>>(wt_pos, mt_pos, edst, tabU, nodeH, midsum);
  k_final<<<1, 256, 0, stream>>>(sc2w, lin2b, headw, headb, scalsum, midsum, (float*)d_out);
}

// Round 10
// 76.290 us; speedup vs baseline: 11.4243x; 1.3190x over previous
//
#include <hip/hip_runtime.h>

typedef unsigned int uint;

#define NH_   4096
#define NNODE 8192
#define NEDGE 262144
#define TS    4096
#define RT    17.4f
#define RIDX  (((float)(TS - 1)) / RT)

// ---- workspace layout (float offsets) ----
#define OFF_H      0        // 8192*28
#define OFF_SC1    229376   // 8192*16
#define OFF_NODEH  360448   // 8192*36
#define OFF_SCALS  655360   // 32*10
#define OFF_MIDS   655680   // 32*16  (contiguous with SCALS: 832)
#define OFF_TABU   656384   // 4096*64 uints (bf16-packed r-table, scales folded)
#define OFF_A      918528   // 8192*44
#define OFF_SSRC   1278976  // 262144 ints (src sorted by dst)
#define OFF_SOFF   1541120  // 8256 ints (CSR offsets by dst)

// ---- compile-time unroll ----
template <int I> struct ic { static constexpr int v = I; };
template <int N, typename F>
__device__ __forceinline__ void UN(F&& f) {
  if constexpr (N > 0) { UN<N - 1>(f); f(ic<N - 1>{}); }
}

template <int K>
__device__ __forceinline__ float f4c(float4 v) {
  if constexpr (K == 0) return v.x;
  else if constexpr (K == 1) return v.y;
  else if constexpr (K == 2) return v.z;
  else return v.w;
}
template <int C>
__device__ __forceinline__ float f4get(const float4* v) {
  return f4c<C & 3>(v[C >> 2]);
}
template <int K>
__device__ __forceinline__ uint u4c(uint4 v) {
  if constexpr (K == 0) return v.x;
  else if constexpr (K == 1) return v.y;
  else if constexpr (K == 2) return v.z;
  else return v.w;
}
// unpack bf16-pair channel CH from packed uint4 regs
template <int CH>
__device__ __forceinline__ float upk(const uint4* wr) {
  constexpr int pr = CH >> 1;
  uint u = u4c<pr & 3>(wr[pr >> 2]);
  if constexpr (CH & 1) return __uint_as_float(u & 0xffff0000u);
  else return __uint_as_float(u << 16);
}

__device__ __forceinline__ float sigmoidf_(float v) { return 1.0f / (1.0f + __expf(-v)); }

// full-wave compacting reduction: C channels -> channel (lane & (C-1))
template <int C, int B>
__device__ __forceinline__ void cred_rec(float* a, int lane) {
  if constexpr ((1 << B) < C) {
    const bool hi = (lane >> B) & 1;
    constexpr int n = C >> (B + 1);
    UN<n>([&](auto j){
      float s0 = a[2 * j.v], s1 = a[2 * j.v + 1];
      float send = hi ? s0 : s1;
      float recv = __shfl_xor(send, 1 << B);
      a[j.v] = (hi ? s1 : s0) + recv;
    });
    cred_rec<C, B + 1>(a, lane);
  }
}
template <int C>
__device__ __forceinline__ float creduce(float* v, int lane) {
  cred_rec<C, 0>(v, lane);
  float s = v[0];
#pragma unroll
  for (int m = C; m < 64; m <<= 1) s += __shfl_xor(s, m);
  return s;
}
// half-wave (32-lane) compacting reduction of 64 channels, 5 steps.
template <int B>
__device__ __forceinline__ void cred32_rec(float* a, int lane) {
  if constexpr (B < 5) {
    const bool hi = (lane >> B) & 1;
    constexpr int n = 64 >> (B + 1);
    UN<n>([&](auto j){
      float s0 = a[2 * j.v], s1 = a[2 * j.v + 1];
      float send = hi ? s0 : s1;
      float recv = __shfl_xor(send, 1 << B);
      a[j.v] = (hi ? s1 : s0) + recv;
    });
    cred32_rec<B + 1>(a, lane);
  }
}

__device__ __forceinline__ void make_emb(float r, float* embs) {
  float rb = r * 0.45f;
  UN<10>([&](auto b){ float d = rb - (float)b.v; embs[b.v] = __expf(-d * d); });
}

__device__ __forceinline__ void make_sh(float vx, float vy, float vz, float r, float* sh) {
  float rinv = 1.0f / fmaxf(r, 1e-9f);
  float x = vx * rinv, y = vy * rinv, z = vz * rinv;
  float x2 = x * x, y2 = y * y, z2 = z * z;
  float shA = 3.87298334620742f * x * z;
  float shB = 1.93649167310371f * (z2 - x2);
  sh[0] = 1.f;
  sh[1] = 1.73205080756888f * x;
  sh[2] = 1.73205080756888f * y;
  sh[3] = 1.73205080756888f * z;
  sh[4] = shA;
  sh[5] = 3.87298334620742f * x * y;
  sh[6] = 2.23606797749979f * (y2 - 0.5f * (x2 + z2));
  sh[7] = 3.87298334620742f * y * z;
  sh[8] = shB;
  sh[9]  = 1.08012344973464f * (shA * z + shB * x);
  sh[10] = 2.64575131106459f * shA * y;
  sh[11] = 1.62018517460197f * (4.f * y2 - x2 - z2) * x;
  sh[12] = 1.32287565553230f * y * (2.f * y2 - 3.f * x2 - 3.f * z2);
  sh[13] = 1.62018517460197f * z * (4.f * y2 - x2 - z2);
  sh[14] = 2.64575131106459f * shB * y;
  sh[15] = 1.08012344973464f * (shB * z - shA * x);
}

// ---------------------------------------------------------------------------
// k_prep (merged, block-ranged):
//   blocks [0,2048): r-table build, 2 samples/block, lane = output channel.
//     phase1: all 128 silu values per sample in parallel -> LDS (2 KB);
//     phase2: lane-owned channel accumulates over k (coalesced loads + LDS
//     broadcast); bf16 pair-pack via shfl.
//   blocks [2048,2080): node1 (h pad 28, sc1).
//   blocks [2080,2144): counting sort of edges by dst (4096 edges/block).
//   block 2144: zero scalsum+midsum.
// ---------------------------------------------------------------------------
__global__ void __launch_bounds__(256, 4) k_prep(
    const float* __restrict__ wt_x, const float* __restrict__ mt_x,
    const float* __restrict__ lin1a, const float* __restrict__ sc1w,
    const float* __restrict__ fc1w1, const float* __restrict__ fc1w2,
    const float* __restrict__ fc2w1, const float* __restrict__ fc2w2,
    const int* __restrict__ edst,
    float* __restrict__ h, float* __restrict__ sc1,
    uint* __restrict__ tabU, float* __restrict__ zacc,
    int* __restrict__ ssrc, int* __restrict__ soff)
{
  __shared__ float smemf[512];   // table: sv[2][2][128]; sort: hist+cnt
  const int blk = blockIdx.x;
  const int tid = threadIdx.x;

  if (blk < 2048) {
    // ---- r-table ----
    float (*sv)[2][128] = (float(*)[2][128])smemf;   // [si][role][k]
    const int lane = tid & 63;
    const int wv = tid >> 6;
    const int si = wv >> 1;
    const int role = wv & 1;                          // 0: s1/w1-lo, 1: s2 + w1-hi/w2
    const int s = blk * 2 + si;
    const float r = (float)s * (RT / (float)(TS - 1));
    float emb[10];
    make_emb(r, emb);
    const float FS1 = 0.003125f;   // (1/sqrt(128))*(1/sqrt(32))*(1/5)
    const float FS2 = 0.015625f;   // (1/sqrt(128))*(1/sqrt(32))

    // phase 1: silu values for all 128 k in parallel
    const float* wmat = (role == 0) ? fc1w1 : fc2w1;
    UN<2>([&](auto hh){
      int kk = lane + hh.v * 64;
      float hk = 0.f;
      UN<10>([&](auto j){ hk = fmaf(emb[j.v], wmat[j.v * 128 + kk], hk); });
      sv[si][role][kk] = hk * sigmoidf_(hk);
    });
    __syncthreads();

    // phase 2: lane-owned channel accumulation
    float acc = 0.f;
    if (role == 0) {
      const float* base = fc1w2 + lane;              // w1 channel = lane
#pragma unroll 4
      for (int k = 0; k < 128; ++k)
        acc = fmaf(sv[si][0][k], base[k * 100], acc);
      acc *= FS1;
    } else {
      const bool isW1 = lane < 36;                   // w1 channel 64+lane
      const bool isW2 = (lane >= 36) && (lane < 52); // w2 channel lane-36
      if (isW1 || isW2) {
        const float* base = isW1 ? (fc1w2 + 64 + lane) : (fc2w2 + (lane - 36));
        const int stride = isW1 ? 100 : 16;
        const int svi = isW1 ? 0 : 1;
#pragma unroll 4
        for (int k = 0; k < 128; ++k)
          acc = fmaf(sv[si][svi][k], base[k * stride], acc);
        acc *= (isW1 ? FS1 : FS2);
      }
    }

    // pack bf16 pairs via shfl (all lanes shfl, masked store)
    int srcLo = 0, srcHi = 0;
    bool valid = false;
    if (role == 0) {
      srcLo = 2 * lane; srcHi = srcLo + 1; valid = lane < 32;   // cols 0..31
    } else {
      if (lane >= 32 && lane < 50)      { int i = lane - 32; srcLo = 2 * i;      srcHi = 2 * i + 1;  valid = true; }  // cols 32..49
      else if (lane >= 52 && lane < 60) { int i = lane - 52; srcLo = 36 + 2 * i; srcHi = 37 + 2 * i; valid = true; }  // cols 52..59
    }
    float lo = __shfl(acc, srcLo);
    float hi = __shfl(acc, srcHi);
    if (valid) {
      uint u = ((__float_as_uint(lo) + 0x8000u) >> 16)
             | (((__float_as_uint(hi) + 0x8000u) >> 16) << 16);
      tabU[(size_t)s * 64 + lane] = u;
    }
  } else if (blk < 2080) {
    // ---- node1 ----
    int i = (blk - 2048) * 256 + tid;
    const float* xp = (i < NH_) ? (wt_x + i * 25) : (mt_x + (i - NH_) * 25);
    float xr[25];
    UN<25>([&](auto m){ xr[m.v] = xp[m.v]; });
    float ah[25], as[16];
    UN<25>([&](auto j){ ah[j.v] = 0.f; });
    UN<16>([&](auto j){ as[j.v] = 0.f; });
    UN<25>([&](auto m){
      float xm = xr[m.v];
      UN<25>([&](auto j){ ah[j.v] = fmaf(xm, lin1a[m.v * 25 + j.v], ah[j.v]); });
      UN<16>([&](auto j){ as[j.v] = fmaf(xm, sc1w[m.v * 16 + j.v], as[j.v]); });
    });
    UN<25>([&](auto j){ h[i * 28 + j.v] = 0.2f * ah[j.v]; });
    UN<16>([&](auto j){ sc1[i * 16 + j.v] = 0.2f * as[j.v]; });
  } else if (blk < 2144) {
    // ---- counting sort by dst: one block per group (4096 edges) ----
    int* hist = (int*)smemf;
    int* cnt  = hist + 128;
    const int g = blk - 2080;
    if (tid < 128) hist[tid] = 0;
    __syncthreads();
    int dl[16];
    UN<16>([&](auto k){
      int e = g * 4096 + k.v * 256 + tid;
      dl[k.v] = edst[e] & 127;
      atomicAdd(&hist[dl[k.v]], 1);
    });
    __syncthreads();
    if (tid < 64) {
      int s0 = hist[2 * tid], s1 = hist[2 * tid + 1];
      int ps = s0 + s1;
      int sum = ps;
#pragma unroll
      for (int m = 1; m < 64; m <<= 1) {
        int t = __shfl_up(sum, m);
        if (tid >= m) sum += t;
      }
      int excl = sum - ps;
      cnt[2 * tid] = excl;
      cnt[2 * tid + 1] = excl + s0;
      soff[g * 128 + 2 * tid] = g * 4096 + excl;
      soff[g * 128 + 2 * tid + 1] = g * 4096 + excl + s0;
    }
    if (g == 0 && tid == 255) soff[NNODE] = NEDGE;
    __syncthreads();
    UN<16>([&](auto k){
      int e = g * 4096 + k.v * 256 + tid;
      int slot = atomicAdd(&cnt[dl[k.v]], 1);
      ssrc[g * 4096 + slot] = e >> 5;    // src = e / K (edge list is src-major)
    });
  } else {
    for (int z = tid; z < 832; z += 256) zacc[z] = 0.f;
  }
}

// ---------------------------------------------------------------------------
// edge pass 1 (gather): half-wave per dst, register accumulate + tree reduce.
// ---------------------------------------------------------------------------
__global__ void __launch_bounds__(256, 3) k_edge1(
    const float* __restrict__ wt_pos, const float* __restrict__ mt_pos,
    const int* __restrict__ soff, const int* __restrict__ ssrc,
    const uint* __restrict__ tabU, const float* __restrict__ h,
    const float* __restrict__ l2a0, const float* __restrict__ l2a1,
    const float* __restrict__ l2a2, const float* __restrict__ l2a3,
    float* __restrict__ A)
{
  const int tid = threadIdx.x;
  const int lane = tid & 63;
  const int li = lane & 31;
  const int wv = tid >> 6;
  const int dst = (blockIdx.x * 4 + wv) * 2 + (lane >> 5);

  const int start = soff[dst];
  const int n = soff[dst + 1] - start;
  const float* pd = (dst < NH_) ? (wt_pos + dst * 3) : (mt_pos + (dst - NH_) * 3);
  const float pdx = pd[0], pdy = pd[1], pdz = pd[2];

  float acc[42];
  UN<42>([&](auto c){ acc[c.v] = 0.f; });

  const int nmax = max(n, __shfl_xor(n, 32));
#pragma unroll 1
  for (int it = 0; it < nmax; it += 32) {
    const int i = it + li;
    if (i < n) {
      const int src = ssrc[start + i];
      const float* ps = (src < NH_) ? (wt_pos + src * 3) : (mt_pos + (src - NH_) * 3);
      float vx = ps[0] - pdx, vy = ps[1] - pdy, vz = ps[2] - pdz;
      float r = sqrtf(vx * vx + vy * vy + vz * vz);
      int ti = min((int)(r * RIDX + 0.5f), TS - 1);
      const uint4* w4 = (const uint4*)(tabU + (size_t)ti * 64);
      uint4 wr[13];
      UN<13>([&](auto j){ wr[j.v] = w4[j.v]; });
      const float4* hp = (const float4*)(h + src * 28);
      float4 hq[7];
      UN<7>([&](auto j){ hq[j.v] = hp[j.v]; });
      float sh[16];
      make_sh(vx, vy, vz, r, sh);

      UN<25>([&](auto mm){
        float t = f4get<mm.v>(hq) * upk<mm.v>(wr);
        UN<16>([&](auto v){ acc[v.v] = fmaf(t, l2a0[mm.v * 16 + v.v], acc[v.v]); });
      });
      {
        float p1[3] = {0.f, 0.f, 0.f};
        UN<25>([&](auto mm){
          float t = f4get<mm.v>(hq) * upk<25 + mm.v>(wr);
          UN<3>([&](auto v){ p1[v.v] = fmaf(t, l2a1[mm.v * 3 + v.v], p1[v.v]); });
        });
        UN<3>([&](auto v){
          UN<3>([&](auto m){ acc[16 + v.v * 3 + m.v] = fmaf(p1[v.v], sh[1 + m.v], acc[16 + v.v * 3 + m.v]); });
        });
      }
      {
        float p2[2] = {0.f, 0.f};
        UN<25>([&](auto mm){
          float t = f4get<mm.v>(hq) * upk<50 + mm.v>(wr);
          UN<2>([&](auto v){ p2[v.v] = fmaf(t, l2a2[mm.v * 2 + v.v], p2[v.v]); });
        });
        UN<2>([&](auto v){
          UN<5>([&](auto m){ acc[25 + v.v * 5 + m.v] = fmaf(p2[v.v], sh[4 + m.v], acc[25 + v.v * 5 + m.v]); });
        });
      }
      {
        float p3 = 0.f;
        UN<25>([&](auto mm){
          float t = f4get<mm.v>(hq) * upk<75 + mm.v>(wr);
          p3 = fmaf(t, l2a3[mm.v], p3);
        });
        UN<7>([&](auto m){ acc[35 + m.v] = fmaf(p3, sh[9 + m.v], acc[35 + m.v]); });
      }
    }
  }

  float red[64];
  UN<42>([&](auto c){ red[c.v] = acc[c.v]; });
  UN<22>([&](auto c){ red[42 + c.v] = 0.f; });
  cred32_rec<0>(red, lane);
  float* Ad = A + (size_t)dst * 44;
  Ad[li] = red[0];
  if (li < 10) Ad[32 + li] = red[1];
}

// per-node stage 2: A -> gates/scal -> h0..h3 (36) + group scal sums
__global__ void __launch_bounds__(256, 4) k_node2(
    const float* __restrict__ A, const float* __restrict__ sc1,
    const float* __restrict__ l1b0, const float* __restrict__ l1b1,
    const float* __restrict__ l1b2, const float* __restrict__ l1b3,
    float* __restrict__ nodeH, float* __restrict__ scalsum)
{
  int i = blockIdx.x * 256 + threadIdx.x;
  const float4* A0 = (const float4*)(A + (size_t)i * 44);
  float Ai[44];
  UN<11>([&](auto j){
    float4 a = A0[j.v];
    Ai[j.v * 4 + 0] = a.x; Ai[j.v * 4 + 1] = a.y;
    Ai[j.v * 4 + 2] = a.z; Ai[j.v * 4 + 3] = a.w;
  });
  const float CS_ = 0.38268343236509f, CX_ = 0.92387953251129f;
  float scal[16], gate[6];
  UN<10>([&](auto c){
    float s = CS_ * sc1[i * 16 + c.v] + CX_ * Ai[c.v];
    scal[c.v] = s * sigmoidf_(s);
  });
  UN<6>([&](auto c){
    float s = CS_ * sc1[i * 16 + 10 + c.v] + CX_ * Ai[10 + c.v];
    gate[c.v] = sigmoidf_(s);
    scal[10 + c.v] = 0.f;
  });
  float* out = nodeH + i * 36;
  UN<10>([&](auto v){
    float a = 0.f;
    UN<10>([&](auto u){ a = fmaf(scal[u.v], l1b0[u.v * 10 + v.v], a); });
    out[v.v] = a * 0.31622776601684f;
  });
  UN<3>([&](auto v){
    UN<3>([&](auto m){
      float a = 0.f;
      UN<3>([&](auto u){ a = fmaf(Ai[16 + u.v * 3 + m.v] * gate[u.v], l1b1[u.v * 3 + v.v], a); });
      out[10 + v.v * 3 + m.v] = a * 0.57735026918963f;
    });
  });
  UN<2>([&](auto v){
    UN<5>([&](auto m){
      float a = 0.f;
      UN<2>([&](auto u){ a = fmaf(Ai[25 + u.v * 5 + m.v] * gate[3 + u.v], l1b2[u.v * 2 + v.v], a); });
      out[19 + v.v * 5 + m.v] = a * 0.70710678118655f;
    });
  });
  float b3 = l1b3[0];
  UN<7>([&](auto m){ out[29 + m.v] = Ai[35 + m.v] * gate[5] * b3; });

  int g = (i >> 7) & 31;
  int lane = threadIdx.x & 63;
  float s = creduce<16>(scal, lane);
  if (lane < 10) atomicAdd(&scalsum[g * 10 + lane], s);
}

// edge pass 2: nearest bf16 table (w2) -> e0..e3 -> tree-reduced group mid sums
__global__ void __launch_bounds__(256, 4) k_edge2(
    const float* __restrict__ wt_pos, const float* __restrict__ mt_pos,
    const int* __restrict__ edst,
    const uint* __restrict__ tabU, const float* __restrict__ nodeH,
    float* __restrict__ midsum)
{
  __shared__ float nh[288];   // 8 src rows x 36
  const int tid = threadIdx.x;
  const int blk = blockIdx.x;
  if (tid < 72) ((float4*)nh)[tid] = ((const float4*)(nodeH + (size_t)blk * 288))[tid];
  __syncthreads();

  int e = blk * 256 + tid;
  int src = e >> 5;                    // edge list is src-major
  int dst = edst[e];
  const float* ps = (src < NH_) ? (wt_pos + src * 3) : (mt_pos + (src - NH_) * 3);
  const float* pdp = (dst < NH_) ? (wt_pos + dst * 3) : (mt_pos + (dst - NH_) * 3);
  float vx = ps[0] - pdp[0], vy = ps[1] - pdp[1], vz = ps[2] - pdp[2];
  float r = sqrtf(vx * vx + vy * vy + vz * vz);
  int ti = min((int)(r * RIDX + 0.5f), TS - 1);
  const uint4* w4 = (const uint4*)(tabU + (size_t)ti * 64 + 52);
  uint4 wr[2];
  wr[0] = w4[0]; wr[1] = w4[1];
  float acc[16];
  UN<16>([&](auto c){ acc[c.v] = upk<c.v>(wr); });

  float sh[16];
  make_sh(vx, vy, vz, r, sh);

  const float4* Hp = (const float4*)(nh + (src & 7) * 36);
  float4 Hv[9];
  UN<9>([&](auto j){ Hv[j.v] = Hp[j.v]; });

  float ev[16];
  UN<10>([&](auto c){ ev[c.v] = f4get<c.v>(Hv) * acc[c.v]; });
  UN<3>([&](auto u){
    float d = 0.f;
    UN<3>([&](auto m){ d = fmaf(f4get<10 + u.v * 3 + m.v>(Hv), sh[1 + m.v], d); });
    ev[10 + u.v] = d * 0.57735026918963f * acc[10 + u.v];
  });
  UN<2>([&](auto u){
    float d = 0.f;
    UN<5>([&](auto m){ d = fmaf(f4get<19 + u.v * 5 + m.v>(Hv), sh[4 + m.v], d); });
    ev[13 + u.v] = d * 0.44721359549996f * acc[13 + u.v];
  });
  {
    float d = 0.f;
    UN<7>([&](auto m){ d = fmaf(f4get<29 + m.v>(Hv), sh[9 + m.v], d); });
    ev[15] = d * 0.37796447300923f * acc[15];
  }

  int g = (dst >> 7) & 31;
  int lane = tid & 63;
  float s = creduce<16>(ev, lane);
  if (lane < 16) atomicAdd(&midsum[g * 16 + lane], s);
}

// finale: fold head through sc2_w / lin2b, one block
__global__ void k_final(const float* __restrict__ sc2w, const float* __restrict__ lin2b,
                        const float* __restrict__ headw, const float* __restrict__ headb,
                        const float* __restrict__ scalsum, const float* __restrict__ midsum,
                        float* __restrict__ out)
{
  __shared__ float WA[20];
  __shared__ float WB[32];
  int t = threadIdx.x;
  if (t < 20) {
    int j = t >> 1, o = t & 1;
    float a = 0.f;
    for (int c = 0; c < 256; ++c) a += sc2w[j * 256 + c] * headw[c * 2 + o];
    WA[t] = a;
  } else if (t < 52) {
    int q = t - 20, j = q >> 1, o = q & 1;
    float a = 0.f;
    for (int c = 0; c < 256; ++c) a += lin2b[j * 256 + c] * headw[c * 2 + o];
    WB[q] = a;
  }
  __syncthreads();
  if (t < 64) {
    int g = t & 31, o = t >> 5;
    float a = 0.f;
    for (int j = 0; j < 10; ++j) a += scalsum[g * 10 + j] * WA[j * 2 + o];
    float b = 0.f;
    for (int j = 0; j < 16; ++j) b += midsum[g * 16 + j] * WB[j * 2 + o];
    float y = a * (0.38268343236509f * 0.31622776601684f)
            + b * (0.92387953251129f * 0.25f);
    out[o * 32 + g] = y * (1.0f / 256.0f) + headb[o];
  }
}

extern "C" void kernel_launch(void* const* d_in, const int* in_sizes, int n_in,
                              void* d_out, int out_size, void* d_ws, size_t ws_size,
                              hipStream_t stream)
{
  float* ws = (float*)d_ws;
  const float* wt_pos = (const float*)d_in[0];
  const float* mt_pos = (const float*)d_in[1];
  const float* wt_x   = (const float*)d_in[2];
  const float* mt_x   = (const float*)d_in[3];
  const int* edst     = (const int*)d_in[7];
  const float* sc1w   = (const float*)d_in[8];
  const float* lin1a  = (const float*)d_in[9];
  const float* fc1w1  = (const float*)d_in[10];
  const float* fc1w2  = (const float*)d_in[11];
  const float* l2a0   = (const float*)d_in[12];
  const float* l2a1   = (const float*)d_in[13];
  const float* l2a2   = (const float*)d_in[14];
  const float* l2a3   = (const float*)d_in[15];
  const float* sc2w   = (const float*)d_in[16];
  const float* l1b0   = (const float*)d_in[17];
  const float* l1b1   = (const float*)d_in[18];
  const float* l1b2   = (const float*)d_in[19];
  const float* l1b3   = (const float*)d_in[20];
  const float* fc2w1  = (const float*)d_in[21];
  const float* fc2w2  = (const float*)d_in[22];
  const float* lin2b  = (const float*)d_in[23];
  const float* headw  = (const float*)d_in[24];
  const float* headb  = (const float*)d_in[25];

  float* h       = ws + OFF_H;
  float* sc1     = ws + OFF_SC1;
  float* nodeH   = ws + OFF_NODEH;
  float* scalsum = ws + OFF_SCALS;
  float* midsum  = ws + OFF_MIDS;
  uint*  tabU    = (uint*)(ws + OFF_TABU);
  float* A       = ws + OFF_A;
  int*   ssrc    = (int*)(ws + OFF_SSRC);
  int*   soff    = (int*)(ws + OFF_SOFF);

  k_prep<<<2145, 256, 0, stream>>>(wt_x, mt_x, lin1a, sc1w, fc1w1, fc1w2, fc2w1, fc2w2,
                                   edst, h, sc1, tabU, scalsum, ssrc, soff);
  k_edge1<<<1024, 256, 0, stream>>>(wt_pos, mt_pos, soff, ssrc, tabU, h,
                                    l2a0, l2a1, l2a2, l2a3, A);
  k_node2<<<32, 256, 0, stream>>>(A, sc1, l1b0, l1b1, l1b2, l1b3, nodeH, scalsum);
  k_edge2<<<1024, 256, 0, stream>>>(wt_pos, mt_pos, edst, tabU, nodeH, midsum);
  k_final<<<1, 256, 0, stream>>>(sc2w, lin2b, headw, headb, scalsum, midsum, (float*)d_out);
}

// Round 11
// 72.079 us; speedup vs baseline: 12.0917x; 1.0584x over previous
//
#include <hip/hip_runtime.h>

typedef unsigned int uint;

#define NH_   4096
#define NNODE 8192
#define NEDGE 262144
#define TS    4096
#define RT    17.4f
#define RIDX  (((float)(TS - 1)) / RT)

// ---- workspace layout (float offsets) ----
#define OFF_H      0        // 8192*28
#define OFF_SC1    229376   // 8192*16
#define OFF_SCALS  655360   // 32*10
#define OFF_MIDS   655680   // 32*16  (contiguous with SCALS: 832)
#define OFF_TABU   656384   // 4096*64 uints (bf16-packed r-table, scales folded)
#define OFF_SSRC   1278976  // 262144 ints (src sorted by dst)
#define OFF_SOFF   1541120  // 8256 ints (CSR offsets by dst)

// ---- compile-time unroll ----
template <int I> struct ic { static constexpr int v = I; };
template <int N, typename F>
__device__ __forceinline__ void UN(F&& f) {
  if constexpr (N > 0) { UN<N - 1>(f); f(ic<N - 1>{}); }
}

template <int K>
__device__ __forceinline__ float f4c(float4 v) {
  if constexpr (K == 0) return v.x;
  else if constexpr (K == 1) return v.y;
  else if constexpr (K == 2) return v.z;
  else return v.w;
}
template <int C>
__device__ __forceinline__ float f4get(const float4* v) {
  return f4c<C & 3>(v[C >> 2]);
}
template <int K>
__device__ __forceinline__ uint u4c(uint4 v) {
  if constexpr (K == 0) return v.x;
  else if constexpr (K == 1) return v.y;
  else if constexpr (K == 2) return v.z;
  else return v.w;
}
// unpack bf16-pair channel CH from packed uint4 regs
template <int CH>
__device__ __forceinline__ float upk(const uint4* wr) {
  constexpr int pr = CH >> 1;
  uint u = u4c<pr & 3>(wr[pr >> 2]);
  if constexpr (CH & 1) return __uint_as_float(u & 0xffff0000u);
  else return __uint_as_float(u << 16);
}

__device__ __forceinline__ float sigmoidf_(float v) { return 1.0f / (1.0f + __expf(-v)); }

// full-wave compacting reduction: C channels -> channel (lane & (C-1))
template <int C, int B>
__device__ __forceinline__ void cred_rec(float* a, int lane) {
  if constexpr ((1 << B) < C) {
    const bool hi = (lane >> B) & 1;
    constexpr int n = C >> (B + 1);
    UN<n>([&](auto j){
      float s0 = a[2 * j.v], s1 = a[2 * j.v + 1];
      float send = hi ? s0 : s1;
      float recv = __shfl_xor(send, 1 << B);
      a[j.v] = (hi ? s1 : s0) + recv;
    });
    cred_rec<C, B + 1>(a, lane);
  }
}
template <int C>
__device__ __forceinline__ float creduce(float* v, int lane) {
  cred_rec<C, 0>(v, lane);
  float s = v[0];
#pragma unroll
  for (int m = C; m < 64; m <<= 1) s += __shfl_xor(s, m);
  return s;
}
// half-wave (32-lane) compacting reduction of 64 channels, 5 steps.
template <int B>
__device__ __forceinline__ void cred32_rec(float* a, int lane) {
  if constexpr (B < 5) {
    const bool hi = (lane >> B) & 1;
    constexpr int n = 64 >> (B + 1);
    UN<n>([&](auto j){
      float s0 = a[2 * j.v], s1 = a[2 * j.v + 1];
      float send = hi ? s0 : s1;
      float recv = __shfl_xor(send, 1 << B);
      a[j.v] = (hi ? s1 : s0) + recv;
    });
    cred32_rec<B + 1>(a, lane);
  }
}

__device__ __forceinline__ void make_emb(float r, float* embs) {
  float rb = r * 0.45f;
  UN<10>([&](auto b){ float d = rb - (float)b.v; embs[b.v] = __expf(-d * d); });
}

__device__ __forceinline__ void make_sh(float vx, float vy, float vz, float r, float* sh) {
  float rinv = 1.0f / fmaxf(r, 1e-9f);
  float x = vx * rinv, y = vy * rinv, z = vz * rinv;
  float x2 = x * x, y2 = y * y, z2 = z * z;
  float shA = 3.87298334620742f * x * z;
  float shB = 1.93649167310371f * (z2 - x2);
  sh[0] = 1.f;
  sh[1] = 1.73205080756888f * x;
  sh[2] = 1.73205080756888f * y;
  sh[3] = 1.73205080756888f * z;
  sh[4] = shA;
  sh[5] = 3.87298334620742f * x * y;
  sh[6] = 2.23606797749979f * (y2 - 0.5f * (x2 + z2));
  sh[7] = 3.87298334620742f * y * z;
  sh[8] = shB;
  sh[9]  = 1.08012344973464f * (shA * z + shB * x);
  sh[10] = 2.64575131106459f * shA * y;
  sh[11] = 1.62018517460197f * (4.f * y2 - x2 - z2) * x;
  sh[12] = 1.32287565553230f * y * (2.f * y2 - 3.f * x2 - 3.f * z2);
  sh[13] = 1.62018517460197f * z * (4.f * y2 - x2 - z2);
  sh[14] = 2.64575131106459f * shB * y;
  sh[15] = 1.08012344973464f * (shB * z - shA * x);
}

// ---------------------------------------------------------------------------
// k_prep (merged, block-ranged): table / node1 / sort / zero  (same as r10)
// ---------------------------------------------------------------------------
__global__ void __launch_bounds__(256, 4) k_prep(
    const float* __restrict__ wt_x, const float* __restrict__ mt_x,
    const float* __restrict__ lin1a, const float* __restrict__ sc1w,
    const float* __restrict__ fc1w1, const float* __restrict__ fc1w2,
    const float* __restrict__ fc2w1, const float* __restrict__ fc2w2,
    const int* __restrict__ edst,
    float* __restrict__ h, float* __restrict__ sc1,
    uint* __restrict__ tabU, float* __restrict__ zacc,
    int* __restrict__ ssrc, int* __restrict__ soff)
{
  __shared__ float smemf[512];
  const int blk = blockIdx.x;
  const int tid = threadIdx.x;

  if (blk < 2048) {
    float (*sv)[2][128] = (float(*)[2][128])smemf;
    const int lane = tid & 63;
    const int wv = tid >> 6;
    const int si = wv >> 1;
    const int role = wv & 1;
    const int s = blk * 2 + si;
    const float r = (float)s * (RT / (float)(TS - 1));
    float emb[10];
    make_emb(r, emb);
    const float FS1 = 0.003125f;
    const float FS2 = 0.015625f;

    const float* wmat = (role == 0) ? fc1w1 : fc2w1;
    UN<2>([&](auto hh){
      int kk = lane + hh.v * 64;
      float hk = 0.f;
      UN<10>([&](auto j){ hk = fmaf(emb[j.v], wmat[j.v * 128 + kk], hk); });
      sv[si][role][kk] = hk * sigmoidf_(hk);
    });
    __syncthreads();

    float acc = 0.f;
    if (role == 0) {
      const float* base = fc1w2 + lane;
#pragma unroll 4
      for (int k = 0; k < 128; ++k)
        acc = fmaf(sv[si][0][k], base[k * 100], acc);
      acc *= FS1;
    } else {
      const bool isW1 = lane < 36;
      const bool isW2 = (lane >= 36) && (lane < 52);
      if (isW1 || isW2) {
        const float* base = isW1 ? (fc1w2 + 64 + lane) : (fc2w2 + (lane - 36));
        const int stride = isW1 ? 100 : 16;
        const int svi = isW1 ? 0 : 1;
#pragma unroll 4
        for (int k = 0; k < 128; ++k)
          acc = fmaf(sv[si][svi][k], base[k * stride], acc);
        acc *= (isW1 ? FS1 : FS2);
      }
    }

    int srcLo = 0, srcHi = 0;
    bool valid = false;
    if (role == 0) {
      srcLo = 2 * lane; srcHi = srcLo + 1; valid = lane < 32;
    } else {
      if (lane >= 32 && lane < 50)      { int i = lane - 32; srcLo = 2 * i;      srcHi = 2 * i + 1;  valid = true; }
      else if (lane >= 52 && lane < 60) { int i = lane - 52; srcLo = 36 + 2 * i; srcHi = 37 + 2 * i; valid = true; }
    }
    float lo = __shfl(acc, srcLo);
    float hi = __shfl(acc, srcHi);
    if (valid) {
      uint u = ((__float_as_uint(lo) + 0x8000u) >> 16)
             | (((__float_as_uint(hi) + 0x8000u) >> 16) << 16);
      tabU[(size_t)s * 64 + lane] = u;
    }
  } else if (blk < 2080) {
    int i = (blk - 2048) * 256 + tid;
    const float* xp = (i < NH_) ? (wt_x + i * 25) : (mt_x + (i - NH_) * 25);
    float xr[25];
    UN<25>([&](auto m){ xr[m.v] = xp[m.v]; });
    float ah[25], as[16];
    UN<25>([&](auto j){ ah[j.v] = 0.f; });
    UN<16>([&](auto j){ as[j.v] = 0.f; });
    UN<25>([&](auto m){
      float xm = xr[m.v];
      UN<25>([&](auto j){ ah[j.v] = fmaf(xm, lin1a[m.v * 25 + j.v], ah[j.v]); });
      UN<16>([&](auto j){ as[j.v] = fmaf(xm, sc1w[m.v * 16 + j.v], as[j.v]); });
    });
    UN<25>([&](auto j){ h[i * 28 + j.v] = 0.2f * ah[j.v]; });
    UN<16>([&](auto j){ sc1[i * 16 + j.v] = 0.2f * as[j.v]; });
  } else if (blk < 2144) {
    int* hist = (int*)smemf;
    int* cnt  = hist + 128;
    const int g = blk - 2080;
    if (tid < 128) hist[tid] = 0;
    __syncthreads();
    int dl[16];
    UN<16>([&](auto k){
      int e = g * 4096 + k.v * 256 + tid;
      dl[k.v] = edst[e] & 127;
      atomicAdd(&hist[dl[k.v]], 1);
    });
    __syncthreads();
    if (tid < 64) {
      int s0 = hist[2 * tid], s1 = hist[2 * tid + 1];
      int ps = s0 + s1;
      int sum = ps;
#pragma unroll
      for (int m = 1; m < 64; m <<= 1) {
        int t = __shfl_up(sum, m);
        if (tid >= m) sum += t;
      }
      int excl = sum - ps;
      cnt[2 * tid] = excl;
      cnt[2 * tid + 1] = excl + s0;
      soff[g * 128 + 2 * tid] = g * 4096 + excl;
      soff[g * 128 + 2 * tid + 1] = g * 4096 + excl + s0;
    }
    if (g == 0 && tid == 255) soff[NNODE] = NEDGE;
    __syncthreads();
    UN<16>([&](auto k){
      int e = g * 4096 + k.v * 256 + tid;
      int slot = atomicAdd(&cnt[dl[k.v]], 1);
      ssrc[g * 4096 + slot] = e >> 5;
    });
  } else {
    for (int z = tid; z < 832; z += 256) zacc[z] = 0.f;
  }
}

// ---------------------------------------------------------------------------
// k_mega: per block = 8 nodes [blk*8, blk*8+8).
//   Phase A (edge1 gather): half-wave per dst -> A-tile in LDS (no globals).
//   Phase B (node2): 8 threads -> nodeH tile in LDS + scal group atomics.
//   Phase C (edge2): 256 src-major edges e in [blk*256, blk*256+256),
//     src = e>>5 is in this block's node range; nodeH from LDS;
//     per-wave creduce -> midsum atomics.
// ---------------------------------------------------------------------------
__global__ void __launch_bounds__(256, 3) k_mega(
    const float* __restrict__ wt_pos, const float* __restrict__ mt_pos,
    const int* __restrict__ soff, const int* __restrict__ ssrc,
    const int* __restrict__ edst,
    const uint* __restrict__ tabU, const float* __restrict__ h,
    const float* __restrict__ sc1,
    const float* __restrict__ l2a0, const float* __restrict__ l2a1,
    const float* __restrict__ l2a2, const float* __restrict__ l2a3,
    const float* __restrict__ l1b0, const float* __restrict__ l1b1,
    const float* __restrict__ l1b2, const float* __restrict__ l1b3,
    float* __restrict__ scalsum, float* __restrict__ midsum)
{
  __shared__ float Atile[8][44];    // per-dst aggregated A (channels 0..41)
  __shared__ float nodeHs[8][36];   // per-node h0..h3

  const int tid = threadIdx.x;
  const int lane = tid & 63;
  const int li = lane & 31;
  const int hw = tid >> 5;                       // half-wave id 0..7
  const int dst = blockIdx.x * 8 + hw;

  // ---- Phase A: gather + accumulate + half-wave tree reduce ----
  {
    const int start = soff[dst];
    const int n = soff[dst + 1] - start;
    const float* pd = (dst < NH_) ? (wt_pos + dst * 3) : (mt_pos + (dst - NH_) * 3);
    const float pdx = pd[0], pdy = pd[1], pdz = pd[2];

    float acc[42];
    UN<42>([&](auto c){ acc[c.v] = 0.f; });

    const int nmax = max(n, __shfl_xor(n, 32));
#pragma unroll 1
    for (int it = 0; it < nmax; it += 32) {
      const int i = it + li;
      if (i < n) {
        const int src = ssrc[start + i];
        const float* ps = (src < NH_) ? (wt_pos + src * 3) : (mt_pos + (src - NH_) * 3);
        float vx = ps[0] - pdx, vy = ps[1] - pdy, vz = ps[2] - pdz;
        float r = sqrtf(vx * vx + vy * vy + vz * vz);
        int ti = min((int)(r * RIDX + 0.5f), TS - 1);
        const uint4* w4 = (const uint4*)(tabU + (size_t)ti * 64);
        uint4 wr[13];
        UN<13>([&](auto j){ wr[j.v] = w4[j.v]; });
        const float4* hp = (const float4*)(h + src * 28);
        float4 hq[7];
        UN<7>([&](auto j){ hq[j.v] = hp[j.v]; });
        float sh[16];
        make_sh(vx, vy, vz, r, sh);

        UN<25>([&](auto mm){
          float t = f4get<mm.v>(hq) * upk<mm.v>(wr);
          UN<16>([&](auto v){ acc[v.v] = fmaf(t, l2a0[mm.v * 16 + v.v], acc[v.v]); });
        });
        {
          float p1[3] = {0.f, 0.f, 0.f};
          UN<25>([&](auto mm){
            float t = f4get<mm.v>(hq) * upk<25 + mm.v>(wr);
            UN<3>([&](auto v){ p1[v.v] = fmaf(t, l2a1[mm.v * 3 + v.v], p1[v.v]); });
          });
          UN<3>([&](auto v){
            UN<3>([&](auto m){ acc[16 + v.v * 3 + m.v] = fmaf(p1[v.v], sh[1 + m.v], acc[16 + v.v * 3 + m.v]); });
          });
        }
        {
          float p2[2] = {0.f, 0.f};
          UN<25>([&](auto mm){
            float t = f4get<mm.v>(hq) * upk<50 + mm.v>(wr);
            UN<2>([&](auto v){ p2[v.v] = fmaf(t, l2a2[mm.v * 2 + v.v], p2[v.v]); });
          });
          UN<2>([&](auto v){
            UN<5>([&](auto m){ acc[25 + v.v * 5 + m.v] = fmaf(p2[v.v], sh[4 + m.v], acc[25 + v.v * 5 + m.v]); });
          });
        }
        {
          float p3 = 0.f;
          UN<25>([&](auto mm){
            float t = f4get<mm.v>(hq) * upk<75 + mm.v>(wr);
            p3 = fmaf(t, l2a3[mm.v], p3);
          });
          UN<7>([&](auto m){ acc[35 + m.v] = fmaf(p3, sh[9 + m.v], acc[35 + m.v]); });
        }
      }
    }

    float red[64];
    UN<42>([&](auto c){ red[c.v] = acc[c.v]; });
    UN<22>([&](auto c){ red[42 + c.v] = 0.f; });
    cred32_rec<0>(red, lane);
    Atile[hw][li] = red[0];
    if (li < 10) Atile[hw][32 + li] = red[1];
  }
  __syncthreads();

  // ---- Phase B: node2 for the block's 8 nodes (8 threads) ----
  if (tid < 8) {
    const int i = blockIdx.x * 8 + tid;
    float Ai[42];
    UN<42>([&](auto c){ Ai[c.v] = Atile[tid][c.v]; });
    const float CS_ = 0.38268343236509f, CX_ = 0.92387953251129f;
    float scal[10], gate[6];
    UN<10>([&](auto c){
      float s = CS_ * sc1[i * 16 + c.v] + CX_ * Ai[c.v];
      scal[c.v] = s * sigmoidf_(s);
    });
    UN<6>([&](auto c){
      float s = CS_ * sc1[i * 16 + 10 + c.v] + CX_ * Ai[10 + c.v];
      gate[c.v] = sigmoidf_(s);
    });
    UN<10>([&](auto v){
      float a = 0.f;
      UN<10>([&](auto u){ a = fmaf(scal[u.v], l1b0[u.v * 10 + v.v], a); });
      nodeHs[tid][v.v] = a * 0.31622776601684f;
    });
    UN<3>([&](auto v){
      UN<3>([&](auto m){
        float a = 0.f;
        UN<3>([&](auto u){ a = fmaf(Ai[16 + u.v * 3 + m.v] * gate[u.v], l1b1[u.v * 3 + v.v], a); });
        nodeHs[tid][10 + v.v * 3 + m.v] = a * 0.57735026918963f;
      });
    });
    UN<2>([&](auto v){
      UN<5>([&](auto m){
        float a = 0.f;
        UN<2>([&](auto u){ a = fmaf(Ai[25 + u.v * 5 + m.v] * gate[3 + u.v], l1b2[u.v * 2 + v.v], a); });
        nodeHs[tid][19 + v.v * 5 + m.v] = a * 0.70710678118655f;
      });
    });
    float b3 = l1b3[0];
    UN<7>([&](auto m){ nodeHs[tid][29 + m.v] = Ai[35 + m.v] * gate[5] * b3; });

    // group scal sums (group uniform within block)
    const int g = (i >> 7) & 31;
    UN<10>([&](auto c){ atomicAdd(&scalsum[g * 10 + c.v], scal[c.v]); });
  }
  __syncthreads();

  // ---- Phase C: edge2 for edges e in [blk*256, blk*256+256) ----
  {
    const int e = blockIdx.x * 256 + tid;
    const int sl = tid >> 5;                    // local src = e>>5 - blk*8
    const int src = blockIdx.x * 8 + sl;
    const int dst2 = edst[e];
    const float* ps = (src < NH_) ? (wt_pos + src * 3) : (mt_pos + (src - NH_) * 3);
    const float* pdp = (dst2 < NH_) ? (wt_pos + dst2 * 3) : (mt_pos + (dst2 - NH_) * 3);
    float vx = ps[0] - pdp[0], vy = ps[1] - pdp[1], vz = ps[2] - pdp[2];
    float r = sqrtf(vx * vx + vy * vy + vz * vz);
    int ti = min((int)(r * RIDX + 0.5f), TS - 1);
    const uint4* w4 = (const uint4*)(tabU + (size_t)ti * 64 + 52);
    uint4 wr[2];
    wr[0] = w4[0]; wr[1] = w4[1];
    float acc[16];
    UN<16>([&](auto c){ acc[c.v] = upk<c.v>(wr); });

    float sh[16];
    make_sh(vx, vy, vz, r, sh);

    const float* Hs = nodeHs[sl];
    float ev[16];
    UN<10>([&](auto c){ ev[c.v] = Hs[c.v] * acc[c.v]; });
    UN<3>([&](auto u){
      float d = 0.f;
      UN<3>([&](auto m){ d = fmaf(Hs[10 + u.v * 3 + m.v], sh[1 + m.v], d); });
      ev[10 + u.v] = d * 0.57735026918963f * acc[10 + u.v];
    });
    UN<2>([&](auto u){
      float d = 0.f;
      UN<5>([&](auto m){ d = fmaf(Hs[19 + u.v * 5 + m.v], sh[4 + m.v], d); });
      ev[13 + u.v] = d * 0.44721359549996f * acc[13 + u.v];
    });
    {
      float d = 0.f;
      UN<7>([&](auto m){ d = fmaf(Hs[29 + m.v], sh[9 + m.v], d); });
      ev[15] = d * 0.37796447300923f * acc[15];
    }

    const int g = (dst2 >> 7) & 31;
    float s = creduce<16>(ev, lane);
    if (lane < 16) atomicAdd(&midsum[g * 16 + lane], s);
  }
}

// finale: fold head through sc2_w / lin2b, one block
__global__ void k_final(const float* __restrict__ sc2w, const float* __restrict__ lin2b,
                        const float* __restrict__ headw, const float* __restrict__ headb,
                        const float* __restrict__ scalsum, const float* __restrict__ midsum,
                        float* __restrict__ out)
{
  __shared__ float WA[20];
  __shared__ float WB[32];
  int t = threadIdx.x;
  if (t < 20) {
    int j = t >> 1, o = t & 1;
    float a = 0.f;
    for (int c = 0; c < 256; ++c) a += sc2w[j * 256 + c] * headw[c * 2 + o];
    WA[t] = a;
  } else if (t < 52) {
    int q = t - 20, j = q >> 1, o = q & 1;
    float a = 0.f;
    for (int c = 0; c < 256; ++c) a += lin2b[j * 256 + c] * headw[c * 2 + o];
    WB[q] = a;
  }
  __syncthreads();
  if (t < 64) {
    int g = t & 31, o = t >> 5;
    float a = 0.f;
    for (int j = 0; j < 10; ++j) a += scalsum[g * 10 + j] * WA[j * 2 + o];
    float b = 0.f;
    for (int j = 0; j < 16; ++j) b += midsum[g * 16 + j] * WB[j * 2 + o];
    float y = a * (0.38268343236509f * 0.31622776601684f)
            + b * (0.92387953251129f * 0.25f);
    out[o * 32 + g] = y * (1.0f / 256.0f) + headb[o];
  }
}

extern "C" void kernel_launch(void* const* d_in, const int* in_sizes, int n_in,
                              void* d_out, int out_size, void* d_ws, size_t ws_size,
                              hipStream_t stream)
{
  float* ws = (float*)d_ws;
  const float* wt_pos = (const float*)d_in[0];
  const float* mt_pos = (const float*)d_in[1];
  const float* wt_x   = (const float*)d_in[2];
  const float* mt_x   = (const float*)d_in[3];
  const int* edst     = (const int*)d_in[7];
  const float* sc1w   = (const float*)d_in[8];
  const float* lin1a  = (const float*)d_in[9];
  const float* fc1w1  = (const float*)d_in[10];
  const float* fc1w2  = (const float*)d_in[11];
  const float* l2a0   = (const float*)d_in[12];
  const float* l2a1   = (const float*)d_in[13];
  const float* l2a2   = (const float*)d_in[14];
  const float* l2a3   = (const float*)d_in[15];
  const float* sc2w   = (const float*)d_in[16];
  const float* l1b0   = (const float*)d_in[17];
  const float* l1b1   = (const float*)d_in[18];
  const float* l1b2   = (const float*)d_in[19];
  const float* l1b3   = (const float*)d_in[20];
  const float* fc2w1  = (const float*)d_in[21];
  const float* fc2w2  = (const float*)d_in[22];
  const float* lin2b  = (const float*)d_in[23];
  const float* headw  = (const float*)d_in[24];
  const float* headb  = (const float*)d_in[25];

  float* h       = ws + OFF_H;
  float* sc1     = ws + OFF_SC1;
  float* scalsum = ws + OFF_SCALS;
  float* midsum  = ws + OFF_MIDS;
  uint*  tabU    = (uint*)(ws + OFF_TABU);
  int*   ssrc    = (int*)(ws + OFF_SSRC);
  int*   soff    = (int*)(ws + OFF_SOFF);

  k_prep<<<2145, 256, 0, stream>>>(wt_x, mt_x, lin1a, sc1w, fc1w1, fc1w2, fc2w1, fc2w2,
                                   edst, h, sc1, tabU, scalsum, ssrc, soff);
  k_mega<<<1024, 256, 0, stream>>>(wt_pos, mt_pos, soff, ssrc, edst, tabU, h, sc1,
                                   l2a0, l2a1, l2a2, l2a3,
                                   l1b0, l1b1, l1b2, l1b3,
                                   scalsum, midsum);
  k_final<<<1, 256, 0, stream>>>(sc2w, lin2b, headw, headb, scalsum, midsum, (float*)d_out);
}